// Round 5
// baseline (3588.647 us; speedup 1.0000x reference)
//
#include <hip/hip_runtime.h>
#include <math.h>

// ---------------------------------------------------------------------------
// VQ-VAE forward, fp32, NHWC intermediates.
// R5: LDS-staged transposed convs (input tile read from HBM once per block,
// co-groups looped inside the kernel), merged-cog conv2.
//  x (1024,1,50,50)
//  conv1 k3s2p1+relu -> h1 (n,25,25,32)   [regB]
//  conv2 k3s2p1+relu -> h2 (n,13,13,64)   [regA]   (single pass, 64 co/thread)
//  conv3 1x1         -> z  (n,13,13,64)   [regB]
//  VQ 512x64 (slice+merge) -> q (n,13,13,64) [regA] + loss atomic
//  tconv1 13->25+relu-> d1 (n,25,25,64)   [regB]   (LDS tile, 4 cog inside)
//  tconv2 25->50+relu-> d2 (n,50,50,32)   [regA]   (LDS tile, 2 cog inside)
//  convf k3s1p1+sigm -> out (n,50,50)
// ---------------------------------------------------------------------------

__global__ __launch_bounds__(64) void k_zero(float* __restrict__ p) {
    if (threadIdx.x == 0 && blockIdx.x == 0) *p = 0.f;
}

// ---- weight transpose preps ------------------------------------------------
// w2m: [cc8][tap9][j4][co64] <- ew2[co][ci=cc*4+j][tap]
__global__ __launch_bounds__(256) void k_prep_w2m(const float* __restrict__ w,
                                                  float* __restrict__ o) {
    int i = blockIdx.x * 256 + threadIdx.x;  // 18432
    int co = i & 63, j = (i >> 6) & 3, tap = (i >> 8) % 9, cc = (i >> 8) / 9;
    o[i] = w[(co * 32 + cc * 4 + j) * 9 + tap];
}
// w3t: [ci64][co64] <- ew3[co][ci]
__global__ __launch_bounds__(256) void k_prep_w3t(const float* __restrict__ w,
                                                  float* __restrict__ o) {
    int i = blockIdx.x * 256 + threadIdx.x;  // 4096
    int co = i & 63, ci = i >> 6;
    o[i] = w[co * 64 + ci];
}
// wt1: [cog4][cc16][tap9][j4][co16] <- dw1[co_g=cog*16+co][ci=cc*4+j][tap]
__global__ __launch_bounds__(256) void k_prep_wt1(const float* __restrict__ w,
                                                  float* __restrict__ o) {
    int i = blockIdx.x * 256 + threadIdx.x;  // 36864
    int co = i & 15, j = (i >> 4) & 3, tap = (i >> 6) % 9;
    int q = (i >> 6) / 9, cc = q & 15, cog = q >> 4;
    o[i] = w[((cog * 16 + co) * 64 + cc * 4 + j) * 9 + tap];
}
// wt2: [cog2][cc16][tap9][j4][co16] <- dw2[co_g=cog*16+co][ci=cc*4+j][tap]
__global__ __launch_bounds__(256) void k_prep_wt2(const float* __restrict__ w,
                                                  float* __restrict__ o) {
    int i = blockIdx.x * 256 + threadIdx.x;  // 18432
    int co = i & 15, j = (i >> 4) & 3, tap = (i >> 6) % 9;
    int q = (i >> 6) / 9, cc = q & 15, cog = q >> 4;
    o[i] = w[((cog * 16 + co) * 64 + cc * 4 + j) * 9 + tap];
}
// cn[k] = ||cb[k]||^2
__global__ __launch_bounds__(256) void k_prep_cn(const float* __restrict__ cb,
                                                 float* __restrict__ cn) {
    int k = blockIdx.x * 256 + threadIdx.x;  // 512
    const float* r = cb + k * 64;
    float s = 0.f;
#pragma unroll
    for (int c = 0; c < 64; ++c) s += r[c] * r[c];
    cn[k] = s;
}

// ---- conv1: x (bc,50,50) -> h1 (bc,25,25,32), relu -------------------------
__global__ __launch_bounds__(256) void k_conv1(const float* __restrict__ x,
                                               const float* __restrict__ w,   // ew1 OIHW
                                               const float* __restrict__ b,
                                               float* __restrict__ h1, int total) {
    __shared__ float4 wl4[72];  // [tap9][co32] as f4
    float* wl = (float*)wl4;
    int tid = threadIdx.x;
    for (int t = tid; t < 288; t += 256) {
        int tap = t >> 5, co = t & 31;
        wl[t] = w[co * 9 + tap];
    }
    __syncthreads();
    int pix = blockIdx.x * 256 + tid;
    if (pix >= total) return;
    int n = pix / 625, p = pix % 625, oh = p / 25, ow = p % 25;
    const float* xp = x + (size_t)n * 2500;
    float4 a[8];
#pragma unroll
    for (int j = 0; j < 8; ++j) a[j] = ((const float4*)b)[j];
#pragma unroll
    for (int kh = 0; kh < 3; ++kh) {
        int ih = 2 * oh - 1 + kh;
        if ((unsigned)ih >= 50u) continue;
#pragma unroll
        for (int kw = 0; kw < 3; ++kw) {
            int iw = 2 * ow - 1 + kw;
            if ((unsigned)iw >= 50u) continue;
            float v = xp[ih * 50 + iw];
            int tap = kh * 3 + kw;
#pragma unroll
            for (int j = 0; j < 8; ++j) {
                float4 ww = wl4[tap * 8 + j];
                a[j].x += v * ww.x; a[j].y += v * ww.y;
                a[j].z += v * ww.z; a[j].w += v * ww.w;
            }
        }
    }
    float4* op = (float4*)(h1 + (size_t)pix * 32);
#pragma unroll
    for (int j = 0; j < 8; ++j) {
        float4 r;
        r.x = fmaxf(a[j].x, 0.f); r.y = fmaxf(a[j].y, 0.f);
        r.z = fmaxf(a[j].z, 0.f); r.w = fmaxf(a[j].w, 0.f);
        op[j] = r;
    }
}

// ---- conv2: h1 -> h2 (bc,13,13,64), relu. lane=pixel, ALL 64 co/thread -----
__global__ __launch_bounds__(256, 3) void k_conv2(const float* __restrict__ h1,
                                                  const float* __restrict__ w2m,
                                                  const float* __restrict__ b,
                                                  float* __restrict__ h2, int npix) {
    int pix = blockIdx.x * 256 + threadIdx.x;
    if (pix >= npix) return;
    int n = pix / 169, p = pix % 169, oh = p / 13, ow = p % 13;
    float acc[64];
#pragma unroll
    for (int co = 0; co < 64; ++co) acc[co] = b[co];
    const float4 zero = {0.f, 0.f, 0.f, 0.f};
    auto ldcc = [&](float4* dst, int cc) {
#pragma unroll
        for (int kh = 0; kh < 3; ++kh) {
            int ih = 2 * oh - 1 + kh;
#pragma unroll
            for (int kw = 0; kw < 3; ++kw) {
                int iw = 2 * ow - 1 + kw;
                bool ok = ((unsigned)ih < 25u) && ((unsigned)iw < 25u);
                dst[kh * 3 + kw] = ok ? *(const float4*)(h1 + (((size_t)n * 25 + ih) * 25 + iw) * 32 + cc * 4)
                                      : zero;
            }
        }
    };
    float4 t[9], tn[9];
    ldcc(t, 0);
#pragma unroll 1
    for (int cc = 0; cc < 8; ++cc) {
        if (cc < 7) ldcc(tn, cc + 1);  // prefetch next chunk's inputs
#pragma unroll
        for (int tap = 0; tap < 9; ++tap) {
#pragma unroll
            for (int j = 0; j < 4; ++j) {
                float vj = (j == 0) ? t[tap].x : (j == 1) ? t[tap].y : (j == 2) ? t[tap].z : t[tap].w;
                const float* wp = w2m + ((cc * 9 + tap) * 4 + j) * 64;
#pragma unroll
                for (int co = 0; co < 64; ++co) acc[co] = fmaf(vj, wp[co], acc[co]);
            }
        }
        if (cc < 7) {
#pragma unroll
            for (int i = 0; i < 9; ++i) t[i] = tn[i];
        }
    }
    float* op = h2 + (size_t)pix * 64;
#pragma unroll
    for (int c4 = 0; c4 < 16; ++c4) {
        float4 r = {fmaxf(acc[c4 * 4], 0.f), fmaxf(acc[c4 * 4 + 1], 0.f),
                    fmaxf(acc[c4 * 4 + 2], 0.f), fmaxf(acc[c4 * 4 + 3], 0.f)};
        *(float4*)(op + c4 * 4) = r;
    }
}

// ---- conv3 1x1: h2 -> z. lane=pixel, all 64 co in regs ---------------------
__global__ __launch_bounds__(256, 3) void k_conv3(const float* __restrict__ h2,
                                                  const float* __restrict__ w3t,
                                                  const float* __restrict__ b,
                                                  float* __restrict__ z, int npix) {
    int pix = blockIdx.x * 256 + threadIdx.x;
    if (pix >= npix) return;
    float acc[64];
#pragma unroll
    for (int co = 0; co < 64; ++co) acc[co] = b[co];
    const float4* zp = (const float4*)(h2 + (size_t)pix * 64);
    float4 v = zp[0];
#pragma unroll 1
    for (int cc = 0; cc < 16; ++cc) {
        float4 vn;
        if (cc < 15) vn = zp[cc + 1];  // prefetch
#pragma unroll
        for (int j = 0; j < 4; ++j) {
            float vj = (j == 0) ? v.x : (j == 1) ? v.y : (j == 2) ? v.z : v.w;
            const float* wp = w3t + (cc * 4 + j) * 64;
#pragma unroll
            for (int co = 0; co < 64; ++co) acc[co] = fmaf(vj, wp[co], acc[co]);
        }
        if (cc < 15) v = vn;
    }
    float* op = z + (size_t)pix * 64;
#pragma unroll
    for (int c4 = 0; c4 < 16; ++c4) {
        float4 r = {acc[c4 * 4], acc[c4 * 4 + 1], acc[c4 * 4 + 2], acc[c4 * 4 + 3]};
        *(float4*)(op + c4 * 4) = r;
    }
}

// ---- VQ slice: scan 256 codes, write per-pixel (bestd, bestk) --------------
__global__ __launch_bounds__(256, 3) void k_vq_slice(const float* __restrict__ z,
                                                     const float* __restrict__ cb,
                                                     const float* __restrict__ cn,
                                                     float* __restrict__ bestd,
                                                     int* __restrict__ bestk, int npix) {
    int pix = blockIdx.x * 256 + threadIdx.x;
    if (pix >= npix) return;
    int k0 = blockIdx.y * 256;
    float4 z4[16];
    const float4* zp = (const float4*)(z + (size_t)pix * 64);
#pragma unroll
    for (int i = 0; i < 16; ++i) z4[i] = zp[i];
    const float4* cb4 = (const float4*)cb + (size_t)k0 * 16;
    const float* cns = cn + k0;
    float best = 3.4e38f;
    int bk = k0;
    for (int k = 0; k < 256; ++k) {
        const float4* cr = cb4 + k * 16;  // uniform index -> s_load
        float s0 = 0.f, s1 = 0.f;
#pragma unroll
        for (int i = 0; i < 16; i += 2) {
            float4 a = z4[i], b0 = cr[i];
            float4 c = z4[i + 1], d = cr[i + 1];
            s0 += a.x * b0.x + a.y * b0.y + a.z * b0.z + a.w * b0.w;
            s1 += c.x * d.x + c.y * d.y + c.z * d.z + c.w * d.w;
        }
        float dd = cns[k] - 2.f * (s0 + s1);
        if (dd < best) { best = dd; bk = k0 + k; }
    }
    bestd[(size_t)blockIdx.y * npix + pix] = best;
    bestk[(size_t)blockIdx.y * npix + pix] = bk;
}

// ---- VQ merge: pick winner, write q, accumulate loss -----------------------
__global__ __launch_bounds__(256) void k_vq_merge(const float* __restrict__ z,
                                                  const float* __restrict__ cb,
                                                  const float* __restrict__ bestd,
                                                  const int* __restrict__ bestk,
                                                  float* __restrict__ q,
                                                  float* __restrict__ loss, int npix) {
    __shared__ float red[4];
    int tid = threadIdx.x;
    int pix = blockIdx.x * 256 + tid;
    bool active = pix < npix;
    float lsum = 0.f;
    if (active) {
        float d0 = bestd[pix], d1 = bestd[(size_t)npix + pix];
        int kk0 = bestk[pix], kk1 = bestk[(size_t)npix + pix];
        int bk = (d1 < d0) ? kk1 : kk0;  // strict < : slice0 (lower k) wins ties
        const float4* cb4 = (const float4*)cb;
        const float4* zp = (const float4*)(z + (size_t)pix * 64);
        float4* qp = (float4*)(q + (size_t)pix * 64);
#pragma unroll
        for (int i = 0; i < 16; ++i) {
            float4 cq = cb4[bk * 16 + i];
            float4 zz = zp[i];
            float dx = cq.x - zz.x, dy = cq.y - zz.y, dz = cq.z - zz.z, dw = cq.w - zz.w;
            lsum += dx * dx + dy * dy + dz * dz + dw * dw;
            qp[i] = cq;
        }
    }
#pragma unroll
    for (int off = 32; off > 0; off >>= 1) lsum += __shfl_down(lsum, off);
    if ((tid & 63) == 0) red[tid >> 6] = lsum;
    __syncthreads();
    if (tid == 0) {
        float t = red[0] + red[1] + red[2] + red[3];
        atomicAdd(loss, t * (1.25f / 11075584.f));  // /(1024*64*13*13)
    }
}

// ---- tconv1: q (13,13,64) -> d1 (25,25,64), relu ---------------------------
// block = 192 threads = one image (169 quads); LDS tile 14x14 pos x 64 ch,
// pad 17 f4/pos; 4 cog passes from LDS; weights via uniform s_load stream.
__global__ __launch_bounds__(192) void k_tconv1(const float* __restrict__ in,
                                                const float* __restrict__ wt,
                                                const float* __restrict__ b,
                                                float* __restrict__ out) {
    __shared__ float4 lds4[196 * 17];  // 53,312 B
    int tid = threadIdx.x;
    int n = blockIdx.x;
    const float4 zero = {0.f, 0.f, 0.f, 0.f};
    const float4* in4 = (const float4*)(in + (size_t)n * 10816);
    for (int idx = tid; idx < 3136; idx += 192) {  // 14*14*16 f4
        int c4 = idx & 15, pos = idx >> 4;
        int rr = pos / 14, cc_ = pos % 14;
        bool ok = (rr < 13) && (cc_ < 13);
        lds4[pos * 17 + c4] = ok ? in4[(rr * 13 + cc_) * 16 + c4] : zero;
    }
    __syncthreads();
    if (tid >= 169) return;
    int qm = tid / 13, qw = tid % 13;
    bool bm = (qm < 12), bw = (qw < 12);
    int i00 = (qm * 14 + qw) * 17;
    int i01 = i00 + 17, i10 = i00 + 14 * 17, i11 = i10 + 17;
#pragma unroll 1
    for (int cog = 0; cog < 4; ++cog) {
        const float* bb = b + cog * 16;
        float a0[16], a1[16], a2[16], a3[16];
#pragma unroll
        for (int co = 0; co < 16; ++co) { float t = bb[co]; a0[co] = t; a1[co] = t; a2[co] = t; a3[co] = t; }
        const float* wb = wt + cog * 9216;
        float4 p00 = lds4[i00], p01 = lds4[i01], p10 = lds4[i10], p11 = lds4[i11];
#pragma unroll 1
        for (int cc = 0; cc < 16; ++cc) {
            float4 v00 = p00, v01 = p01, v10 = p10, v11 = p11;
            if (cc < 15) {  // prefetch next channel chunk
                p00 = lds4[i00 + cc + 1]; p01 = lds4[i01 + cc + 1];
                p10 = lds4[i10 + cc + 1]; p11 = lds4[i11 + cc + 1];
            }
#pragma unroll
            for (int jh = 0; jh < 3; ++jh) {
#pragma unroll
                for (int jw = 0; jw < 3; ++jw) {
                    int tap = jh * 3 + jw;
                    float4 v = (jh == 0) ? ((jw == 0) ? v11 : v10)
                                         : ((jw == 0) ? v01 : v00);
#pragma unroll
                    for (int j = 0; j < 4; ++j) {
                        float vj = (j == 0) ? v.x : (j == 1) ? v.y : (j == 2) ? v.z : v.w;
                        const float* wp = wb + ((cc * 9 + tap) * 4 + j) * 16;
#pragma unroll
                        for (int co = 0; co < 16; ++co) {
                            if (jh == 1 && jw == 1)      a0[co] = fmaf(vj, wp[co], a0[co]);
                            else if (jh == 1)            a1[co] = fmaf(vj, wp[co], a1[co]);
                            else if (jw == 1)            a2[co] = fmaf(vj, wp[co], a2[co]);
                            else                         a3[co] = fmaf(vj, wp[co], a3[co]);
                        }
                    }
                }
            }
        }
        size_t ob = (((size_t)n * 25 + 2 * qm) * 25 + 2 * qw) * 64 + cog * 16;
#pragma unroll
        for (int c4 = 0; c4 < 4; ++c4) {
            float4 r = {fmaxf(a0[c4 * 4], 0.f), fmaxf(a0[c4 * 4 + 1], 0.f),
                        fmaxf(a0[c4 * 4 + 2], 0.f), fmaxf(a0[c4 * 4 + 3], 0.f)};
            *(float4*)(out + ob + c4 * 4) = r;
        }
        if (bw) {
#pragma unroll
            for (int c4 = 0; c4 < 4; ++c4) {
                float4 r = {fmaxf(a1[c4 * 4], 0.f), fmaxf(a1[c4 * 4 + 1], 0.f),
                            fmaxf(a1[c4 * 4 + 2], 0.f), fmaxf(a1[c4 * 4 + 3], 0.f)};
                *(float4*)(out + ob + 64 + c4 * 4) = r;
            }
        }
        if (bm) {
#pragma unroll
            for (int c4 = 0; c4 < 4; ++c4) {
                float4 r = {fmaxf(a2[c4 * 4], 0.f), fmaxf(a2[c4 * 4 + 1], 0.f),
                            fmaxf(a2[c4 * 4 + 2], 0.f), fmaxf(a2[c4 * 4 + 3], 0.f)};
                *(float4*)(out + ob + 25 * 64 + c4 * 4) = r;
            }
        }
        if (bm && bw) {
#pragma unroll
            for (int c4 = 0; c4 < 4; ++c4) {
                float4 r = {fmaxf(a3[c4 * 4], 0.f), fmaxf(a3[c4 * 4 + 1], 0.f),
                            fmaxf(a3[c4 * 4 + 2], 0.f), fmaxf(a3[c4 * 4 + 3], 0.f)};
                *(float4*)(out + ob + 26 * 64 + c4 * 4) = r;
            }
        }
    }
}

// ---- tconv2: d1 (25,25,64) -> d2 (50,50,32), relu --------------------------
// block = 192 threads = one 13x13-quad tile (4 tiles/image); LDS 14x14x64,
// pad 17 f4/pos; 2 cog passes from LDS.
__global__ __launch_bounds__(192) void k_tconv2(const float* __restrict__ in,
                                                const float* __restrict__ wt,
                                                const float* __restrict__ b,
                                                float* __restrict__ out) {
    __shared__ float4 lds4[196 * 17];  // 53,312 B
    int tid = threadIdx.x;
    int bx = blockIdx.x;
    int n = bx >> 2, tile = bx & 3;
    int tm0 = (tile >> 1) * 13, tw0 = (tile & 1) * 13;
    const float4 zero = {0.f, 0.f, 0.f, 0.f};
    const float4* in4 = (const float4*)(in + (size_t)n * 40000);
    for (int idx = tid; idx < 3136; idx += 192) {  // 14*14*16 f4
        int c4 = idx & 15, pos = idx >> 4;
        int rr = tm0 + pos / 14, cc_ = tw0 + pos % 14;
        bool ok = (rr < 25) && (cc_ < 25);
        lds4[pos * 17 + c4] = ok ? in4[(rr * 25 + cc_) * 16 + c4] : zero;
    }
    __syncthreads();
    if (tid >= 169) return;
    int qm = tid / 13, qw = tid % 13;
    int qmg = tm0 + qm, qwg = tw0 + qw;
    if (qmg >= 25 || qwg >= 25) return;
    int i00 = (qm * 14 + qw) * 17;
    int i01 = i00 + 17, i10 = i00 + 14 * 17, i11 = i10 + 17;
#pragma unroll 1
    for (int cog = 0; cog < 2; ++cog) {
        const float* bb = b + cog * 16;
        float a0[16], a1[16], a2[16], a3[16];
#pragma unroll
        for (int co = 0; co < 16; ++co) { float t = bb[co]; a0[co] = t; a1[co] = t; a2[co] = t; a3[co] = t; }
        const float* wb = wt + cog * 9216;
        float4 p00 = lds4[i00], p01 = lds4[i01], p10 = lds4[i10], p11 = lds4[i11];
#pragma unroll 1
        for (int cc = 0; cc < 16; ++cc) {
            float4 v00 = p00, v01 = p01, v10 = p10, v11 = p11;
            if (cc < 15) {
                p00 = lds4[i00 + cc + 1]; p01 = lds4[i01 + cc + 1];
                p10 = lds4[i10 + cc + 1]; p11 = lds4[i11 + cc + 1];
            }
#pragma unroll
            for (int jh = 0; jh < 3; ++jh) {
#pragma unroll
                for (int jw = 0; jw < 3; ++jw) {
                    int tap = jh * 3 + jw;
                    float4 v = (jh == 0) ? ((jw == 0) ? v11 : v10)
                                         : ((jw == 0) ? v01 : v00);
#pragma unroll
                    for (int j = 0; j < 4; ++j) {
                        float vj = (j == 0) ? v.x : (j == 1) ? v.y : (j == 2) ? v.z : v.w;
                        const float* wp = wb + ((cc * 9 + tap) * 4 + j) * 16;
#pragma unroll
                        for (int co = 0; co < 16; ++co) {
                            if (jh == 1 && jw == 1)      a0[co] = fmaf(vj, wp[co], a0[co]);
                            else if (jh == 1)            a1[co] = fmaf(vj, wp[co], a1[co]);
                            else if (jw == 1)            a2[co] = fmaf(vj, wp[co], a2[co]);
                            else                         a3[co] = fmaf(vj, wp[co], a3[co]);
                        }
                    }
                }
            }
        }
        size_t ob = (((size_t)n * 50 + 2 * qmg) * 50 + 2 * qwg) * 32 + cog * 16;
#pragma unroll
        for (int c4 = 0; c4 < 4; ++c4) {
            float4 r0 = {fmaxf(a0[c4 * 4], 0.f), fmaxf(a0[c4 * 4 + 1], 0.f),
                         fmaxf(a0[c4 * 4 + 2], 0.f), fmaxf(a0[c4 * 4 + 3], 0.f)};
            *(float4*)(out + ob + c4 * 4) = r0;
            float4 r1 = {fmaxf(a1[c4 * 4], 0.f), fmaxf(a1[c4 * 4 + 1], 0.f),
                         fmaxf(a1[c4 * 4 + 2], 0.f), fmaxf(a1[c4 * 4 + 3], 0.f)};
            *(float4*)(out + ob + 32 + c4 * 4) = r1;
            float4 r2 = {fmaxf(a2[c4 * 4], 0.f), fmaxf(a2[c4 * 4 + 1], 0.f),
                         fmaxf(a2[c4 * 4 + 2], 0.f), fmaxf(a2[c4 * 4 + 3], 0.f)};
            *(float4*)(out + ob + 50 * 32 + c4 * 4) = r2;
            float4 r3 = {fmaxf(a3[c4 * 4], 0.f), fmaxf(a3[c4 * 4 + 1], 0.f),
                         fmaxf(a3[c4 * 4 + 2], 0.f), fmaxf(a3[c4 * 4 + 3], 0.f)};
            *(float4*)(out + ob + 51 * 32 + c4 * 4) = r3;
        }
    }
}

// ---- convf: d2 (bc,50,50,32) -> out (bc,50,50), sigmoid --------------------
__global__ __launch_bounds__(256) void k_convf(const float* __restrict__ in,
                                               const float* __restrict__ w,  // dw3 (1,32,3,3)
                                               const float* __restrict__ b,
                                               float* __restrict__ out, int total) {
    __shared__ float4 wl4[72];  // [tap9][ci32] f4
    float* wl = (float*)wl4;
    int tid = threadIdx.x;
    for (int t = tid; t < 288; t += 256) {
        int tap = t >> 5, ci = t & 31;
        wl[t] = w[ci * 9 + tap];
    }
    __syncthreads();
    int pix = blockIdx.x * 256 + tid;
    if (pix >= total) return;
    int n = pix / 2500, p = pix % 2500, oh = p / 50, ow = p % 50;
    float acc = b[0];
#pragma unroll
    for (int kh = 0; kh < 3; ++kh) {
        int ih = oh - 1 + kh;
        if ((unsigned)ih >= 50u) continue;
#pragma unroll
        for (int kw = 0; kw < 3; ++kw) {
            int iw = ow - 1 + kw;
            if ((unsigned)iw >= 50u) continue;
            int tap = kh * 3 + kw;
            const float4* ip = (const float4*)(in + (((size_t)n * 50 + ih) * 50 + iw) * 32);
#pragma unroll
            for (int cc = 0; cc < 8; ++cc) {
                float4 v = ip[cc];
                float4 ww = wl4[tap * 8 + cc];
                acc += v.x * ww.x + v.y * ww.y + v.z * ww.z + v.w * ww.w;
            }
        }
    }
    out[pix] = 1.f / (1.f + expf(-acc));
}

extern "C" void kernel_launch(void* const* d_in, const int* in_sizes, int n_in,
                              void* d_out, int out_size, void* d_ws, size_t ws_size,
                              hipStream_t stream) {
    const float* x   = (const float*)d_in[0];
    const float* ew1 = (const float*)d_in[1];
    const float* eb1 = (const float*)d_in[2];
    const float* ew2 = (const float*)d_in[3];
    const float* eb2 = (const float*)d_in[4];
    const float* ew3 = (const float*)d_in[5];
    const float* eb3 = (const float*)d_in[6];
    const float* cb  = (const float*)d_in[7];
    const float* dw1 = (const float*)d_in[8];
    const float* db1 = (const float*)d_in[9];
    const float* dw2 = (const float*)d_in[10];
    const float* db2 = (const float*)d_in[11];
    const float* dw3 = (const float*)d_in[12];
    const float* db3 = (const float*)d_in[13];
    float* out = (float*)d_out;
    float* loss = out + 2560000;

    float* ws   = (float*)d_ws;
    float* w2m  = ws;              // 18432
    float* w3t  = ws + 18432;      // 4096
    float* wt1  = ws + 22528;      // 36864
    float* wt2  = ws + 59392;      // 18432
    float* cn   = ws + 77824;      // 512
    const size_t tw_floats = 78336;

    const int B = 1024;
    // per image: regA 80000 + regB 40000 + bestd 2*169 + bestk 2*169
    const size_t A_per = 80000, B_per = 40000, V_per = 676;
    size_t avail = (ws_size / 4 > tw_floats) ? ws_size / 4 - tw_floats : 0;
    int BC = (int)(avail / (A_per + B_per + V_per));
    if (BC > B) BC = B;
    if (BC < 1) BC = 1;
    float* regA  = ws + tw_floats;
    float* regB  = regA + (size_t)BC * A_per;
    float* bestd = regB + (size_t)BC * B_per;            // 2*BC*169 floats
    int*   bestk = (int*)(bestd + (size_t)2 * BC * 169); // 2*BC*169 ints

    k_zero<<<1, 64, 0, stream>>>(loss);
    k_prep_w2m<<<72, 256, 0, stream>>>(ew2, w2m);
    k_prep_w3t<<<16, 256, 0, stream>>>(ew3, w3t);
    k_prep_wt1<<<144, 256, 0, stream>>>(dw1, wt1);
    k_prep_wt2<<<72, 256, 0, stream>>>(dw2, wt2);
    k_prep_cn <<<2, 256, 0, stream>>>(cb, cn);

    for (int n0 = 0; n0 < B; n0 += BC) {
        int bc = (B - n0 < BC) ? (B - n0) : BC;
        const float* xch = x + (size_t)n0 * 2500;

        int t1 = bc * 625;   // conv1: x -> h1 (regB)
        k_conv1<<<(t1 + 255) / 256, 256, 0, stream>>>(xch, ew1, eb1, regB, t1);

        int npix = bc * 169;
        // conv2 (merged cogs): regB -> regA (h2)
        k_conv2<<<(npix + 255) / 256, 256, 0, stream>>>(regB, w2m, eb2, regA, npix);

        // conv3: regA -> regB (z)
        k_conv3<<<(npix + 255) / 256, 256, 0, stream>>>(regA, w3t, eb3, regB, npix);

        // vq: regB (z) -> regA (q), via slice + merge
        dim3 gv((npix + 255) / 256, 2);
        k_vq_slice<<<gv, 256, 0, stream>>>(regB, cb, cn, bestd, bestk, npix);
        k_vq_merge<<<(npix + 255) / 256, 256, 0, stream>>>(regB, cb, bestd, bestk, regA, loss, npix);

        // tconv1 (LDS tile): regA (q) -> regB (d1); 1 block per image
        k_tconv1<<<bc, 192, 0, stream>>>(regA, wt1, db1, regB);

        // tconv2 (LDS tile): regB (d1) -> regA (d2); 4 tiles per image
        k_tconv2<<<bc * 4, 192, 0, stream>>>(regB, wt2, db2, regA);

        int t6 = bc * 2500;  // convf: regA -> out
        k_convf<<<(t6 + 255) / 256, 256, 0, stream>>>(regA, dw3, db3, out + (size_t)n0 * 2500, t6);
    }
}

// Round 6
// 1366.766 us; speedup vs baseline: 2.6256x; 2.6256x over previous
//
#include <hip/hip_runtime.h>
#include <math.h>

// ---------------------------------------------------------------------------
// VQ-VAE forward. Encoder+VQ fp32 (bit-stable argmin); decoder tconvs as
// bf16 MFMA implicit GEMM (safe: q is exact codebook lookup, bf16 error
// enters after argmin; output tolerance 1.05e-2 >> bf16 decoder error).
//  x (1024,1,50,50)
//  conv1 k3s2p1+relu -> h1 (n,25,25,32) f32   [regB]
//  conv2 k3s2p1+relu -> h2 (n,13,13,64) f32   [regA]
//  conv3 1x1         -> z  (n,13,13,64) f32   [regB]
//  VQ 512x64 (slice+merge) -> q f32           [regA] + loss atomic
//  tconv1 MFMA: q -> d1 (n,25,25,64) bf16     [regB]  GEMM M=169n,K=256,N=256
//  tconv2 MFMA: d1 -> d2 (n,50,50,32) bf16    [regA]  GEMM M=625n,K=256,N=128
//  convf k3s1p1+sigm (bf16 in, fp32 math) -> out (n,50,50)
// ---------------------------------------------------------------------------

typedef __attribute__((ext_vector_type(8))) short s8v;   // 8 bf16 frag
typedef __attribute__((ext_vector_type(4))) float f4v;   // MFMA acc
typedef __attribute__((ext_vector_type(4))) int i4v;

__device__ inline unsigned short f2bf(float f) {  // RNE fp32->bf16
    unsigned u = __builtin_bit_cast(unsigned, f);
    return (unsigned short)((u + 0x7fffu + ((u >> 16) & 1u)) >> 16);
}

__global__ __launch_bounds__(64) void k_zero(float* __restrict__ p) {
    if (threadIdx.x == 0 && blockIdx.x == 0) *p = 0.f;
}

// ---- weight preps ----------------------------------------------------------
// w2m: [cc8][tap9][j4][co64] <- ew2[co][ci=cc*4+j][tap]
__global__ __launch_bounds__(256) void k_prep_w2m(const float* __restrict__ w,
                                                  float* __restrict__ o) {
    int i = blockIdx.x * 256 + threadIdx.x;  // 18432
    int co = i & 63, j = (i >> 6) & 3, tap = (i >> 8) % 9, cc = (i >> 8) / 9;
    o[i] = w[(co * 32 + cc * 4 + j) * 9 + tap];
}
// w3t: [ci64][co64] <- ew3[co][ci]
__global__ __launch_bounds__(256) void k_prep_w3t(const float* __restrict__ w,
                                                  float* __restrict__ o) {
    int i = blockIdx.x * 256 + threadIdx.x;  // 4096
    int co = i & 63, ci = i >> 6;
    o[i] = w[co * 64 + ci];
}
// cn[k] = ||cb[k]||^2
__global__ __launch_bounds__(256) void k_prep_cn(const float* __restrict__ cb,
                                                 float* __restrict__ cn) {
    int k = blockIdx.x * 256 + threadIdx.x;  // 512
    const float* r = cb + k * 64;
    float s = 0.f;
#pragma unroll
    for (int c = 0; c < 64; ++c) s += r[c] * r[c];
    cn[k] = s;
}
// Zero-padded tconv weight matrices, MFMA-B-fragment-ready bf16 layout:
// element (nt, kc, lane, j) = B[k = kc*32+(lane>>4)*8+j][n = nt*16+(lane&15)]
// tconv1: K=256 (p*64+ci, p=patch pos), N=256 (cls*64+co), cls=a*2+b.
__global__ __launch_bounds__(256) void k_prep_B1(const float* __restrict__ w,  // dw1 (64,64,3,3)
                                                 unsigned short* __restrict__ o) {
    int i = blockIdx.x * 256 + threadIdx.x;  // 65536
    int j = i & 7, l = (i >> 3) & 63, kc = (i >> 9) & 7, nt = i >> 12;
    int n = nt * 16 + (l & 15), k = kc * 32 + (l >> 4) * 8 + j;
    int cls = n >> 6, co = n & 63, p = k >> 6, ci = k & 63;
    int jh = -1, jw = -1;
    if (cls == 0)      { if (p == 0) { jh = 1; jw = 1; } }
    else if (cls == 1) { if (p == 1) { jh = 1; jw = 0; } else if (p == 0) { jh = 1; jw = 2; } }
    else if (cls == 2) { if (p == 2) { jh = 0; jw = 1; } else if (p == 0) { jh = 2; jw = 1; } }
    else { if (p == 3) { jh = 0; jw = 0; } else if (p == 2) { jh = 0; jw = 2; }
           else if (p == 1) { jh = 2; jw = 0; } else { jh = 2; jw = 2; } }
    float v = (jh >= 0) ? w[((co * 64 + ci) * 3 + jh) * 3 + jw] : 0.f;
    o[i] = f2bf(v);
}
// tconv2: K=256, N=128 (cls*32+co), w = dw2 (32,64,3,3)
__global__ __launch_bounds__(256) void k_prep_B2(const float* __restrict__ w,
                                                 unsigned short* __restrict__ o) {
    int i = blockIdx.x * 256 + threadIdx.x;  // 32768
    int j = i & 7, l = (i >> 3) & 63, kc = (i >> 9) & 7, nt = i >> 12;
    int n = nt * 16 + (l & 15), k = kc * 32 + (l >> 4) * 8 + j;
    int cls = n >> 5, co = n & 31, p = k >> 6, ci = k & 63;
    int jh = -1, jw = -1;
    if (cls == 0)      { if (p == 0) { jh = 1; jw = 1; } }
    else if (cls == 1) { if (p == 1) { jh = 1; jw = 0; } else if (p == 0) { jh = 1; jw = 2; } }
    else if (cls == 2) { if (p == 2) { jh = 0; jw = 1; } else if (p == 0) { jh = 2; jw = 1; } }
    else { if (p == 3) { jh = 0; jw = 0; } else if (p == 2) { jh = 0; jw = 2; }
           else if (p == 1) { jh = 2; jw = 0; } else { jh = 2; jw = 2; } }
    float v = (jh >= 0) ? w[((co * 64 + ci) * 3 + jh) * 3 + jw] : 0.f;
    o[i] = f2bf(v);
}

// ---- conv1: x (bc,50,50) -> h1 (bc,25,25,32) f32, relu ---------------------
__global__ __launch_bounds__(256) void k_conv1(const float* __restrict__ x,
                                               const float* __restrict__ w,
                                               const float* __restrict__ b,
                                               float* __restrict__ h1, int total) {
    __shared__ float4 wl4[72];
    float* wl = (float*)wl4;
    int tid = threadIdx.x;
    for (int t = tid; t < 288; t += 256) {
        int tap = t >> 5, co = t & 31;
        wl[t] = w[co * 9 + tap];
    }
    __syncthreads();
    int pix = blockIdx.x * 256 + tid;
    if (pix >= total) return;
    int n = pix / 625, p = pix % 625, oh = p / 25, ow = p % 25;
    const float* xp = x + (size_t)n * 2500;
    float4 a[8];
#pragma unroll
    for (int j = 0; j < 8; ++j) a[j] = ((const float4*)b)[j];
#pragma unroll
    for (int kh = 0; kh < 3; ++kh) {
        int ih = 2 * oh - 1 + kh;
        if ((unsigned)ih >= 50u) continue;
#pragma unroll
        for (int kw = 0; kw < 3; ++kw) {
            int iw = 2 * ow - 1 + kw;
            if ((unsigned)iw >= 50u) continue;
            float v = xp[ih * 50 + iw];
            int tap = kh * 3 + kw;
#pragma unroll
            for (int j = 0; j < 8; ++j) {
                float4 ww = wl4[tap * 8 + j];
                a[j].x += v * ww.x; a[j].y += v * ww.y;
                a[j].z += v * ww.z; a[j].w += v * ww.w;
            }
        }
    }
    float4* op = (float4*)(h1 + (size_t)pix * 32);
#pragma unroll
    for (int j = 0; j < 8; ++j) {
        float4 r;
        r.x = fmaxf(a[j].x, 0.f); r.y = fmaxf(a[j].y, 0.f);
        r.z = fmaxf(a[j].z, 0.f); r.w = fmaxf(a[j].w, 0.f);
        op[j] = r;
    }
}

// ---- conv2: h1 -> h2 (bc,13,13,64) f32, relu -------------------------------
__global__ __launch_bounds__(256, 3) void k_conv2(const float* __restrict__ h1,
                                                  const float* __restrict__ w2m,
                                                  const float* __restrict__ b,
                                                  float* __restrict__ h2, int npix) {
    int pix = blockIdx.x * 256 + threadIdx.x;
    if (pix >= npix) return;
    int n = pix / 169, p = pix % 169, oh = p / 13, ow = p % 13;
    float acc[64];
#pragma unroll
    for (int co = 0; co < 64; ++co) acc[co] = b[co];
    const float4 zero = {0.f, 0.f, 0.f, 0.f};
    auto ldcc = [&](float4* dst, int cc) {
#pragma unroll
        for (int kh = 0; kh < 3; ++kh) {
            int ih = 2 * oh - 1 + kh;
#pragma unroll
            for (int kw = 0; kw < 3; ++kw) {
                int iw = 2 * ow - 1 + kw;
                bool ok = ((unsigned)ih < 25u) && ((unsigned)iw < 25u);
                dst[kh * 3 + kw] = ok ? *(const float4*)(h1 + (((size_t)n * 25 + ih) * 25 + iw) * 32 + cc * 4)
                                      : zero;
            }
        }
    };
    float4 t[9], tn[9];
    ldcc(t, 0);
#pragma unroll 1
    for (int cc = 0; cc < 8; ++cc) {
        if (cc < 7) ldcc(tn, cc + 1);
#pragma unroll
        for (int tap = 0; tap < 9; ++tap) {
#pragma unroll
            for (int j = 0; j < 4; ++j) {
                float vj = (j == 0) ? t[tap].x : (j == 1) ? t[tap].y : (j == 2) ? t[tap].z : t[tap].w;
                const float* wp = w2m + ((cc * 9 + tap) * 4 + j) * 64;
#pragma unroll
                for (int co = 0; co < 64; ++co) acc[co] = fmaf(vj, wp[co], acc[co]);
            }
        }
        if (cc < 7) {
#pragma unroll
            for (int i = 0; i < 9; ++i) t[i] = tn[i];
        }
    }
    float* op = h2 + (size_t)pix * 64;
#pragma unroll
    for (int c4 = 0; c4 < 16; ++c4) {
        float4 r = {fmaxf(acc[c4 * 4], 0.f), fmaxf(acc[c4 * 4 + 1], 0.f),
                    fmaxf(acc[c4 * 4 + 2], 0.f), fmaxf(acc[c4 * 4 + 3], 0.f)};
        *(float4*)(op + c4 * 4) = r;
    }
}

// ---- conv3 1x1: h2 -> z f32 ------------------------------------------------
__global__ __launch_bounds__(256, 3) void k_conv3(const float* __restrict__ h2,
                                                  const float* __restrict__ w3t,
                                                  const float* __restrict__ b,
                                                  float* __restrict__ z, int npix) {
    int pix = blockIdx.x * 256 + threadIdx.x;
    if (pix >= npix) return;
    float acc[64];
#pragma unroll
    for (int co = 0; co < 64; ++co) acc[co] = b[co];
    const float4* zp = (const float4*)(h2 + (size_t)pix * 64);
    float4 v = zp[0];
#pragma unroll 1
    for (int cc = 0; cc < 16; ++cc) {
        float4 vn;
        if (cc < 15) vn = zp[cc + 1];
#pragma unroll
        for (int j = 0; j < 4; ++j) {
            float vj = (j == 0) ? v.x : (j == 1) ? v.y : (j == 2) ? v.z : v.w;
            const float* wp = w3t + (cc * 4 + j) * 64;
#pragma unroll
            for (int co = 0; co < 64; ++co) acc[co] = fmaf(vj, wp[co], acc[co]);
        }
        if (cc < 15) v = vn;
    }
    float* op = z + (size_t)pix * 64;
#pragma unroll
    for (int c4 = 0; c4 < 16; ++c4) {
        float4 r = {acc[c4 * 4], acc[c4 * 4 + 1], acc[c4 * 4 + 2], acc[c4 * 4 + 3]};
        *(float4*)(op + c4 * 4) = r;
    }
}

// ---- VQ slice + merge (fp32, exact argmin semantics) -----------------------
__global__ __launch_bounds__(256, 3) void k_vq_slice(const float* __restrict__ z,
                                                     const float* __restrict__ cb,
                                                     const float* __restrict__ cn,
                                                     float* __restrict__ bestd,
                                                     int* __restrict__ bestk, int npix) {
    int pix = blockIdx.x * 256 + threadIdx.x;
    if (pix >= npix) return;
    int k0 = blockIdx.y * 256;
    float4 z4[16];
    const float4* zp = (const float4*)(z + (size_t)pix * 64);
#pragma unroll
    for (int i = 0; i < 16; ++i) z4[i] = zp[i];
    const float4* cb4 = (const float4*)cb + (size_t)k0 * 16;
    const float* cns = cn + k0;
    float best = 3.4e38f;
    int bk = k0;
    for (int k = 0; k < 256; ++k) {
        const float4* cr = cb4 + k * 16;
        float s0 = 0.f, s1 = 0.f;
#pragma unroll
        for (int i = 0; i < 16; i += 2) {
            float4 a = z4[i], b0 = cr[i];
            float4 c = z4[i + 1], d = cr[i + 1];
            s0 += a.x * b0.x + a.y * b0.y + a.z * b0.z + a.w * b0.w;
            s1 += c.x * d.x + c.y * d.y + c.z * d.z + c.w * d.w;
        }
        float dd = cns[k] - 2.f * (s0 + s1);
        if (dd < best) { best = dd; bk = k0 + k; }
    }
    bestd[(size_t)blockIdx.y * npix + pix] = best;
    bestk[(size_t)blockIdx.y * npix + pix] = bk;
}

__global__ __launch_bounds__(256) void k_vq_merge(const float* __restrict__ z,
                                                  const float* __restrict__ cb,
                                                  const float* __restrict__ bestd,
                                                  const int* __restrict__ bestk,
                                                  float* __restrict__ q,
                                                  float* __restrict__ loss, int npix) {
    __shared__ float red[4];
    int tid = threadIdx.x;
    int pix = blockIdx.x * 256 + tid;
    bool active = pix < npix;
    float lsum = 0.f;
    if (active) {
        float d0 = bestd[pix], d1 = bestd[(size_t)npix + pix];
        int kk0 = bestk[pix], kk1 = bestk[(size_t)npix + pix];
        int bk = (d1 < d0) ? kk1 : kk0;
        const float4* cb4 = (const float4*)cb;
        const float4* zp = (const float4*)(z + (size_t)pix * 64);
        float4* qp = (float4*)(q + (size_t)pix * 64);
#pragma unroll
        for (int i = 0; i < 16; ++i) {
            float4 cq = cb4[bk * 16 + i];
            float4 zz = zp[i];
            float dx = cq.x - zz.x, dy = cq.y - zz.y, dz = cq.z - zz.z, dw = cq.w - zz.w;
            lsum += dx * dx + dy * dy + dz * dz + dw * dw;
            qp[i] = cq;
        }
    }
#pragma unroll
    for (int off = 32; off > 0; off >>= 1) lsum += __shfl_down(lsum, off);
    if ((tid & 63) == 0) red[tid >> 6] = lsum;
    __syncthreads();
    if (tid == 0) {
        float t = red[0] + red[1] + red[2] + red[3];
        atomicAdd(loss, t * (1.25f / 11075584.f));
    }
}

// ---- tconv1 MFMA: q f32 (13,13,64) -> d1 bf16 (25,25,64), relu -------------
// GEMM: M-tile = 16 quads/block, K=256 (2x2 patch x 64ci), N=256 (cls*64+co).
// 4 waves x 4 N-tiles; A staged bf16 in LDS (stride 264 sh); B frag-ready in ws.
__global__ __launch_bounds__(256) void k_tconv1_m(const float* __restrict__ q,
                                                  const unsigned short* __restrict__ wB,
                                                  const float* __restrict__ bias,
                                                  unsigned short* __restrict__ d1,
                                                  int nquad) {
    __shared__ short a_lds[16 * 264];
    __shared__ short c_lds[16 * 264];
    int tid = threadIdx.x, blk = blockIdx.x;
    {   // stage A: thread t -> quad m=t>>4, 16 k's (chunk = t&15)
        int m = tid >> 4, chunk = tid & 15;
        int qg = blk * 16 + m;
        unsigned short tmp[16];
        bool have = false;
        if (qg < nquad) {
            int img = qg / 169, r = qg % 169, qm = r / 13, qw = r % 13;
            int p = chunk >> 2, ci0 = (chunk & 3) * 16;
            int sm = qm + (p >> 1), sw = qw + (p & 1);
            if (sm < 13 && sw < 13) {
                const float* src = q + (((size_t)img * 13 + sm) * 13 + sw) * 64 + ci0;
#pragma unroll
                for (int v = 0; v < 16; ++v) tmp[v] = f2bf(src[v]);
                have = true;
            }
        }
        if (!have) {
#pragma unroll
            for (int v = 0; v < 16; ++v) tmp[v] = 0;
        }
        unsigned pk[8];
#pragma unroll
        for (int v = 0; v < 8; ++v) pk[v] = (unsigned)tmp[2 * v] | ((unsigned)tmp[2 * v + 1] << 16);
        i4v* dst = (i4v*)(a_lds + m * 264 + chunk * 16);
        dst[0] = (i4v){(int)pk[0], (int)pk[1], (int)pk[2], (int)pk[3]};
        dst[1] = (i4v){(int)pk[4], (int)pk[5], (int)pk[6], (int)pk[7]};
    }
    __syncthreads();
    int wave = tid >> 6, lane = tid & 63;
    f4v acc[4];
#pragma unroll
    for (int i = 0; i < 4; ++i) acc[i] = (f4v){0.f, 0.f, 0.f, 0.f};
    float bv[4];
#pragma unroll
    for (int i = 0; i < 4; ++i) bv[i] = bias[((wave * 4 + i) * 16 + (lane & 15)) & 63];
    int arow = (lane & 15) * 264 + (lane >> 4) * 8;
#pragma unroll
    for (int kc = 0; kc < 8; ++kc) {
        s8v a = *(const s8v*)(a_lds + arow + kc * 32);
#pragma unroll
        for (int i = 0; i < 4; ++i) {
            int nt = wave * 4 + i;
            s8v b = *(const s8v*)((const short*)wB + ((size_t)((nt * 8 + kc) * 64 + lane)) * 8);
            acc[i] = __builtin_amdgcn_mfma_f32_16x16x32_bf16(a, b, acc[i], 0, 0, 0);
        }
    }
    // C (col n = lane&15, row m = (lane>>4)*4+reg) -> LDS, +bias, relu, bf16
#pragma unroll
    for (int i = 0; i < 4; ++i) {
        int n = (wave * 4 + i) * 16 + (lane & 15);
#pragma unroll
        for (int r2 = 0; r2 < 4; ++r2) {
            int m = (lane >> 4) * 4 + r2;
            float v = fmaxf(acc[i][r2] + bv[i], 0.f);
            c_lds[m * 264 + n] = (short)f2bf(v);
        }
    }
    __syncthreads();
    // coalesced store: 512 chunks of 8 co; skip invalid subpixels/quads
#pragma unroll
    for (int ch2 = 0; ch2 < 2; ++ch2) {
        int ch = tid + ch2 * 256;
        int m = ch >> 5, cpart = ch & 31;
        int qg = blk * 16 + m;
        if (qg >= nquad) continue;
        int img = qg / 169, r = qg % 169, qm = r / 13, qw = r % 13;
        int cls = cpart >> 3, co8 = (cpart & 7) * 8;
        int oh = 2 * qm + (cls >> 1), ow = 2 * qw + (cls & 1);
        if (oh >= 25 || ow >= 25) continue;
        i4v val = *(i4v*)(c_lds + m * 264 + cls * 64 + co8);
        *(i4v*)(d1 + (((size_t)img * 25 + oh) * 25 + ow) * 64 + co8) = val;
    }
}

// ---- tconv2 MFMA: d1 bf16 (25,25,64) -> d2 bf16 (50,50,32), relu -----------
// M-tile 16 quads, K=256, N=128 (cls*32+co). 4 waves x 2 N-tiles.
__global__ __launch_bounds__(256) void k_tconv2_m(const unsigned short* __restrict__ d1,
                                                  const unsigned short* __restrict__ wB,
                                                  const float* __restrict__ bias,
                                                  unsigned short* __restrict__ d2,
                                                  int nquad) {
    __shared__ short a_lds[16 * 264];
    __shared__ short c_lds[16 * 136];
    int tid = threadIdx.x, blk = blockIdx.x;
    {
        int m = tid >> 4, chunk = tid & 15;
        int qg = blk * 16 + m;
        i4v v0 = (i4v){0, 0, 0, 0}, v1 = v0;
        if (qg < nquad) {
            int img = qg / 625, r = qg % 625, qm = r / 25, qw = r % 25;
            int p = chunk >> 2, ci0 = (chunk & 3) * 16;
            int sm = qm + (p >> 1), sw = qw + (p & 1);
            if (sm < 25 && sw < 25) {
                const i4v* src = (const i4v*)(d1 + (((size_t)img * 25 + sm) * 25 + sw) * 64 + ci0);
                v0 = src[0]; v1 = src[1];
            }
        }
        i4v* dst = (i4v*)(a_lds + m * 264 + chunk * 16);
        dst[0] = v0; dst[1] = v1;
    }
    __syncthreads();
    int wave = tid >> 6, lane = tid & 63;
    f4v acc[2];
    acc[0] = (f4v){0.f, 0.f, 0.f, 0.f};
    acc[1] = acc[0];
    float bv[2];
#pragma unroll
    for (int i = 0; i < 2; ++i) bv[i] = bias[((wave * 2 + i) * 16 + (lane & 15)) & 31];
    int arow = (lane & 15) * 264 + (lane >> 4) * 8;
#pragma unroll
    for (int kc = 0; kc < 8; ++kc) {
        s8v a = *(const s8v*)(a_lds + arow + kc * 32);
#pragma unroll
        for (int i = 0; i < 2; ++i) {
            int nt = wave * 2 + i;
            s8v b = *(const s8v*)((const short*)wB + ((size_t)((nt * 8 + kc) * 64 + lane)) * 8);
            acc[i] = __builtin_amdgcn_mfma_f32_16x16x32_bf16(a, b, acc[i], 0, 0, 0);
        }
    }
#pragma unroll
    for (int i = 0; i < 2; ++i) {
        int n = (wave * 2 + i) * 16 + (lane & 15);
#pragma unroll
        for (int r2 = 0; r2 < 4; ++r2) {
            int m = (lane >> 4) * 4 + r2;
            float v = fmaxf(acc[i][r2] + bv[i], 0.f);
            c_lds[m * 136 + n] = (short)f2bf(v);
        }
    }
    __syncthreads();
    {   // 256 chunks: m(16) x cpart(16); all subpixels valid for op=1
        int m = tid >> 4, cpart = tid & 15;
        int qg = blk * 16 + m;
        if (qg < nquad) {
            int img = qg / 625, r = qg % 625, qm = r / 25, qw = r % 25;
            int cls = cpart >> 2, co8 = (cpart & 3) * 8;
            int oh = 2 * qm + (cls >> 1), ow = 2 * qw + (cls & 1);
            i4v val = *(i4v*)(c_lds + m * 136 + cls * 32 + co8);
            *(i4v*)(d2 + (((size_t)img * 50 + oh) * 50 + ow) * 32 + co8) = val;
        }
    }
}

// ---- convf: d2 bf16 (bc,50,50,32) -> out f32 (bc,50,50), sigmoid -----------
__global__ __launch_bounds__(256) void k_convf(const unsigned short* __restrict__ in,
                                               const float* __restrict__ w,  // dw3 (1,32,3,3)
                                               const float* __restrict__ b,
                                               float* __restrict__ out, int total) {
    __shared__ float wl[288];  // [tap9][ci32]
    int tid = threadIdx.x;
    for (int t = tid; t < 288; t += 256) {
        int tap = t >> 5, ci = t & 31;
        wl[t] = w[ci * 9 + tap];
    }
    __syncthreads();
    int pix = blockIdx.x * 256 + tid;
    if (pix >= total) return;
    int n = pix / 2500, p = pix % 2500, oh = p / 50, ow = p % 50;
    float acc = b[0];
#pragma unroll
    for (int kh = 0; kh < 3; ++kh) {
        int ih = oh - 1 + kh;
        if ((unsigned)ih >= 50u) continue;
#pragma unroll
        for (int kw = 0; kw < 3; ++kw) {
            int iw = ow - 1 + kw;
            if ((unsigned)iw >= 50u) continue;
            const float* wt = wl + (kh * 3 + kw) * 32;
            const i4v* ip4 = (const i4v*)(in + (((size_t)n * 50 + ih) * 50 + iw) * 32);
#pragma unroll
            for (int c8 = 0; c8 < 4; ++c8) {
                i4v u = ip4[c8];
#pragma unroll
                for (int e = 0; e < 4; ++e) {
                    unsigned uu = (unsigned)u[e];
                    float x0 = __builtin_bit_cast(float, uu << 16);
                    float x1 = __builtin_bit_cast(float, uu & 0xffff0000u);
                    acc = fmaf(x0, wt[c8 * 8 + e * 2], acc);
                    acc = fmaf(x1, wt[c8 * 8 + e * 2 + 1], acc);
                }
            }
        }
    }
    out[pix] = 1.f / (1.f + expf(-acc));
}

extern "C" void kernel_launch(void* const* d_in, const int* in_sizes, int n_in,
                              void* d_out, int out_size, void* d_ws, size_t ws_size,
                              hipStream_t stream) {
    const float* x   = (const float*)d_in[0];
    const float* ew1 = (const float*)d_in[1];
    const float* eb1 = (const float*)d_in[2];
    const float* ew2 = (const float*)d_in[3];
    const float* eb2 = (const float*)d_in[4];
    const float* ew3 = (const float*)d_in[5];
    const float* eb3 = (const float*)d_in[6];
    const float* cb  = (const float*)d_in[7];
    const float* dw1 = (const float*)d_in[8];
    const float* db1 = (const float*)d_in[9];
    const float* dw2 = (const float*)d_in[10];
    const float* db2 = (const float*)d_in[11];
    const float* dw3 = (const float*)d_in[12];
    const float* db3 = (const float*)d_in[13];
    float* out = (float*)d_out;
    float* loss = out + 2560000;

    float* ws   = (float*)d_ws;
    float* w2m  = ws;                      // 18432 f
    float* w3t  = ws + 18432;              // 4096 f
    float* cn   = ws + 22528;              // 512 f
    unsigned short* wB1 = (unsigned short*)(ws + 23040);  // 65536 sh = 32768 f
    unsigned short* wB2 = (unsigned short*)(ws + 55808);  // 32768 sh = 16384 f
    const size_t tw_floats = 72192;

    const int B = 1024;
    // per image (floats): regA = max(h2 10816, q 10816, d2-bf16 40000) = 40000
    //                     regB = max(h1 20000, z 10816, d1-bf16 20000) = 20000
    const size_t A_per = 40000, B_per = 20000, V_per = 676;
    size_t avail = (ws_size / 4 > tw_floats) ? ws_size / 4 - tw_floats : 0;
    int BC = (int)(avail / (A_per + B_per + V_per));
    if (BC > B) BC = B;
    if (BC < 1) BC = 1;
    float* regA  = ws + tw_floats;
    float* regB  = regA + (size_t)BC * A_per;
    float* bestd = regB + (size_t)BC * B_per;
    int*   bestk = (int*)(bestd + (size_t)2 * BC * 169);

    k_zero<<<1, 64, 0, stream>>>(loss);
    k_prep_w2m<<<72, 256, 0, stream>>>(ew2, w2m);
    k_prep_w3t<<<16, 256, 0, stream>>>(ew3, w3t);
    k_prep_cn <<<2, 256, 0, stream>>>(cb, cn);
    k_prep_B1 <<<256, 256, 0, stream>>>(dw1, wB1);
    k_prep_B2 <<<128, 256, 0, stream>>>(dw2, wB2);

    for (int n0 = 0; n0 < B; n0 += BC) {
        int bc = (B - n0 < BC) ? (B - n0) : BC;
        const float* xch = x + (size_t)n0 * 2500;

        int t1 = bc * 625;   // conv1: x -> h1 (regB)
        k_conv1<<<(t1 + 255) / 256, 256, 0, stream>>>(xch, ew1, eb1, regB, t1);

        int npix = bc * 169;
        k_conv2<<<(npix + 255) / 256, 256, 0, stream>>>(regB, w2m, eb2, regA, npix);
        k_conv3<<<(npix + 255) / 256, 256, 0, stream>>>(regA, w3t, eb3, regB, npix);

        dim3 gv((npix + 255) / 256, 2);
        k_vq_slice<<<gv, 256, 0, stream>>>(regB, cb, cn, bestd, bestk, npix);
        k_vq_merge<<<(npix + 255) / 256, 256, 0, stream>>>(regB, cb, bestd, bestk, regA, loss, npix);

        // tconv1 MFMA: q (regA f32) -> d1 (regB bf16)
        unsigned short* d1 = (unsigned short*)regB;
        k_tconv1_m<<<(npix + 15) / 16, 256, 0, stream>>>(regA, wB1, db1, d1, npix);

        // tconv2 MFMA: d1 (regB bf16) -> d2 (regA bf16)
        int nq2 = bc * 625;
        unsigned short* d2 = (unsigned short*)regA;
        k_tconv2_m<<<(nq2 + 15) / 16, 256, 0, stream>>>(d1, wB2, db2, d2, nq2);

        int t6 = bc * 2500;  // convf: d2 bf16 -> out
        k_convf<<<(t6 + 255) / 256, 256, 0, stream>>>(d2, dw3, db3, out + (size_t)n0 * 2500, t6);
    }
}

// Round 7
// 1249.304 us; speedup vs baseline: 2.8725x; 1.0940x over previous
//
#include <hip/hip_runtime.h>
#include <math.h>

// ---------------------------------------------------------------------------
// VQ-VAE forward. Encoder+VQ fp32 (bit-stable argmin); decoder tconvs as
// bf16 MFMA implicit GEMM. R7: conv2 rewritten line-consuming (per tap, each
// lane loads its pixel's full 32-ch vector = one 128-B line, fully used).
//  x (1024,1,50,50)
//  conv1 k3s2p1+relu -> h1 (n,25,25,32) f32   [regB]
//  conv2 k3s2p1+relu -> h2 (n,13,13,64) f32   [regA]
//  conv3 1x1         -> z  (n,13,13,64) f32   [regB]
//  VQ 512x64 (slice+merge) -> q f32           [regA] + loss atomic
//  tconv1 MFMA: q -> d1 (n,25,25,64) bf16     [regB]
//  tconv2 MFMA: d1 -> d2 (n,50,50,32) bf16    [regA]
//  convf k3s1p1+sigm (bf16 in, fp32 math) -> out (n,50,50)
// ---------------------------------------------------------------------------

typedef __attribute__((ext_vector_type(8))) short s8v;   // 8 bf16 frag
typedef __attribute__((ext_vector_type(4))) float f4v;   // MFMA acc
typedef __attribute__((ext_vector_type(4))) int i4v;

__device__ inline unsigned short f2bf(float f) {  // RNE fp32->bf16
    unsigned u = __builtin_bit_cast(unsigned, f);
    return (unsigned short)((u + 0x7fffu + ((u >> 16) & 1u)) >> 16);
}

__global__ __launch_bounds__(64) void k_zero(float* __restrict__ p) {
    if (threadIdx.x == 0 && blockIdx.x == 0) *p = 0.f;
}

// ---- weight preps ----------------------------------------------------------
// w2n: [tap9][ci32][co64] <- ew2[co][ci][tap]
__global__ __launch_bounds__(256) void k_prep_w2n(const float* __restrict__ w,
                                                  float* __restrict__ o) {
    int i = blockIdx.x * 256 + threadIdx.x;  // 18432
    int co = i & 63, ci = (i >> 6) & 31, tap = i >> 11;
    o[i] = w[(co * 32 + ci) * 9 + tap];
}
// w3t: [ci64][co64] <- ew3[co][ci]
__global__ __launch_bounds__(256) void k_prep_w3t(const float* __restrict__ w,
                                                  float* __restrict__ o) {
    int i = blockIdx.x * 256 + threadIdx.x;  // 4096
    int co = i & 63, ci = i >> 6;
    o[i] = w[co * 64 + ci];
}
// cn[k] = ||cb[k]||^2
__global__ __launch_bounds__(256) void k_prep_cn(const float* __restrict__ cb,
                                                 float* __restrict__ cn) {
    int k = blockIdx.x * 256 + threadIdx.x;  // 512
    const float* r = cb + k * 64;
    float s = 0.f;
#pragma unroll
    for (int c = 0; c < 64; ++c) s += r[c] * r[c];
    cn[k] = s;
}
// Zero-padded tconv weight matrices, MFMA-B-fragment-ready bf16 layout:
// element (nt, kc, lane, j) = B[k = kc*32+(lane>>4)*8+j][n = nt*16+(lane&15)]
__global__ __launch_bounds__(256) void k_prep_B1(const float* __restrict__ w,  // dw1 (64,64,3,3)
                                                 unsigned short* __restrict__ o) {
    int i = blockIdx.x * 256 + threadIdx.x;  // 65536
    int j = i & 7, l = (i >> 3) & 63, kc = (i >> 9) & 7, nt = i >> 12;
    int n = nt * 16 + (l & 15), k = kc * 32 + (l >> 4) * 8 + j;
    int cls = n >> 6, co = n & 63, p = k >> 6, ci = k & 63;
    int jh = -1, jw = -1;
    if (cls == 0)      { if (p == 0) { jh = 1; jw = 1; } }
    else if (cls == 1) { if (p == 1) { jh = 1; jw = 0; } else if (p == 0) { jh = 1; jw = 2; } }
    else if (cls == 2) { if (p == 2) { jh = 0; jw = 1; } else if (p == 0) { jh = 2; jw = 1; } }
    else { if (p == 3) { jh = 0; jw = 0; } else if (p == 2) { jh = 0; jw = 2; }
           else if (p == 1) { jh = 2; jw = 0; } else { jh = 2; jw = 2; } }
    float v = (jh >= 0) ? w[((co * 64 + ci) * 3 + jh) * 3 + jw] : 0.f;
    o[i] = f2bf(v);
}
__global__ __launch_bounds__(256) void k_prep_B2(const float* __restrict__ w,  // dw2 (32,64,3,3)
                                                 unsigned short* __restrict__ o) {
    int i = blockIdx.x * 256 + threadIdx.x;  // 32768
    int j = i & 7, l = (i >> 3) & 63, kc = (i >> 9) & 7, nt = i >> 12;
    int n = nt * 16 + (l & 15), k = kc * 32 + (l >> 4) * 8 + j;
    int cls = n >> 5, co = n & 31, p = k >> 6, ci = k & 63;
    int jh = -1, jw = -1;
    if (cls == 0)      { if (p == 0) { jh = 1; jw = 1; } }
    else if (cls == 1) { if (p == 1) { jh = 1; jw = 0; } else if (p == 0) { jh = 1; jw = 2; } }
    else if (cls == 2) { if (p == 2) { jh = 0; jw = 1; } else if (p == 0) { jh = 2; jw = 1; } }
    else { if (p == 3) { jh = 0; jw = 0; } else if (p == 2) { jh = 0; jw = 2; }
           else if (p == 1) { jh = 2; jw = 0; } else { jh = 2; jw = 2; } }
    float v = (jh >= 0) ? w[((co * 64 + ci) * 3 + jh) * 3 + jw] : 0.f;
    o[i] = f2bf(v);
}

// ---- conv1: x (bc,50,50) -> h1 (bc,25,25,32) f32, relu ---------------------
__global__ __launch_bounds__(256) void k_conv1(const float* __restrict__ x,
                                               const float* __restrict__ w,
                                               const float* __restrict__ b,
                                               float* __restrict__ h1, int total) {
    __shared__ float4 wl4[72];
    float* wl = (float*)wl4;
    int tid = threadIdx.x;
    for (int t = tid; t < 288; t += 256) {
        int tap = t >> 5, co = t & 31;
        wl[t] = w[co * 9 + tap];
    }
    __syncthreads();
    int pix = blockIdx.x * 256 + tid;
    if (pix >= total) return;
    int n = pix / 625, p = pix % 625, oh = p / 25, ow = p % 25;
    const float* xp = x + (size_t)n * 2500;
    float4 a[8];
#pragma unroll
    for (int j = 0; j < 8; ++j) a[j] = ((const float4*)b)[j];
#pragma unroll
    for (int kh = 0; kh < 3; ++kh) {
        int ih = 2 * oh - 1 + kh;
        if ((unsigned)ih >= 50u) continue;
#pragma unroll
        for (int kw = 0; kw < 3; ++kw) {
            int iw = 2 * ow - 1 + kw;
            if ((unsigned)iw >= 50u) continue;
            float v = xp[ih * 50 + iw];
            int tap = kh * 3 + kw;
#pragma unroll
            for (int j = 0; j < 8; ++j) {
                float4 ww = wl4[tap * 8 + j];
                a[j].x += v * ww.x; a[j].y += v * ww.y;
                a[j].z += v * ww.z; a[j].w += v * ww.w;
            }
        }
    }
    float4* op = (float4*)(h1 + (size_t)pix * 32);
#pragma unroll
    for (int j = 0; j < 8; ++j) {
        float4 r;
        r.x = fmaxf(a[j].x, 0.f); r.y = fmaxf(a[j].y, 0.f);
        r.z = fmaxf(a[j].z, 0.f); r.w = fmaxf(a[j].w, 0.f);
        op[j] = r;
    }
}

// ---- conv2: h1 -> h2 (bc,13,13,64) f32, relu. Tap-outer, line-consuming ----
// Per tap each lane loads its pixel's full 32-ch vector (one 128-B line,
// fully used), then 32ci x 64co FMA block with s_load weight stream.
__global__ __launch_bounds__(256, 3) void k_conv2(const float* __restrict__ h1,
                                                  const float* __restrict__ w2n,
                                                  const float* __restrict__ b,
                                                  float* __restrict__ h2, int npix) {
    int pix = blockIdx.x * 256 + threadIdx.x;
    if (pix >= npix) return;
    int n = pix / 169, p = pix % 169, oh = p / 13, ow = p % 13;
    float acc[64];
#pragma unroll
    for (int co = 0; co < 64; ++co) acc[co] = b[co];
    const float4 zero = {0.f, 0.f, 0.f, 0.f};
    auto ldtap = [&](float4* dst, int tap) {
        int kh = tap / 3, kw = tap % 3;
        int ih = 2 * oh - 1 + kh, iw = 2 * ow - 1 + kw;
        bool ok = ((unsigned)ih < 25u) && ((unsigned)iw < 25u);
        const float4* ip = (const float4*)(h1 + (((size_t)n * 25 + ih) * 25 + iw) * 32);
#pragma unroll
        for (int c4 = 0; c4 < 8; ++c4) dst[c4] = ok ? ip[c4] : zero;
    };
    float4 cur[8], nxt[8];
    ldtap(cur, 0);
#pragma unroll 1
    for (int tap = 0; tap < 9; ++tap) {
        if (tap < 8) ldtap(nxt, tap + 1);  // prefetch next tap's line
        const float* wp0 = w2n + tap * 2048;
#pragma unroll
        for (int c4 = 0; c4 < 8; ++c4) {
#pragma unroll
            for (int e = 0; e < 4; ++e) {
                float vj = (e == 0) ? cur[c4].x : (e == 1) ? cur[c4].y : (e == 2) ? cur[c4].z : cur[c4].w;
                const float* wp = wp0 + (c4 * 4 + e) * 64;
#pragma unroll
                for (int co = 0; co < 64; ++co) acc[co] = fmaf(vj, wp[co], acc[co]);
            }
        }
        if (tap < 8) {
#pragma unroll
            for (int i = 0; i < 8; ++i) cur[i] = nxt[i];
        }
    }
    float* op = h2 + (size_t)pix * 64;
#pragma unroll
    for (int c4 = 0; c4 < 16; ++c4) {
        float4 r = {fmaxf(acc[c4 * 4], 0.f), fmaxf(acc[c4 * 4 + 1], 0.f),
                    fmaxf(acc[c4 * 4 + 2], 0.f), fmaxf(acc[c4 * 4 + 3], 0.f)};
        *(float4*)(op + c4 * 4) = r;
    }
}

// ---- conv3 1x1: h2 -> z f32 ------------------------------------------------
__global__ __launch_bounds__(256, 3) void k_conv3(const float* __restrict__ h2,
                                                  const float* __restrict__ w3t,
                                                  const float* __restrict__ b,
                                                  float* __restrict__ z, int npix) {
    int pix = blockIdx.x * 256 + threadIdx.x;
    if (pix >= npix) return;
    float acc[64];
#pragma unroll
    for (int co = 0; co < 64; ++co) acc[co] = b[co];
    const float4* zp = (const float4*)(h2 + (size_t)pix * 64);
    float4 v = zp[0];
#pragma unroll 1
    for (int cc = 0; cc < 16; ++cc) {
        float4 vn;
        if (cc < 15) vn = zp[cc + 1];
#pragma unroll
        for (int j = 0; j < 4; ++j) {
            float vj = (j == 0) ? v.x : (j == 1) ? v.y : (j == 2) ? v.z : v.w;
            const float* wp = w3t + (cc * 4 + j) * 64;
#pragma unroll
            for (int co = 0; co < 64; ++co) acc[co] = fmaf(vj, wp[co], acc[co]);
        }
        if (cc < 15) v = vn;
    }
    float* op = z + (size_t)pix * 64;
#pragma unroll
    for (int c4 = 0; c4 < 16; ++c4) {
        float4 r = {acc[c4 * 4], acc[c4 * 4 + 1], acc[c4 * 4 + 2], acc[c4 * 4 + 3]};
        *(float4*)(op + c4 * 4) = r;
    }
}

// ---- VQ slice + merge (fp32, exact argmin semantics) -----------------------
__global__ __launch_bounds__(256, 3) void k_vq_slice(const float* __restrict__ z,
                                                     const float* __restrict__ cb,
                                                     const float* __restrict__ cn,
                                                     float* __restrict__ bestd,
                                                     int* __restrict__ bestk, int npix) {
    int pix = blockIdx.x * 256 + threadIdx.x;
    if (pix >= npix) return;
    int k0 = blockIdx.y * 256;
    float4 z4[16];
    const float4* zp = (const float4*)(z + (size_t)pix * 64);
#pragma unroll
    for (int i = 0; i < 16; ++i) z4[i] = zp[i];
    const float4* cb4 = (const float4*)cb + (size_t)k0 * 16;
    const float* cns = cn + k0;
    float best = 3.4e38f;
    int bk = k0;
    for (int k = 0; k < 256; ++k) {
        const float4* cr = cb4 + k * 16;
        float s0 = 0.f, s1 = 0.f;
#pragma unroll
        for (int i = 0; i < 16; i += 2) {
            float4 a = z4[i], b0 = cr[i];
            float4 c = z4[i + 1], d = cr[i + 1];
            s0 += a.x * b0.x + a.y * b0.y + a.z * b0.z + a.w * b0.w;
            s1 += c.x * d.x + c.y * d.y + c.z * d.z + c.w * d.w;
        }
        float dd = cns[k] - 2.f * (s0 + s1);
        if (dd < best) { best = dd; bk = k0 + k; }
    }
    bestd[(size_t)blockIdx.y * npix + pix] = best;
    bestk[(size_t)blockIdx.y * npix + pix] = bk;
}

__global__ __launch_bounds__(256) void k_vq_merge(const float* __restrict__ z,
                                                  const float* __restrict__ cb,
                                                  const float* __restrict__ bestd,
                                                  const int* __restrict__ bestk,
                                                  float* __restrict__ q,
                                                  float* __restrict__ loss, int npix) {
    __shared__ float red[4];
    int tid = threadIdx.x;
    int pix = blockIdx.x * 256 + tid;
    bool active = pix < npix;
    float lsum = 0.f;
    if (active) {
        float d0 = bestd[pix], d1 = bestd[(size_t)npix + pix];
        int kk0 = bestk[pix], kk1 = bestk[(size_t)npix + pix];
        int bk = (d1 < d0) ? kk1 : kk0;
        const float4* cb4 = (const float4*)cb;
        const float4* zp = (const float4*)(z + (size_t)pix * 64);
        float4* qp = (float4*)(q + (size_t)pix * 64);
#pragma unroll
        for (int i = 0; i < 16; ++i) {
            float4 cq = cb4[bk * 16 + i];
            float4 zz = zp[i];
            float dx = cq.x - zz.x, dy = cq.y - zz.y, dz = cq.z - zz.z, dw = cq.w - zz.w;
            lsum += dx * dx + dy * dy + dz * dz + dw * dw;
            qp[i] = cq;
        }
    }
#pragma unroll
    for (int off = 32; off > 0; off >>= 1) lsum += __shfl_down(lsum, off);
    if ((tid & 63) == 0) red[tid >> 6] = lsum;
    __syncthreads();
    if (tid == 0) {
        float t = red[0] + red[1] + red[2] + red[3];
        atomicAdd(loss, t * (1.25f / 11075584.f));
    }
}

// ---- tconv1 MFMA: q f32 (13,13,64) -> d1 bf16 (25,25,64), relu -------------
__global__ __launch_bounds__(256) void k_tconv1_m(const float* __restrict__ q,
                                                  const unsigned short* __restrict__ wB,
                                                  const float* __restrict__ bias,
                                                  unsigned short* __restrict__ d1,
                                                  int nquad) {
    __shared__ short a_lds[16 * 264];
    __shared__ short c_lds[16 * 264];
    int tid = threadIdx.x, blk = blockIdx.x;
    {
        int m = tid >> 4, chunk = tid & 15;
        int qg = blk * 16 + m;
        unsigned short tmp[16];
        bool have = false;
        if (qg < nquad) {
            int img = qg / 169, r = qg % 169, qm = r / 13, qw = r % 13;
            int p = chunk >> 2, ci0 = (chunk & 3) * 16;
            int sm = qm + (p >> 1), sw = qw + (p & 1);
            if (sm < 13 && sw < 13) {
                const float* src = q + (((size_t)img * 13 + sm) * 13 + sw) * 64 + ci0;
#pragma unroll
                for (int v = 0; v < 16; ++v) tmp[v] = f2bf(src[v]);
                have = true;
            }
        }
        if (!have) {
#pragma unroll
            for (int v = 0; v < 16; ++v) tmp[v] = 0;
        }
        unsigned pk[8];
#pragma unroll
        for (int v = 0; v < 8; ++v) pk[v] = (unsigned)tmp[2 * v] | ((unsigned)tmp[2 * v + 1] << 16);
        i4v* dst = (i4v*)(a_lds + m * 264 + chunk * 16);
        dst[0] = (i4v){(int)pk[0], (int)pk[1], (int)pk[2], (int)pk[3]};
        dst[1] = (i4v){(int)pk[4], (int)pk[5], (int)pk[6], (int)pk[7]};
    }
    __syncthreads();
    int wave = tid >> 6, lane = tid & 63;
    f4v acc[4];
#pragma unroll
    for (int i = 0; i < 4; ++i) acc[i] = (f4v){0.f, 0.f, 0.f, 0.f};
    float bv[4];
#pragma unroll
    for (int i = 0; i < 4; ++i) bv[i] = bias[((wave * 4 + i) * 16 + (lane & 15)) & 63];
    int arow = (lane & 15) * 264 + (lane >> 4) * 8;
#pragma unroll
    for (int kc = 0; kc < 8; ++kc) {
        s8v a = *(const s8v*)(a_lds + arow + kc * 32);
#pragma unroll
        for (int i = 0; i < 4; ++i) {
            int nt = wave * 4 + i;
            s8v b = *(const s8v*)((const short*)wB + ((size_t)((nt * 8 + kc) * 64 + lane)) * 8);
            acc[i] = __builtin_amdgcn_mfma_f32_16x16x32_bf16(a, b, acc[i], 0, 0, 0);
        }
    }
#pragma unroll
    for (int i = 0; i < 4; ++i) {
        int n = (wave * 4 + i) * 16 + (lane & 15);
#pragma unroll
        for (int r2 = 0; r2 < 4; ++r2) {
            int m = (lane >> 4) * 4 + r2;
            float v = fmaxf(acc[i][r2] + bv[i], 0.f);
            c_lds[m * 264 + n] = (short)f2bf(v);
        }
    }
    __syncthreads();
#pragma unroll
    for (int ch2 = 0; ch2 < 2; ++ch2) {
        int ch = tid + ch2 * 256;
        int m = ch >> 5, cpart = ch & 31;
        int qg = blk * 16 + m;
        if (qg >= nquad) continue;
        int img = qg / 169, r = qg % 169, qm = r / 13, qw = r % 13;
        int cls = cpart >> 3, co8 = (cpart & 7) * 8;
        int oh = 2 * qm + (cls >> 1), ow = 2 * qw + (cls & 1);
        if (oh >= 25 || ow >= 25) continue;
        i4v val = *(i4v*)(c_lds + m * 264 + cls * 64 + co8);
        *(i4v*)(d1 + (((size_t)img * 25 + oh) * 25 + ow) * 64 + co8) = val;
    }
}

// ---- tconv2 MFMA: d1 bf16 (25,25,64) -> d2 bf16 (50,50,32), relu -----------
__global__ __launch_bounds__(256) void k_tconv2_m(const unsigned short* __restrict__ d1,
                                                  const unsigned short* __restrict__ wB,
                                                  const float* __restrict__ bias,
                                                  unsigned short* __restrict__ d2,
                                                  int nquad) {
    __shared__ short a_lds[16 * 264];
    __shared__ short c_lds[16 * 136];
    int tid = threadIdx.x, blk = blockIdx.x;
    {
        int m = tid >> 4, chunk = tid & 15;
        int qg = blk * 16 + m;
        i4v v0 = (i4v){0, 0, 0, 0}, v1 = v0;
        if (qg < nquad) {
            int img = qg / 625, r = qg % 625, qm = r / 25, qw = r % 25;
            int p = chunk >> 2, ci0 = (chunk & 3) * 16;
            int sm = qm + (p >> 1), sw = qw + (p & 1);
            if (sm < 25 && sw < 25) {
                const i4v* src = (const i4v*)(d1 + (((size_t)img * 25 + sm) * 25 + sw) * 64 + ci0);
                v0 = src[0]; v1 = src[1];
            }
        }
        i4v* dst = (i4v*)(a_lds + m * 264 + chunk * 16);
        dst[0] = v0; dst[1] = v1;
    }
    __syncthreads();
    int wave = tid >> 6, lane = tid & 63;
    f4v acc[2];
    acc[0] = (f4v){0.f, 0.f, 0.f, 0.f};
    acc[1] = acc[0];
    float bv[2];
#pragma unroll
    for (int i = 0; i < 2; ++i) bv[i] = bias[((wave * 2 + i) * 16 + (lane & 15)) & 31];
    int arow = (lane & 15) * 264 + (lane >> 4) * 8;
#pragma unroll
    for (int kc = 0; kc < 8; ++kc) {
        s8v a = *(const s8v*)(a_lds + arow + kc * 32);
#pragma unroll
        for (int i = 0; i < 2; ++i) {
            int nt = wave * 2 + i;
            s8v b = *(const s8v*)((const short*)wB + ((size_t)((nt * 8 + kc) * 64 + lane)) * 8);
            acc[i] = __builtin_amdgcn_mfma_f32_16x16x32_bf16(a, b, acc[i], 0, 0, 0);
        }
    }
#pragma unroll
    for (int i = 0; i < 2; ++i) {
        int n = (wave * 2 + i) * 16 + (lane & 15);
#pragma unroll
        for (int r2 = 0; r2 < 4; ++r2) {
            int m = (lane >> 4) * 4 + r2;
            float v = fmaxf(acc[i][r2] + bv[i], 0.f);
            c_lds[m * 136 + n] = (short)f2bf(v);
        }
    }
    __syncthreads();
    {
        int m = tid >> 4, cpart = tid & 15;
        int qg = blk * 16 + m;
        if (qg < nquad) {
            int img = qg / 625, r = qg % 625, qm = r / 25, qw = r % 25;
            int cls = cpart >> 2, co8 = (cpart & 3) * 8;
            int oh = 2 * qm + (cls >> 1), ow = 2 * qw + (cls & 1);
            i4v val = *(i4v*)(c_lds + m * 136 + cls * 32 + co8);
            *(i4v*)(d2 + (((size_t)img * 50 + oh) * 50 + ow) * 32 + co8) = val;
        }
    }
}

// ---- convf: d2 bf16 (bc,50,50,32) -> out f32 (bc,50,50), sigmoid -----------
__global__ __launch_bounds__(256) void k_convf(const unsigned short* __restrict__ in,
                                               const float* __restrict__ w,  // dw3 (1,32,3,3)
                                               const float* __restrict__ b,
                                               float* __restrict__ out, int total) {
    __shared__ float wl[288];  // [tap9][ci32]
    int tid = threadIdx.x;
    for (int t = tid; t < 288; t += 256) {
        int tap = t >> 5, ci = t & 31;
        wl[t] = w[ci * 9 + tap];
    }
    __syncthreads();
    int pix = blockIdx.x * 256 + tid;
    if (pix >= total) return;
    int n = pix / 2500, p = pix % 2500, oh = p / 50, ow = p % 50;
    float acc = b[0];
#pragma unroll
    for (int kh = 0; kh < 3; ++kh) {
        int ih = oh - 1 + kh;
        if ((unsigned)ih >= 50u) continue;
#pragma unroll
        for (int kw = 0; kw < 3; ++kw) {
            int iw = ow - 1 + kw;
            if ((unsigned)iw >= 50u) continue;
            const float* wt = wl + (kh * 3 + kw) * 32;
            const i4v* ip4 = (const i4v*)(in + (((size_t)n * 50 + ih) * 50 + iw) * 32);
#pragma unroll
            for (int c8 = 0; c8 < 4; ++c8) {
                i4v u = ip4[c8];
#pragma unroll
                for (int e = 0; e < 4; ++e) {
                    unsigned uu = (unsigned)u[e];
                    float x0 = __builtin_bit_cast(float, uu << 16);
                    float x1 = __builtin_bit_cast(float, uu & 0xffff0000u);
                    acc = fmaf(x0, wt[c8 * 8 + e * 2], acc);
                    acc = fmaf(x1, wt[c8 * 8 + e * 2 + 1], acc);
                }
            }
        }
    }
    out[pix] = 1.f / (1.f + expf(-acc));
}

extern "C" void kernel_launch(void* const* d_in, const int* in_sizes, int n_in,
                              void* d_out, int out_size, void* d_ws, size_t ws_size,
                              hipStream_t stream) {
    const float* x   = (const float*)d_in[0];
    const float* ew1 = (const float*)d_in[1];
    const float* eb1 = (const float*)d_in[2];
    const float* ew2 = (const float*)d_in[3];
    const float* eb2 = (const float*)d_in[4];
    const float* ew3 = (const float*)d_in[5];
    const float* eb3 = (const float*)d_in[6];
    const float* cb  = (const float*)d_in[7];
    const float* dw1 = (const float*)d_in[8];
    const float* db1 = (const float*)d_in[9];
    const float* dw2 = (const float*)d_in[10];
    const float* db2 = (const float*)d_in[11];
    const float* dw3 = (const float*)d_in[12];
    const float* db3 = (const float*)d_in[13];
    float* out = (float*)d_out;
    float* loss = out + 2560000;

    float* ws   = (float*)d_ws;
    float* w2n  = ws;                      // 18432 f
    float* w3t  = ws + 18432;              // 4096 f
    float* cn   = ws + 22528;              // 512 f
    unsigned short* wB1 = (unsigned short*)(ws + 23040);  // 65536 sh
    unsigned short* wB2 = (unsigned short*)(ws + 55808);  // 32768 sh
    const size_t tw_floats = 72192;

    const int B = 1024;
    const size_t A_per = 40000, B_per = 20000, V_per = 676;
    size_t avail = (ws_size / 4 > tw_floats) ? ws_size / 4 - tw_floats : 0;
    int BC = (int)(avail / (A_per + B_per + V_per));
    if (BC > B) BC = B;
    if (BC < 1) BC = 1;
    float* regA  = ws + tw_floats;
    float* regB  = regA + (size_t)BC * A_per;
    float* bestd = regB + (size_t)BC * B_per;
    int*   bestk = (int*)(bestd + (size_t)2 * BC * 169);

    k_zero<<<1, 64, 0, stream>>>(loss);
    k_prep_w2n<<<72, 256, 0, stream>>>(ew2, w2n);
    k_prep_w3t<<<16, 256, 0, stream>>>(ew3, w3t);
    k_prep_cn <<<2, 256, 0, stream>>>(cb, cn);
    k_prep_B1 <<<256, 256, 0, stream>>>(dw1, wB1);
    k_prep_B2 <<<128, 256, 0, stream>>>(dw2, wB2);

    for (int n0 = 0; n0 < B; n0 += BC) {
        int bc = (B - n0 < BC) ? (B - n0) : BC;
        const float* xch = x + (size_t)n0 * 2500;

        int t1 = bc * 625;
        k_conv1<<<(t1 + 255) / 256, 256, 0, stream>>>(xch, ew1, eb1, regB, t1);

        int npix = bc * 169;
        k_conv2<<<(npix + 255) / 256, 256, 0, stream>>>(regB, w2n, eb2, regA, npix);
        k_conv3<<<(npix + 255) / 256, 256, 0, stream>>>(regA, w3t, eb3, regB, npix);

        dim3 gv((npix + 255) / 256, 2);
        k_vq_slice<<<gv, 256, 0, stream>>>(regB, cb, cn, bestd, bestk, npix);
        k_vq_merge<<<(npix + 255) / 256, 256, 0, stream>>>(regB, cb, bestd, bestk, regA, loss, npix);

        unsigned short* d1 = (unsigned short*)regB;
        k_tconv1_m<<<(npix + 15) / 16, 256, 0, stream>>>(regA, wB1, db1, d1, npix);

        int nq2 = bc * 625;
        unsigned short* d2 = (unsigned short*)regA;
        k_tconv2_m<<<(nq2 + 15) / 16, 256, 0, stream>>>(d1, wB2, db2, d2, nq2);

        int t6 = bc * 2500;
        k_convf<<<(t6 + 255) / 256, 256, 0, stream>>>(d2, dw3, db3, out + (size_t)n0 * 2500, t6);
    }
}

// Round 10
// 854.950 us; speedup vs baseline: 4.1975x; 1.4613x over previous
//
#include <hip/hip_runtime.h>
#include <math.h>

// ---------------------------------------------------------------------------
// VQ-VAE forward. R10 = R9 with the ping-pong region mapping FIXED:
// d2 (80000 sh/img) must land in the 40000-float region (regA).
//  conv1: x -> h1 (n,25,25,32) f32            [regA]
//  enc_m: h1 -> z (n,13,13,64) f32            [regB]  (conv2+relu+conv3, MFMA)
//  VQ: z -> q f32                             [regA]  + loss atomic
//  tconv1 MFMA: q -> d1 (n,25,25,64) bf16     [regB]  (40000 sh = exact fit)
//  tconv2 MFMA: d1 -> d2 (n,50,50,32) bf16    [regA]  (80000 sh = exact fit)
//  convf k3s1p1+sigm (bf16 in, fp32 math) -> out (n,50,50)
// ---------------------------------------------------------------------------

typedef __attribute__((ext_vector_type(8))) short s8v;   // 8 bf16 frag
typedef __attribute__((ext_vector_type(4))) float f4v;   // MFMA acc
typedef __attribute__((ext_vector_type(4))) int i4v;

__device__ inline unsigned short f2bf(float f) {  // RNE fp32->bf16
    unsigned u = __builtin_bit_cast(unsigned, f);
    return (unsigned short)((u + 0x7fffu + ((u >> 16) & 1u)) >> 16);
}
__device__ inline float bf2f(unsigned short h) {
    return __builtin_bit_cast(float, ((unsigned)h) << 16);
}

__global__ __launch_bounds__(64) void k_zero(float* __restrict__ p) {
    if (threadIdx.x == 0 && blockIdx.x == 0) *p = 0.f;
}

// ---- weight preps ----------------------------------------------------------
__global__ __launch_bounds__(256) void k_prep_cn(const float* __restrict__ cb,
                                                 float* __restrict__ cn) {
    int k = blockIdx.x * 256 + threadIdx.x;  // 512
    const float* r = cb + k * 64;
    float s = 0.f;
#pragma unroll
    for (int c = 0; c < 64; ++c) s += r[c] * r[c];
    cn[k] = s;
}
// B2n: conv2 split-bf16 B, frag layout (nt4, kc27, lane64, j8):
// k = kc*32+(lane>>4)*8+j; n = nt*16+(lane&15)=co.
// k<288: hi(w2[co][ci=k%32][tap=k/32]); k<576: lo; k<864: hi.
__global__ __launch_bounds__(256) void k_prep_B2n(const float* __restrict__ w,  // ew2 (64,32,3,3)
                                                  unsigned short* __restrict__ o) {
    int i = blockIdx.x * 256 + threadIdx.x;  // 55296
    if (i >= 55296) return;
    int j = i & 7, lane = (i >> 3) & 63;
    int kc = (i >> 9) % 27, nt = (i >> 9) / 27;
    int k = kc * 32 + ((lane >> 4) << 3) + j;
    int co = nt * 16 + (lane & 15);
    int part = (k < 288) ? 0 : (k < 576) ? 1 : 0;  // 0=hi,1=lo
    int kk = (k < 288) ? k : (k < 576) ? k - 288 : k - 576;
    int tap = kk >> 5, ci = kk & 31;
    float v = w[(co * 32 + ci) * 9 + tap];
    unsigned short hi = f2bf(v);
    o[i] = part ? f2bf(v - bf2f(hi)) : hi;
}
// B3: conv3 split-bf16 B, frag layout (nt4, kc6, lane64, j8)
__global__ __launch_bounds__(256) void k_prep_B3(const float* __restrict__ w,  // ew3 (64,64)
                                                 unsigned short* __restrict__ o) {
    int i = blockIdx.x * 256 + threadIdx.x;  // 12288
    if (i >= 12288) return;
    int j = i & 7, lane = (i >> 3) & 63;
    int kc = (i >> 9) % 6, nt = (i >> 9) / 6;
    int k = kc * 32 + ((lane >> 4) << 3) + j;
    int n = nt * 16 + (lane & 15);
    int part = (k < 64) ? 0 : (k < 128) ? 1 : 0;
    int kk = (k < 64) ? k : (k < 128) ? k - 64 : k - 128;
    float v = w[n * 64 + kk];
    unsigned short hi = f2bf(v);
    o[i] = part ? f2bf(v - bf2f(hi)) : hi;
}
// Zero-padded tconv weight matrices
__global__ __launch_bounds__(256) void k_prep_B1(const float* __restrict__ w,  // dw1 (64,64,3,3)
                                                 unsigned short* __restrict__ o) {
    int i = blockIdx.x * 256 + threadIdx.x;  // 65536
    int j = i & 7, l = (i >> 3) & 63, kc = (i >> 9) & 7, nt = i >> 12;
    int n = nt * 16 + (l & 15), k = kc * 32 + (l >> 4) * 8 + j;
    int cls = n >> 6, co = n & 63, p = k >> 6, ci = k & 63;
    int jh = -1, jw = -1;
    if (cls == 0)      { if (p == 0) { jh = 1; jw = 1; } }
    else if (cls == 1) { if (p == 1) { jh = 1; jw = 0; } else if (p == 0) { jh = 1; jw = 2; } }
    else if (cls == 2) { if (p == 2) { jh = 0; jw = 1; } else if (p == 0) { jh = 2; jw = 1; } }
    else { if (p == 3) { jh = 0; jw = 0; } else if (p == 2) { jh = 0; jw = 2; }
           else if (p == 1) { jh = 2; jw = 0; } else { jh = 2; jw = 2; } }
    float v = (jh >= 0) ? w[((co * 64 + ci) * 3 + jh) * 3 + jw] : 0.f;
    o[i] = f2bf(v);
}
__global__ __launch_bounds__(256) void k_prep_B2(const float* __restrict__ w,  // dw2 (32,64,3,3)
                                                 unsigned short* __restrict__ o) {
    int i = blockIdx.x * 256 + threadIdx.x;  // 32768
    int j = i & 7, l = (i >> 3) & 63, kc = (i >> 9) & 7, nt = i >> 12;
    int n = nt * 16 + (l & 15), k = kc * 32 + (l >> 4) * 8 + j;
    int cls = n >> 5, co = n & 31, p = k >> 6, ci = k & 63;
    int jh = -1, jw = -1;
    if (cls == 0)      { if (p == 0) { jh = 1; jw = 1; } }
    else if (cls == 1) { if (p == 1) { jh = 1; jw = 0; } else if (p == 0) { jh = 1; jw = 2; } }
    else if (cls == 2) { if (p == 2) { jh = 0; jw = 1; } else if (p == 0) { jh = 2; jw = 1; } }
    else { if (p == 3) { jh = 0; jw = 0; } else if (p == 2) { jh = 0; jw = 2; }
           else if (p == 1) { jh = 2; jw = 0; } else { jh = 2; jw = 2; } }
    float v = (jh >= 0) ? w[((co * 64 + ci) * 3 + jh) * 3 + jw] : 0.f;
    o[i] = f2bf(v);
}

// ---- conv1: x (bc,50,50) -> h1 (bc,25,25,32) f32, relu ---------------------
__global__ __launch_bounds__(256) void k_conv1(const float* __restrict__ x,
                                               const float* __restrict__ w,
                                               const float* __restrict__ b,
                                               float* __restrict__ h1, int total) {
    __shared__ float4 wl4[72];
    float* wl = (float*)wl4;
    int tid = threadIdx.x;
    for (int t = tid; t < 288; t += 256) {
        int tap = t >> 5, co = t & 31;
        wl[t] = w[co * 9 + tap];
    }
    __syncthreads();
    int pix = blockIdx.x * 256 + tid;
    if (pix >= total) return;
    int n = pix / 625, p = pix % 625, oh = p / 25, ow = p % 25;
    const float* xp = x + (size_t)n * 2500;
    float4 a[8];
#pragma unroll
    for (int j = 0; j < 8; ++j) a[j] = ((const float4*)b)[j];
#pragma unroll
    for (int kh = 0; kh < 3; ++kh) {
        int ih = 2 * oh - 1 + kh;
        if ((unsigned)ih >= 50u) continue;
#pragma unroll
        for (int kw = 0; kw < 3; ++kw) {
            int iw = 2 * ow - 1 + kw;
            if ((unsigned)iw >= 50u) continue;
            float v = xp[ih * 50 + iw];
            int tap = kh * 3 + kw;
#pragma unroll
            for (int j = 0; j < 8; ++j) {
                float4 ww = wl4[tap * 8 + j];
                a[j].x += v * ww.x; a[j].y += v * ww.y;
                a[j].z += v * ww.z; a[j].w += v * ww.w;
            }
        }
    }
    float4* op = (float4*)(h1 + (size_t)pix * 32);
#pragma unroll
    for (int j = 0; j < 8; ++j) {
        float4 r;
        r.x = fmaxf(a[j].x, 0.f); r.y = fmaxf(a[j].y, 0.f);
        r.z = fmaxf(a[j].z, 0.f); r.w = fmaxf(a[j].w, 0.f);
        op[j] = r;
    }
}

// ---- enc_m: fused conv2(k3s2p1)+relu+conv3(1x1), split-bf16 MFMA -----------
__global__ __launch_bounds__(256) void k_enc_m(const float* __restrict__ h1,
                                               const unsigned short* __restrict__ B2n,
                                               const unsigned short* __restrict__ B3,
                                               const float* __restrict__ b2,
                                               const float* __restrict__ b3,
                                               float* __restrict__ z, int npix) {
    __shared__ short a1[16 * 872];   // 27,904 B  [m][k1: 0-288 hi, 288-576 hi-dup, 576-864 lo]
    __shared__ short a2[16 * 200];   // 6,400 B   [m][k2: 0-64 hi, 64-128 hi-dup, 128-192 lo]
    __shared__ float cz[16 * 68];    // 4,352 B
    int tid = threadIdx.x, blk = blockIdx.x;
    {
        int m = tid >> 4, chunk = tid & 15;
        if (chunk < 9) {
            int pix = blk * 16 + m;
            float4 v[8];
            const float4 zero = {0.f, 0.f, 0.f, 0.f};
            bool ok = false;
            if (pix < npix) {
                int n = pix / 169, p = pix % 169, oh = p / 13, ow = p % 13;
                int kh = chunk / 3, kw = chunk % 3;
                int ih = 2 * oh - 1 + kh, iw = 2 * ow - 1 + kw;
                ok = ((unsigned)ih < 25u) && ((unsigned)iw < 25u);
                if (ok) {
                    const float4* ip = (const float4*)(h1 + (((size_t)n * 25 + ih) * 25 + iw) * 32);
#pragma unroll
                    for (int c4 = 0; c4 < 8; ++c4) v[c4] = ip[c4];
                }
            }
            if (!ok) {
#pragma unroll
                for (int c4 = 0; c4 < 8; ++c4) v[c4] = zero;
            }
            unsigned short hi[32], lo[32];
#pragma unroll
            for (int c4 = 0; c4 < 8; ++c4) {
                float vv[4] = {v[c4].x, v[c4].y, v[c4].z, v[c4].w};
#pragma unroll
                for (int e = 0; e < 4; ++e) {
                    int ci = c4 * 4 + e;
                    unsigned short h = f2bf(vv[e]);
                    hi[ci] = h;
                    lo[ci] = f2bf(vv[e] - bf2f(h));
                }
            }
            short* row = a1 + m * 872 + chunk * 32;
            i4v* d0 = (i4v*)row;             // hi
            i4v* d1 = (i4v*)(row + 288);     // hi dup
            i4v* d2 = (i4v*)(row + 576);     // lo
#pragma unroll
            for (int g = 0; g < 4; ++g) {
                i4v ph, pl;
#pragma unroll
                for (int e = 0; e < 4; ++e) {
                    int b0 = g * 8 + e * 2;
                    ph[e] = (int)((unsigned)hi[b0] | ((unsigned)hi[b0 + 1] << 16));
                    pl[e] = (int)((unsigned)lo[b0] | ((unsigned)lo[b0 + 1] << 16));
                }
                d0[g] = ph; d1[g] = ph; d2[g] = pl;
            }
        }
    }
    __syncthreads();
    int wave = tid >> 6, lane = tid & 63;
    int arow1 = (lane & 15) * 872 + (lane >> 4) * 8;
    f4v acc = (f4v){0.f, 0.f, 0.f, 0.f};
#pragma unroll
    for (int kc = 0; kc < 27; ++kc) {
        s8v a = *(const s8v*)(a1 + arow1 + kc * 32);
        s8v b = *(const s8v*)((const short*)B2n + ((size_t)((wave * 27 + kc) * 64 + lane)) * 8);
        acc = __builtin_amdgcn_mfma_f32_16x16x32_bf16(a, b, acc, 0, 0, 0);
    }
    {
        float bv = b2[wave * 16 + (lane & 15)];
        int n = wave * 16 + (lane & 15);
#pragma unroll
        for (int r = 0; r < 4; ++r) {
            int m = (lane >> 4) * 4 + r;
            float h = fmaxf(acc[r] + bv, 0.f);
            unsigned short hh = f2bf(h);
            unsigned short ll = f2bf(h - bf2f(hh));
            a2[m * 200 + n] = (short)hh;
            a2[m * 200 + 64 + n] = (short)hh;
            a2[m * 200 + 128 + n] = (short)ll;
        }
    }
    __syncthreads();
    int arow2 = (lane & 15) * 200 + (lane >> 4) * 8;
    f4v acc2 = (f4v){0.f, 0.f, 0.f, 0.f};
#pragma unroll
    for (int kc = 0; kc < 6; ++kc) {
        s8v a = *(const s8v*)(a2 + arow2 + kc * 32);
        s8v b = *(const s8v*)((const short*)B3 + ((size_t)((wave * 6 + kc) * 64 + lane)) * 8);
        acc2 = __builtin_amdgcn_mfma_f32_16x16x32_bf16(a, b, acc2, 0, 0, 0);
    }
    {
        float bv = b3[wave * 16 + (lane & 15)];
        int n = wave * 16 + (lane & 15);
#pragma unroll
        for (int r = 0; r < 4; ++r) {
            int m = (lane >> 4) * 4 + r;
            cz[m * 68 + n] = acc2[r] + bv;
        }
    }
    __syncthreads();
    {
        int m = tid >> 4, c4 = tid & 15;
        int pix = blk * 16 + m;
        if (pix < npix) {
            float4 v = *(float4*)(cz + m * 68 + c4 * 4);
            *(float4*)(z + (size_t)pix * 64 + c4 * 4) = v;
        }
    }
}

// ---- VQ slice + merge (fp32, exact argmin semantics) -----------------------
__global__ __launch_bounds__(256, 3) void k_vq_slice(const float* __restrict__ z,
                                                     const float* __restrict__ cb,
                                                     const float* __restrict__ cn,
                                                     float* __restrict__ bestd,
                                                     int* __restrict__ bestk, int npix) {
    int pix = blockIdx.x * 256 + threadIdx.x;
    if (pix >= npix) return;
    int k0 = blockIdx.y * 256;
    float4 z4[16];
    const float4* zp = (const float4*)(z + (size_t)pix * 64);
#pragma unroll
    for (int i = 0; i < 16; ++i) z4[i] = zp[i];
    const float4* cb4 = (const float4*)cb + (size_t)k0 * 16;
    const float* cns = cn + k0;
    float best = 3.4e38f;
    int bk = k0;
    for (int k = 0; k < 256; ++k) {
        const float4* cr = cb4 + k * 16;
        float s0 = 0.f, s1 = 0.f;
#pragma unroll
        for (int i = 0; i < 16; i += 2) {
            float4 a = z4[i], b0 = cr[i];
            float4 c = z4[i + 1], d = cr[i + 1];
            s0 += a.x * b0.x + a.y * b0.y + a.z * b0.z + a.w * b0.w;
            s1 += c.x * d.x + c.y * d.y + c.z * d.z + c.w * d.w;
        }
        float dd = cns[k] - 2.f * (s0 + s1);
        if (dd < best) { best = dd; bk = k0 + k; }
    }
    bestd[(size_t)blockIdx.y * npix + pix] = best;
    bestk[(size_t)blockIdx.y * npix + pix] = bk;
}

__global__ __launch_bounds__(256) void k_vq_merge(const float* __restrict__ z,
                                                  const float* __restrict__ cb,
                                                  const float* __restrict__ bestd,
                                                  const int* __restrict__ bestk,
                                                  float* __restrict__ q,
                                                  float* __restrict__ loss, int npix) {
    __shared__ float red[4];
    int tid = threadIdx.x;
    int pix = blockIdx.x * 256 + tid;
    bool active = pix < npix;
    float lsum = 0.f;
    if (active) {
        float d0 = bestd[pix], d1 = bestd[(size_t)npix + pix];
        int kk0 = bestk[pix], kk1 = bestk[(size_t)npix + pix];
        int bk = (d1 < d0) ? kk1 : kk0;
        const float4* cb4 = (const float4*)cb;
        const float4* zp = (const float4*)(z + (size_t)pix * 64);
        float4* qp = (float4*)(q + (size_t)pix * 64);
#pragma unroll
        for (int i = 0; i < 16; ++i) {
            float4 cq = cb4[bk * 16 + i];
            float4 zz = zp[i];
            float dx = cq.x - zz.x, dy = cq.y - zz.y, dz = cq.z - zz.z, dw = cq.w - zz.w;
            lsum += dx * dx + dy * dy + dz * dz + dw * dw;
            qp[i] = cq;
        }
    }
#pragma unroll
    for (int off = 32; off > 0; off >>= 1) lsum += __shfl_down(lsum, off);
    if ((tid & 63) == 0) red[tid >> 6] = lsum;
    __syncthreads();
    if (tid == 0) {
        float t = red[0] + red[1] + red[2] + red[3];
        atomicAdd(loss, t * (1.25f / 11075584.f));
    }
}

// ---- tconv1 MFMA: q f32 (13,13,64) -> d1 bf16 (25,25,64), relu -------------
__global__ __launch_bounds__(256) void k_tconv1_m(const float* __restrict__ q,
                                                  const unsigned short* __restrict__ wB,
                                                  const float* __restrict__ bias,
                                                  unsigned short* __restrict__ d1,
                                                  int nquad) {
    __shared__ short a_lds[16 * 264];
    __shared__ short c_lds[16 * 264];
    int tid = threadIdx.x, blk = blockIdx.x;
    {
        int m = tid >> 4, chunk = tid & 15;
        int qg = blk * 16 + m;
        unsigned short tmp[16];
        bool have = false;
        if (qg < nquad) {
            int img = qg / 169, r = qg % 169, qm = r / 13, qw = r % 13;
            int p = chunk >> 2, ci0 = (chunk & 3) * 16;
            int sm = qm + (p >> 1), sw = qw + (p & 1);
            if (sm < 13 && sw < 13) {
                const float* src = q + (((size_t)img * 13 + sm) * 13 + sw) * 64 + ci0;
#pragma unroll
                for (int v = 0; v < 16; ++v) tmp[v] = f2bf(src[v]);
                have = true;
            }
        }
        if (!have) {
#pragma unroll
            for (int v = 0; v < 16; ++v) tmp[v] = 0;
        }
        unsigned pk[8];
#pragma unroll
        for (int v = 0; v < 8; ++v) pk[v] = (unsigned)tmp[2 * v] | ((unsigned)tmp[2 * v + 1] << 16);
        i4v* dst = (i4v*)(a_lds + m * 264 + chunk * 16);
        dst[0] = (i4v){(int)pk[0], (int)pk[1], (int)pk[2], (int)pk[3]};
        dst[1] = (i4v){(int)pk[4], (int)pk[5], (int)pk[6], (int)pk[7]};
    }
    __syncthreads();
    int wave = tid >> 6, lane = tid & 63;
    f4v acc[4];
#pragma unroll
    for (int i = 0; i < 4; ++i) acc[i] = (f4v){0.f, 0.f, 0.f, 0.f};
    float bv[4];
#pragma unroll
    for (int i = 0; i < 4; ++i) bv[i] = bias[((wave * 4 + i) * 16 + (lane & 15)) & 63];
    int arow = (lane & 15) * 264 + (lane >> 4) * 8;
#pragma unroll
    for (int kc = 0; kc < 8; ++kc) {
        s8v a = *(const s8v*)(a_lds + arow + kc * 32);
#pragma unroll
        for (int i = 0; i < 4; ++i) {
            int nt = wave * 4 + i;
            s8v b = *(const s8v*)((const short*)wB + ((size_t)((nt * 8 + kc) * 64 + lane)) * 8);
            acc[i] = __builtin_amdgcn_mfma_f32_16x16x32_bf16(a, b, acc[i], 0, 0, 0);
        }
    }
#pragma unroll
    for (int i = 0; i < 4; ++i) {
        int n = (wave * 4 + i) * 16 + (lane & 15);
#pragma unroll
        for (int r2 = 0; r2 < 4; ++r2) {
            int m = (lane >> 4) * 4 + r2;
            float v = fmaxf(acc[i][r2] + bv[i], 0.f);
            c_lds[m * 264 + n] = (short)f2bf(v);
        }
    }
    __syncthreads();
#pragma unroll
    for (int ch2 = 0; ch2 < 2; ++ch2) {
        int ch = tid + ch2 * 256;
        int m = ch >> 5, cpart = ch & 31;
        int qg = blk * 16 + m;
        if (qg >= nquad) continue;
        int img = qg / 169, r = qg % 169, qm = r / 13, qw = r % 13;
        int cls = cpart >> 3, co8 = (cpart & 7) * 8;
        int oh = 2 * qm + (cls >> 1), ow = 2 * qw + (cls & 1);
        if (oh >= 25 || ow >= 25) continue;
        i4v val = *(i4v*)(c_lds + m * 264 + cls * 64 + co8);
        *(i4v*)(d1 + (((size_t)img * 25 + oh) * 25 + ow) * 64 + co8) = val;
    }
}

// ---- tconv2 MFMA: d1 bf16 (25,25,64) -> d2 bf16 (50,50,32), relu -----------
__global__ __launch_bounds__(256) void k_tconv2_m(const unsigned short* __restrict__ d1,
                                                  const unsigned short* __restrict__ wB,
                                                  const float* __restrict__ bias,
                                                  unsigned short* __restrict__ d2,
                                                  int nquad) {
    __shared__ short a_lds[16 * 264];
    __shared__ short c_lds[16 * 136];
    int tid = threadIdx.x, blk = blockIdx.x;
    {
        int m = tid >> 4, chunk = tid & 15;
        int qg = blk * 16 + m;
        i4v v0 = (i4v){0, 0, 0, 0}, v1 = v0;
        if (qg < nquad) {
            int img = qg / 625, r = qg % 625, qm = r / 25, qw = r % 25;
            int p = chunk >> 2, ci0 = (chunk & 3) * 16;
            int sm = qm + (p >> 1), sw = qw + (p & 1);
            if (sm < 25 && sw < 25) {
                const i4v* src = (const i4v*)(d1 + (((size_t)img * 25 + sm) * 25 + sw) * 64 + ci0);
                v0 = src[0]; v1 = src[1];
            }
        }
        i4v* dst = (i4v*)(a_lds + m * 264 + chunk * 16);
        dst[0] = v0; dst[1] = v1;
    }
    __syncthreads();
    int wave = tid >> 6, lane = tid & 63;
    f4v acc[2];
    acc[0] = (f4v){0.f, 0.f, 0.f, 0.f};
    acc[1] = acc[0];
    float bv[2];
#pragma unroll
    for (int i = 0; i < 2; ++i) bv[i] = bias[((wave * 2 + i) * 16 + (lane & 15)) & 31];
    int arow = (lane & 15) * 264 + (lane >> 4) * 8;
#pragma unroll
    for (int kc = 0; kc < 8; ++kc) {
        s8v a = *(const s8v*)(a_lds + arow + kc * 32);
#pragma unroll
        for (int i = 0; i < 2; ++i) {
            int nt = wave * 2 + i;
            s8v b = *(const s8v*)((const short*)wB + ((size_t)((nt * 8 + kc) * 64 + lane)) * 8);
            acc[i] = __builtin_amdgcn_mfma_f32_16x16x32_bf16(a, b, acc[i], 0, 0, 0);
        }
    }
#pragma unroll
    for (int i = 0; i < 2; ++i) {
        int n = (wave * 2 + i) * 16 + (lane & 15);
#pragma unroll
        for (int r2 = 0; r2 < 4; ++r2) {
            int m = (lane >> 4) * 4 + r2;
            float v = fmaxf(acc[i][r2] + bv[i], 0.f);
            c_lds[m * 136 + n] = (short)f2bf(v);
        }
    }
    __syncthreads();
    {
        int m = tid >> 4, cpart = tid & 15;
        int qg = blk * 16 + m;
        if (qg < nquad) {
            int img = qg / 625, r = qg % 625, qm = r / 25, qw = r % 25;
            int cls = cpart >> 2, co8 = (cpart & 3) * 8;
            int oh = 2 * qm + (cls >> 1), ow = 2 * qw + (cls & 1);
            i4v val = *(i4v*)(c_lds + m * 136 + cls * 32 + co8);
            *(i4v*)(d2 + (((size_t)img * 50 + oh) * 50 + ow) * 32 + co8) = val;
        }
    }
}

// ---- convf: d2 bf16 (bc,50,50,32) -> out f32 (bc,50,50), sigmoid -----------
__global__ __launch_bounds__(256) void k_convf(const unsigned short* __restrict__ in,
                                               const float* __restrict__ w,  // dw3 (1,32,3,3)
                                               const float* __restrict__ b,
                                               float* __restrict__ out, int total) {
    __shared__ float wl[288];  // [tap9][ci32]
    int tid = threadIdx.x;
    for (int t = tid; t < 288; t += 256) {
        int tap = t >> 5, ci = t & 31;
        wl[t] = w[ci * 9 + tap];
    }
    __syncthreads();
    int pix = blockIdx.x * 256 + tid;
    if (pix >= total) return;
    int n = pix / 2500, p = pix % 2500, oh = p / 50, ow = p % 50;
    float acc = b[0];
#pragma unroll
    for (int kh = 0; kh < 3; ++kh) {
        int ih = oh - 1 + kh;
        if ((unsigned)ih >= 50u) continue;
#pragma unroll
        for (int kw = 0; kw < 3; ++kw) {
            int iw = ow - 1 + kw;
            if ((unsigned)iw >= 50u) continue;
            const float* wt = wl + (kh * 3 + kw) * 32;
            const i4v* ip4 = (const i4v*)(in + (((size_t)n * 50 + ih) * 50 + iw) * 32);
#pragma unroll
            for (int c8 = 0; c8 < 4; ++c8) {
                i4v u = ip4[c8];
#pragma unroll
                for (int e = 0; e < 4; ++e) {
                    unsigned uu = (unsigned)u[e];
                    float x0 = __builtin_bit_cast(float, uu << 16);
                    float x1 = __builtin_bit_cast(float, uu & 0xffff0000u);
                    acc = fmaf(x0, wt[c8 * 8 + e * 2], acc);
                    acc = fmaf(x1, wt[c8 * 8 + e * 2 + 1], acc);
                }
            }
        }
    }
    out[pix] = 1.f / (1.f + expf(-acc));
}

extern "C" void kernel_launch(void* const* d_in, const int* in_sizes, int n_in,
                              void* d_out, int out_size, void* d_ws, size_t ws_size,
                              hipStream_t stream) {
    const float* x   = (const float*)d_in[0];
    const float* ew1 = (const float*)d_in[1];
    const float* eb1 = (const float*)d_in[2];
    const float* ew2 = (const float*)d_in[3];
    const float* eb2 = (const float*)d_in[4];
    const float* ew3 = (const float*)d_in[5];
    const float* eb3 = (const float*)d_in[6];
    const float* cb  = (const float*)d_in[7];
    const float* dw1 = (const float*)d_in[8];
    const float* db1 = (const float*)d_in[9];
    const float* dw2 = (const float*)d_in[10];
    const float* db2 = (const float*)d_in[11];
    const float* dw3 = (const float*)d_in[12];
    const float* db3 = (const float*)d_in[13];
    float* out = (float*)d_out;
    float* loss = out + 2560000;

    float* ws = (float*)d_ws;
    float* cn = ws;                                        // 512 f
    unsigned short* wB1  = (unsigned short*)(ws + 512);    // 65536 sh = 32768 f
    unsigned short* wB2  = (unsigned short*)(ws + 33280);  // 32768 sh = 16384 f
    unsigned short* wB2n = (unsigned short*)(ws + 49664);  // 55296 sh = 27648 f
    unsigned short* wB3  = (unsigned short*)(ws + 77312);  // 12288 sh = 6144 f
    const size_t tw_floats = 83456;

    const int B = 1024;
    // regA 40000 f/img: h1 (20000), q (10816), d2-bf16 (40000 f = 80000 sh)
    // regB 20000 f/img: z (10816), d1-bf16 (20000 f = 40000 sh)
    const size_t A_per = 40000, B_per = 20000, V_per = 676;
    size_t avail = (ws_size / 4 > tw_floats) ? ws_size / 4 - tw_floats : 0;
    int BC = (int)(avail / (A_per + B_per + V_per));
    if (BC > B) BC = B;
    if (BC < 1) BC = 1;
    float* regA  = ws + tw_floats;
    float* regB  = regA + (size_t)BC * A_per;
    float* bestd = regB + (size_t)BC * B_per;
    int*   bestk = (int*)(bestd + (size_t)2 * BC * 169);

    k_zero<<<1, 64, 0, stream>>>(loss);
    k_prep_cn <<<2, 256, 0, stream>>>(cb, cn);
    k_prep_B2n<<<216, 256, 0, stream>>>(ew2, wB2n);
    k_prep_B3 <<<48, 256, 0, stream>>>(ew3, wB3);
    k_prep_B1 <<<256, 256, 0, stream>>>(dw1, wB1);
    k_prep_B2 <<<128, 256, 0, stream>>>(dw2, wB2);

    for (int n0 = 0; n0 < B; n0 += BC) {
        int bc = (B - n0 < BC) ? (B - n0) : BC;
        const float* xch = x + (size_t)n0 * 2500;

        int t1 = bc * 625;   // conv1: x -> h1 (regA)
        k_conv1<<<(t1 + 255) / 256, 256, 0, stream>>>(xch, ew1, eb1, regA, t1);

        int npix = bc * 169;
        // fused conv2+conv3 MFMA: h1 (regA) -> z (regB)
        k_enc_m<<<(npix + 15) / 16, 256, 0, stream>>>(regA, wB2n, wB3, eb2, eb3, regB, npix);

        // vq: z (regB) -> q (regA)
        dim3 gv((npix + 255) / 256, 2);
        k_vq_slice<<<gv, 256, 0, stream>>>(regB, cb, cn, bestd, bestk, npix);
        k_vq_merge<<<(npix + 255) / 256, 256, 0, stream>>>(regB, cb, bestd, bestk, regA, loss, npix);

        // tconv1 MFMA: q (regA f32) -> d1 (regB bf16, 40000 sh/img exact)
        unsigned short* d1 = (unsigned short*)regB;
        k_tconv1_m<<<(npix + 15) / 16, 256, 0, stream>>>(regA, wB1, db1, d1, npix);

        // tconv2 MFMA: d1 (regB bf16) -> d2 (regA bf16, 80000 sh/img exact)
        int nq2 = bc * 625;
        unsigned short* d2 = (unsigned short*)regA;
        k_tconv2_m<<<(nq2 + 15) / 16, 256, 0, stream>>>(d1, wB2, db2, d2, nq2);

        int t6 = bc * 2500;  // convf: d2 bf16 (regA) -> out
        k_convf<<<(t6 + 255) / 256, 256, 0, stream>>>(d2, dw3, db3, out + (size_t)n0 * 2500, t6);
    }
}

// Round 11
// 624.950 us; speedup vs baseline: 5.7423x; 1.3680x over previous
//
#include <hip/hip_runtime.h>
#include <math.h>

// ---------------------------------------------------------------------------
// VQ-VAE forward. R11: VQ rewritten as split-bf16 MFMA GEMM (4-product
// hi/lo split, K=256) with fused argmin + q-gather + loss — replaces the
// fp32 slice+merge pair. Encoder conv2+conv3 fused MFMA (R10); decoder
// bf16 MFMA implicit GEMM (R7).
//  conv1: x -> h1 (n,25,25,32) f32            [regA]
//  enc_m: h1 -> z (n,13,13,64) f32            [regB]
//  vq_m:  z -> q f32 [regA] + loss            (MFMA distance + argmin fused)
//  tconv1 MFMA: q -> d1 (n,25,25,64) bf16     [regB]
//  tconv2 MFMA: d1 -> d2 (n,50,50,32) bf16    [regA]
//  convf k3s1p1+sigm (bf16 in, fp32 math) -> out (n,50,50)
// ---------------------------------------------------------------------------

typedef __attribute__((ext_vector_type(8))) short s8v;   // 8 bf16 frag
typedef __attribute__((ext_vector_type(4))) float f4v;   // MFMA acc
typedef __attribute__((ext_vector_type(4))) int i4v;

__device__ inline unsigned short f2bf(float f) {  // RNE fp32->bf16
    unsigned u = __builtin_bit_cast(unsigned, f);
    return (unsigned short)((u + 0x7fffu + ((u >> 16) & 1u)) >> 16);
}
__device__ inline float bf2f(unsigned short h) {
    return __builtin_bit_cast(float, ((unsigned)h) << 16);
}

__global__ __launch_bounds__(64) void k_zero(float* __restrict__ p) {
    if (threadIdx.x == 0 && blockIdx.x == 0) *p = 0.f;
}

// ---- weight preps ----------------------------------------------------------
__global__ __launch_bounds__(256) void k_prep_cn(const float* __restrict__ cb,
                                                 float* __restrict__ cn) {
    int k = blockIdx.x * 256 + threadIdx.x;  // 512
    const float* r = cb + k * 64;
    float s = 0.f;
#pragma unroll
    for (int c = 0; c < 64; ++c) s += r[c] * r[c];
    cn[k] = s;
}
// cbm: VQ codebook split-bf16 B-fragments. (nt32, kc8, lane64, j8):
// k = kc*32+(lane>>4)*8+j in [0,256); n = nt*16+(lane&15) = code.
// seg=k>>6: A=[zh,zh,zl,zl] pairs with B=[ch,cl,ch,cl].
__global__ __launch_bounds__(256) void k_prep_cbm(const float* __restrict__ cb,
                                                  unsigned short* __restrict__ o) {
    int i = blockIdx.x * 256 + threadIdx.x;  // 131072
    int j = i & 7, lane = (i >> 3) & 63, kc = (i >> 9) & 7, nt = i >> 12;
    int n = nt * 16 + (lane & 15);
    int k = kc * 32 + ((lane >> 4) << 3) + j;
    int seg = k >> 6, kk = k & 63;
    float c = cb[n * 64 + kk];
    unsigned short ch = f2bf(c);
    o[i] = (seg == 0 || seg == 2) ? ch : f2bf(c - bf2f(ch));
}
// B2n: conv2 split-bf16 B (nt4, kc27, lane64, j8); K1=864 = [hi288|lo288|hi288]
// pairing A1=[hi|hi|lo].
__global__ __launch_bounds__(256) void k_prep_B2n(const float* __restrict__ w,  // ew2 (64,32,3,3)
                                                  unsigned short* __restrict__ o) {
    int i = blockIdx.x * 256 + threadIdx.x;  // 55296
    if (i >= 55296) return;
    int j = i & 7, lane = (i >> 3) & 63;
    int kc = (i >> 9) % 27, nt = (i >> 9) / 27;
    int k = kc * 32 + ((lane >> 4) << 3) + j;
    int co = nt * 16 + (lane & 15);
    int part = (k < 288) ? 0 : (k < 576) ? 1 : 0;  // 0=hi,1=lo
    int kk = (k < 288) ? k : (k < 576) ? k - 288 : k - 576;
    int tap = kk >> 5, ci = kk & 31;
    float v = w[(co * 32 + ci) * 9 + tap];
    unsigned short hi = f2bf(v);
    o[i] = part ? f2bf(v - bf2f(hi)) : hi;
}
// B3: conv3 split-bf16 B (nt4, kc6, lane64, j8); K2=192 = [hi64|lo64|hi64]
__global__ __launch_bounds__(256) void k_prep_B3(const float* __restrict__ w,  // ew3 (64,64)
                                                 unsigned short* __restrict__ o) {
    int i = blockIdx.x * 256 + threadIdx.x;  // 12288
    if (i >= 12288) return;
    int j = i & 7, lane = (i >> 3) & 63;
    int kc = (i >> 9) % 6, nt = (i >> 9) / 6;
    int k = kc * 32 + ((lane >> 4) << 3) + j;
    int n = nt * 16 + (lane & 15);
    int part = (k < 64) ? 0 : (k < 128) ? 1 : 0;
    int kk = (k < 64) ? k : (k < 128) ? k - 64 : k - 128;
    float v = w[n * 64 + kk];
    unsigned short hi = f2bf(v);
    o[i] = part ? f2bf(v - bf2f(hi)) : hi;
}
// Zero-padded tconv weight matrices
__global__ __launch_bounds__(256) void k_prep_B1(const float* __restrict__ w,  // dw1 (64,64,3,3)
                                                 unsigned short* __restrict__ o) {
    int i = blockIdx.x * 256 + threadIdx.x;  // 65536
    int j = i & 7, l = (i >> 3) & 63, kc = (i >> 9) & 7, nt = i >> 12;
    int n = nt * 16 + (l & 15), k = kc * 32 + (l >> 4) * 8 + j;
    int cls = n >> 6, co = n & 63, p = k >> 6, ci = k & 63;
    int jh = -1, jw = -1;
    if (cls == 0)      { if (p == 0) { jh = 1; jw = 1; } }
    else if (cls == 1) { if (p == 1) { jh = 1; jw = 0; } else if (p == 0) { jh = 1; jw = 2; } }
    else if (cls == 2) { if (p == 2) { jh = 0; jw = 1; } else if (p == 0) { jh = 2; jw = 1; } }
    else { if (p == 3) { jh = 0; jw = 0; } else if (p == 2) { jh = 0; jw = 2; }
           else if (p == 1) { jh = 2; jw = 0; } else { jh = 2; jw = 2; } }
    float v = (jh >= 0) ? w[((co * 64 + ci) * 3 + jh) * 3 + jw] : 0.f;
    o[i] = f2bf(v);
}
__global__ __launch_bounds__(256) void k_prep_B2(const float* __restrict__ w,  // dw2 (32,64,3,3)
                                                 unsigned short* __restrict__ o) {
    int i = blockIdx.x * 256 + threadIdx.x;  // 32768
    int j = i & 7, l = (i >> 3) & 63, kc = (i >> 9) & 7, nt = i >> 12;
    int n = nt * 16 + (l & 15), k = kc * 32 + (l >> 4) * 8 + j;
    int cls = n >> 5, co = n & 31, p = k >> 6, ci = k & 63;
    int jh = -1, jw = -1;
    if (cls == 0)      { if (p == 0) { jh = 1; jw = 1; } }
    else if (cls == 1) { if (p == 1) { jh = 1; jw = 0; } else if (p == 0) { jh = 1; jw = 2; } }
    else if (cls == 2) { if (p == 2) { jh = 0; jw = 1; } else if (p == 0) { jh = 2; jw = 1; } }
    else { if (p == 3) { jh = 0; jw = 0; } else if (p == 2) { jh = 0; jw = 2; }
           else if (p == 1) { jh = 2; jw = 0; } else { jh = 2; jw = 2; } }
    float v = (jh >= 0) ? w[((co * 64 + ci) * 3 + jh) * 3 + jw] : 0.f;
    o[i] = f2bf(v);
}

// ---- conv1: x (bc,50,50) -> h1 (bc,25,25,32) f32, relu ---------------------
__global__ __launch_bounds__(256) void k_conv1(const float* __restrict__ x,
                                               const float* __restrict__ w,
                                               const float* __restrict__ b,
                                               float* __restrict__ h1, int total) {
    __shared__ float4 wl4[72];
    float* wl = (float*)wl4;
    int tid = threadIdx.x;
    for (int t = tid; t < 288; t += 256) {
        int tap = t >> 5, co = t & 31;
        wl[t] = w[co * 9 + tap];
    }
    __syncthreads();
    int pix = blockIdx.x * 256 + tid;
    if (pix >= total) return;
    int n = pix / 625, p = pix % 625, oh = p / 25, ow = p % 25;
    const float* xp = x + (size_t)n * 2500;
    float4 a[8];
#pragma unroll
    for (int j = 0; j < 8; ++j) a[j] = ((const float4*)b)[j];
#pragma unroll
    for (int kh = 0; kh < 3; ++kh) {
        int ih = 2 * oh - 1 + kh;
        if ((unsigned)ih >= 50u) continue;
#pragma unroll
        for (int kw = 0; kw < 3; ++kw) {
            int iw = 2 * ow - 1 + kw;
            if ((unsigned)iw >= 50u) continue;
            float v = xp[ih * 50 + iw];
            int tap = kh * 3 + kw;
#pragma unroll
            for (int j = 0; j < 8; ++j) {
                float4 ww = wl4[tap * 8 + j];
                a[j].x += v * ww.x; a[j].y += v * ww.y;
                a[j].z += v * ww.z; a[j].w += v * ww.w;
            }
        }
    }
    float4* op = (float4*)(h1 + (size_t)pix * 32);
#pragma unroll
    for (int j = 0; j < 8; ++j) {
        float4 r;
        r.x = fmaxf(a[j].x, 0.f); r.y = fmaxf(a[j].y, 0.f);
        r.z = fmaxf(a[j].z, 0.f); r.w = fmaxf(a[j].w, 0.f);
        op[j] = r;
    }
}

// ---- enc_m: fused conv2(k3s2p1)+relu+conv3(1x1), split-bf16 MFMA -----------
__global__ __launch_bounds__(256) void k_enc_m(const float* __restrict__ h1,
                                               const unsigned short* __restrict__ B2n,
                                               const unsigned short* __restrict__ B3,
                                               const float* __restrict__ b2,
                                               const float* __restrict__ b3,
                                               float* __restrict__ z, int npix) {
    __shared__ short a1[16 * 872];   // [m][k1: 0-288 hi, 288-576 hi-dup, 576-864 lo]
    __shared__ short a2[16 * 200];   // [m][k2: 0-64 hi, 64-128 hi-dup, 128-192 lo]
    __shared__ float cz[16 * 68];
    int tid = threadIdx.x, blk = blockIdx.x;
    {
        int m = tid >> 4, chunk = tid & 15;
        if (chunk < 9) {
            int pix = blk * 16 + m;
            float4 v[8];
            const float4 zero = {0.f, 0.f, 0.f, 0.f};
            bool ok = false;
            if (pix < npix) {
                int n = pix / 169, p = pix % 169, oh = p / 13, ow = p % 13;
                int kh = chunk / 3, kw = chunk % 3;
                int ih = 2 * oh - 1 + kh, iw = 2 * ow - 1 + kw;
                ok = ((unsigned)ih < 25u) && ((unsigned)iw < 25u);
                if (ok) {
                    const float4* ip = (const float4*)(h1 + (((size_t)n * 25 + ih) * 25 + iw) * 32);
#pragma unroll
                    for (int c4 = 0; c4 < 8; ++c4) v[c4] = ip[c4];
                }
            }
            if (!ok) {
#pragma unroll
                for (int c4 = 0; c4 < 8; ++c4) v[c4] = zero;
            }
            unsigned short hi[32], lo[32];
#pragma unroll
            for (int c4 = 0; c4 < 8; ++c4) {
                float vv[4] = {v[c4].x, v[c4].y, v[c4].z, v[c4].w};
#pragma unroll
                for (int e = 0; e < 4; ++e) {
                    int ci = c4 * 4 + e;
                    unsigned short h = f2bf(vv[e]);
                    hi[ci] = h;
                    lo[ci] = f2bf(vv[e] - bf2f(h));
                }
            }
            short* row = a1 + m * 872 + chunk * 32;
            i4v* d0 = (i4v*)row;             // hi
            i4v* d1 = (i4v*)(row + 288);     // hi dup
            i4v* d2 = (i4v*)(row + 576);     // lo
#pragma unroll
            for (int g = 0; g < 4; ++g) {
                i4v ph, pl;
#pragma unroll
                for (int e = 0; e < 4; ++e) {
                    int b0 = g * 8 + e * 2;
                    ph[e] = (int)((unsigned)hi[b0] | ((unsigned)hi[b0 + 1] << 16));
                    pl[e] = (int)((unsigned)lo[b0] | ((unsigned)lo[b0 + 1] << 16));
                }
                d0[g] = ph; d1[g] = ph; d2[g] = pl;
            }
        }
    }
    __syncthreads();
    int wave = tid >> 6, lane = tid & 63;
    int arow1 = (lane & 15) * 872 + (lane >> 4) * 8;
    f4v acc = (f4v){0.f, 0.f, 0.f, 0.f};
#pragma unroll
    for (int kc = 0; kc < 27; ++kc) {
        s8v a = *(const s8v*)(a1 + arow1 + kc * 32);
        s8v b = *(const s8v*)((const short*)B2n + ((size_t)((wave * 27 + kc) * 64 + lane)) * 8);
        acc = __builtin_amdgcn_mfma_f32_16x16x32_bf16(a, b, acc, 0, 0, 0);
    }
    {
        float bv = b2[wave * 16 + (lane & 15)];
        int n = wave * 16 + (lane & 15);
#pragma unroll
        for (int r = 0; r < 4; ++r) {
            int m = (lane >> 4) * 4 + r;
            float h = fmaxf(acc[r] + bv, 0.f);
            unsigned short hh = f2bf(h);
            unsigned short ll = f2bf(h - bf2f(hh));
            a2[m * 200 + n] = (short)hh;
            a2[m * 200 + 64 + n] = (short)hh;
            a2[m * 200 + 128 + n] = (short)ll;
        }
    }
    __syncthreads();
    int arow2 = (lane & 15) * 200 + (lane >> 4) * 8;
    f4v acc2 = (f4v){0.f, 0.f, 0.f, 0.f};
#pragma unroll
    for (int kc = 0; kc < 6; ++kc) {
        s8v a = *(const s8v*)(a2 + arow2 + kc * 32);
        s8v b = *(const s8v*)((const short*)B3 + ((size_t)((wave * 6 + kc) * 64 + lane)) * 8);
        acc2 = __builtin_amdgcn_mfma_f32_16x16x32_bf16(a, b, acc2, 0, 0, 0);
    }
    {
        float bv = b3[wave * 16 + (lane & 15)];
        int n = wave * 16 + (lane & 15);
#pragma unroll
        for (int r = 0; r < 4; ++r) {
            int m = (lane >> 4) * 4 + r;
            cz[m * 68 + n] = acc2[r] + bv;
        }
    }
    __syncthreads();
    {
        int m = tid >> 4, c4 = tid & 15;
        int pix = blk * 16 + m;
        if (pix < npix) {
            float4 v = *(float4*)(cz + m * 68 + c4 * 4);
            *(float4*)(z + (size_t)pix * 64 + c4 * 4) = v;
        }
    }
}

// ---- vq_m: MFMA distance GEMM + fused argmin + q gather + loss -------------
// M-tile 16 pixels, N=512 codes (4 waves x 8 n-tiles), K=256 (zh,zh,zl,zl x
// ch,cl,ch,cl). d = cn[k] - 2*dot. First-min semantics via ascending-k scan
// with strict < and explicit k tie-break at every merge level.
__global__ __launch_bounds__(256) void k_vq_m(const float* __restrict__ z,
                                              const float* __restrict__ cb,
                                              const unsigned short* __restrict__ cbm,
                                              const float* __restrict__ cn,
                                              float* __restrict__ q,
                                              float* __restrict__ loss, int npix) {
    __shared__ short a_lds[16 * 264];
    __shared__ float reds[4 * 16];
    __shared__ int   redk[4 * 16];
    __shared__ int   bkf[16];
    __shared__ float lred[4];
    int tid = threadIdx.x, blk = blockIdx.x;
    {   // stage A: split z to hi/lo bf16. chunk: seg=chunk>>2 (0,1->zh; 2,3->zl)
        int m = tid >> 4, chunk = tid & 15;
        int pix = blk * 16 + m;
        int seg = chunk >> 2, ci0 = (chunk & 3) * 16;
        unsigned short t16[16];
        if (pix < npix) {
            const float* src = z + (size_t)pix * 64 + ci0;
#pragma unroll
            for (int v = 0; v < 16; ++v) {
                float f = src[v];
                unsigned short h = f2bf(f);
                t16[v] = (seg < 2) ? h : f2bf(f - bf2f(h));
            }
        } else {
#pragma unroll
            for (int v = 0; v < 16; ++v) t16[v] = 0;
        }
        unsigned pk[8];
#pragma unroll
        for (int v = 0; v < 8; ++v) pk[v] = (unsigned)t16[2 * v] | ((unsigned)t16[2 * v + 1] << 16);
        i4v* dst = (i4v*)(a_lds + m * 264 + chunk * 16);
        dst[0] = (i4v){(int)pk[0], (int)pk[1], (int)pk[2], (int)pk[3]};
        dst[1] = (i4v){(int)pk[4], (int)pk[5], (int)pk[6], (int)pk[7]};
    }
    __syncthreads();
    int wave = tid >> 6, lane = tid & 63;
    // preload A fragments (reused across all 8 n-tiles)
    int arow = (lane & 15) * 264 + (lane >> 4) * 8;
    s8v af[8];
#pragma unroll
    for (int kc = 0; kc < 8; ++kc) af[kc] = *(const s8v*)(a_lds + arow + kc * 32);
    float bd[4];
    int bk[4];
#pragma unroll
    for (int r = 0; r < 4; ++r) { bd[r] = 3.4e38f; bk[r] = 0; }
#pragma unroll 1
    for (int nt = 0; nt < 8; ++nt) {
        int ntg = wave * 8 + nt;
        f4v acc = (f4v){0.f, 0.f, 0.f, 0.f};
#pragma unroll
        for (int kc = 0; kc < 8; ++kc) {
            s8v b = *(const s8v*)((const short*)cbm + ((size_t)((ntg * 8 + kc) * 64 + lane)) * 8);
            acc = __builtin_amdgcn_mfma_f32_16x16x32_bf16(af[kc], b, acc, 0, 0, 0);
        }
        int kcol = ntg * 16 + (lane & 15);
        float cnk = cn[kcol];
#pragma unroll
        for (int r = 0; r < 4; ++r) {
            float d = cnk - 2.f * acc[r];
            if (d < bd[r]) { bd[r] = d; bk[r] = kcol; }  // ascending k: < keeps lowest
        }
    }
    // butterfly argmin across the 16 columns (lane&15 varies, row group fixed)
#pragma unroll
    for (int off = 1; off < 16; off <<= 1) {
#pragma unroll
        for (int r = 0; r < 4; ++r) {
            float od = __shfl_xor(bd[r], off);
            int ok = __shfl_xor(bk[r], off);
            if (od < bd[r] || (od == bd[r] && ok < bk[r])) { bd[r] = od; bk[r] = ok; }
        }
    }
    if ((lane & 15) == 0) {
#pragma unroll
        for (int r = 0; r < 4; ++r) {
            int m = (lane >> 4) * 4 + r;
            reds[wave * 16 + m] = bd[r];
            redk[wave * 16 + m] = bk[r];
        }
    }
    __syncthreads();
    if (tid < 16) {   // merge 4 waves (ascending k ranges)
        float d0 = reds[tid]; int k0 = redk[tid];
#pragma unroll
        for (int w = 1; w < 4; ++w) {
            float dw = reds[w * 16 + tid]; int kw = redk[w * 16 + tid];
            if (dw < d0 || (dw == d0 && kw < k0)) { d0 = dw; k0 = kw; }
        }
        bkf[tid] = k0;
    }
    __syncthreads();
    // q gather (exact fp32 codebook rows) + loss
    float lsum = 0.f;
    {
        int m = tid >> 4, c4 = tid & 15;
        int pix = blk * 16 + m;
        if (pix < npix) {
            int k0 = bkf[m];
            float4 cq = ((const float4*)cb)[(size_t)k0 * 16 + c4];
            float4 zz = ((const float4*)(z + (size_t)pix * 64))[c4];
            float dx = cq.x - zz.x, dy = cq.y - zz.y, dz = cq.z - zz.z, dw = cq.w - zz.w;
            lsum = dx * dx + dy * dy + dz * dz + dw * dw;
            ((float4*)(q + (size_t)pix * 64))[c4] = cq;
        }
    }
#pragma unroll
    for (int off = 32; off > 0; off >>= 1) lsum += __shfl_down(lsum, off);
    if ((tid & 63) == 0) lred[tid >> 6] = lsum;
    __syncthreads();
    if (tid == 0) {
        float t = lred[0] + lred[1] + lred[2] + lred[3];
        atomicAdd(loss, t * (1.25f / 11075584.f));
    }
}

// ---- tconv1 MFMA: q f32 (13,13,64) -> d1 bf16 (25,25,64), relu -------------
__global__ __launch_bounds__(256) void k_tconv1_m(const float* __restrict__ q,
                                                  const unsigned short* __restrict__ wB,
                                                  const float* __restrict__ bias,
                                                  unsigned short* __restrict__ d1,
                                                  int nquad) {
    __shared__ short a_lds[16 * 264];
    __shared__ short c_lds[16 * 264];
    int tid = threadIdx.x, blk = blockIdx.x;
    {
        int m = tid >> 4, chunk = tid & 15;
        int qg = blk * 16 + m;
        unsigned short tmp[16];
        bool have = false;
        if (qg < nquad) {
            int img = qg / 169, r = qg % 169, qm = r / 13, qw = r % 13;
            int p = chunk >> 2, ci0 = (chunk & 3) * 16;
            int sm = qm + (p >> 1), sw = qw + (p & 1);
            if (sm < 13 && sw < 13) {
                const float* src = q + (((size_t)img * 13 + sm) * 13 + sw) * 64 + ci0;
#pragma unroll
                for (int v = 0; v < 16; ++v) tmp[v] = f2bf(src[v]);
                have = true;
            }
        }
        if (!have) {
#pragma unroll
            for (int v = 0; v < 16; ++v) tmp[v] = 0;
        }
        unsigned pk[8];
#pragma unroll
        for (int v = 0; v < 8; ++v) pk[v] = (unsigned)tmp[2 * v] | ((unsigned)tmp[2 * v + 1] << 16);
        i4v* dst = (i4v*)(a_lds + m * 264 + chunk * 16);
        dst[0] = (i4v){(int)pk[0], (int)pk[1], (int)pk[2], (int)pk[3]};
        dst[1] = (i4v){(int)pk[4], (int)pk[5], (int)pk[6], (int)pk[7]};
    }
    __syncthreads();
    int wave = tid >> 6, lane = tid & 63;
    f4v acc[4];
#pragma unroll
    for (int i = 0; i < 4; ++i) acc[i] = (f4v){0.f, 0.f, 0.f, 0.f};
    float bv[4];
#pragma unroll
    for (int i = 0; i < 4; ++i) bv[i] = bias[((wave * 4 + i) * 16 + (lane & 15)) & 63];
    int arow = (lane & 15) * 264 + (lane >> 4) * 8;
#pragma unroll
    for (int kc = 0; kc < 8; ++kc) {
        s8v a = *(const s8v*)(a_lds + arow + kc * 32);
#pragma unroll
        for (int i = 0; i < 4; ++i) {
            int nt = wave * 4 + i;
            s8v b = *(const s8v*)((const short*)wB + ((size_t)((nt * 8 + kc) * 64 + lane)) * 8);
            acc[i] = __builtin_amdgcn_mfma_f32_16x16x32_bf16(a, b, acc[i], 0, 0, 0);
        }
    }
#pragma unroll
    for (int i = 0; i < 4; ++i) {
        int n = (wave * 4 + i) * 16 + (lane & 15);
#pragma unroll
        for (int r2 = 0; r2 < 4; ++r2) {
            int m = (lane >> 4) * 4 + r2;
            float v = fmaxf(acc[i][r2] + bv[i], 0.f);
            c_lds[m * 264 + n] = (short)f2bf(v);
        }
    }
    __syncthreads();
#pragma unroll
    for (int ch2 = 0; ch2 < 2; ++ch2) {
        int ch = tid + ch2 * 256;
        int m = ch >> 5, cpart = ch & 31;
        int qg = blk * 16 + m;
        if (qg >= nquad) continue;
        int img = qg / 169, r = qg % 169, qm = r / 13, qw = r % 13;
        int cls = cpart >> 3, co8 = (cpart & 7) * 8;
        int oh = 2 * qm + (cls >> 1), ow = 2 * qw + (cls & 1);
        if (oh >= 25 || ow >= 25) continue;
        i4v val = *(i4v*)(c_lds + m * 264 + cls * 64 + co8);
        *(i4v*)(d1 + (((size_t)img * 25 + oh) * 25 + ow) * 64 + co8) = val;
    }
}

// ---- tconv2 MFMA: d1 bf16 (25,25,64) -> d2 bf16 (50,50,32), relu -----------
__global__ __launch_bounds__(256) void k_tconv2_m(const unsigned short* __restrict__ d1,
                                                  const unsigned short* __restrict__ wB,
                                                  const float* __restrict__ bias,
                                                  unsigned short* __restrict__ d2,
                                                  int nquad) {
    __shared__ short a_lds[16 * 264];
    __shared__ short c_lds[16 * 136];
    int tid = threadIdx.x, blk = blockIdx.x;
    {
        int m = tid >> 4, chunk = tid & 15;
        int qg = blk * 16 + m;
        i4v v0 = (i4v){0, 0, 0, 0}, v1 = v0;
        if (qg < nquad) {
            int img = qg / 625, r = qg % 625, qm = r / 25, qw = r % 25;
            int p = chunk >> 2, ci0 = (chunk & 3) * 16;
            int sm = qm + (p >> 1), sw = qw + (p & 1);
            if (sm < 25 && sw < 25) {
                const i4v* src = (const i4v*)(d1 + (((size_t)img * 25 + sm) * 25 + sw) * 64 + ci0);
                v0 = src[0]; v1 = src[1];
            }
        }
        i4v* dst = (i4v*)(a_lds + m * 264 + chunk * 16);
        dst[0] = v0; dst[1] = v1;
    }
    __syncthreads();
    int wave = tid >> 6, lane = tid & 63;
    f4v acc[2];
    acc[0] = (f4v){0.f, 0.f, 0.f, 0.f};
    acc[1] = acc[0];
    float bv[2];
#pragma unroll
    for (int i = 0; i < 2; ++i) bv[i] = bias[((wave * 2 + i) * 16 + (lane & 15)) & 31];
    int arow = (lane & 15) * 264 + (lane >> 4) * 8;
#pragma unroll
    for (int kc = 0; kc < 8; ++kc) {
        s8v a = *(const s8v*)(a_lds + arow + kc * 32);
#pragma unroll
        for (int i = 0; i < 2; ++i) {
            int nt = wave * 2 + i;
            s8v b = *(const s8v*)((const short*)wB + ((size_t)((nt * 8 + kc) * 64 + lane)) * 8);
            acc[i] = __builtin_amdgcn_mfma_f32_16x16x32_bf16(a, b, acc[i], 0, 0, 0);
        }
    }
#pragma unroll
    for (int i = 0; i < 2; ++i) {
        int n = (wave * 2 + i) * 16 + (lane & 15);
#pragma unroll
        for (int r2 = 0; r2 < 4; ++r2) {
            int m = (lane >> 4) * 4 + r2;
            float v = fmaxf(acc[i][r2] + bv[i], 0.f);
            c_lds[m * 136 + n] = (short)f2bf(v);
        }
    }
    __syncthreads();
    {
        int m = tid >> 4, cpart = tid & 15;
        int qg = blk * 16 + m;
        if (qg < nquad) {
            int img = qg / 625, r = qg % 625, qm = r / 25, qw = r % 25;
            int cls = cpart >> 2, co8 = (cpart & 3) * 8;
            int oh = 2 * qm + (cls >> 1), ow = 2 * qw + (cls & 1);
            i4v val = *(i4v*)(c_lds + m * 136 + cls * 32 + co8);
            *(i4v*)(d2 + (((size_t)img * 50 + oh) * 50 + ow) * 32 + co8) = val;
        }
    }
}

// ---- convf: d2 bf16 (bc,50,50,32) -> out f32 (bc,50,50), sigmoid -----------
__global__ __launch_bounds__(256) void k_convf(const unsigned short* __restrict__ in,
                                               const float* __restrict__ w,  // dw3 (1,32,3,3)
                                               const float* __restrict__ b,
                                               float* __restrict__ out, int total) {
    __shared__ float wl[288];  // [tap9][ci32]
    int tid = threadIdx.x;
    for (int t = tid; t < 288; t += 256) {
        int tap = t >> 5, ci = t & 31;
        wl[t] = w[ci * 9 + tap];
    }
    __syncthreads();
    int pix = blockIdx.x * 256 + tid;
    if (pix >= total) return;
    int n = pix / 2500, p = pix % 2500, oh = p / 50, ow = p % 50;
    float acc = b[0];
#pragma unroll
    for (int kh = 0; kh < 3; ++kh) {
        int ih = oh - 1 + kh;
        if ((unsigned)ih >= 50u) continue;
#pragma unroll
        for (int kw = 0; kw < 3; ++kw) {
            int iw = ow - 1 + kw;
            if ((unsigned)iw >= 50u) continue;
            const float* wt = wl + (kh * 3 + kw) * 32;
            const i4v* ip4 = (const i4v*)(in + (((size_t)n * 50 + ih) * 50 + iw) * 32);
#pragma unroll
            for (int c8 = 0; c8 < 4; ++c8) {
                i4v u = ip4[c8];
#pragma unroll
                for (int e = 0; e < 4; ++e) {
                    unsigned uu = (unsigned)u[e];
                    float x0 = __builtin_bit_cast(float, uu << 16);
                    float x1 = __builtin_bit_cast(float, uu & 0xffff0000u);
                    acc = fmaf(x0, wt[c8 * 8 + e * 2], acc);
                    acc = fmaf(x1, wt[c8 * 8 + e * 2 + 1], acc);
                }
            }
        }
    }
    out[pix] = 1.f / (1.f + expf(-acc));
}

extern "C" void kernel_launch(void* const* d_in, const int* in_sizes, int n_in,
                              void* d_out, int out_size, void* d_ws, size_t ws_size,
                              hipStream_t stream) {
    const float* x   = (const float*)d_in[0];
    const float* ew1 = (const float*)d_in[1];
    const float* eb1 = (const float*)d_in[2];
    const float* ew2 = (const float*)d_in[3];
    const float* eb2 = (const float*)d_in[4];
    const float* ew3 = (const float*)d_in[5];
    const float* eb3 = (const float*)d_in[6];
    const float* cb  = (const float*)d_in[7];
    const float* dw1 = (const float*)d_in[8];
    const float* db1 = (const float*)d_in[9];
    const float* dw2 = (const float*)d_in[10];
    const float* db2 = (const float*)d_in[11];
    const float* dw3 = (const float*)d_in[12];
    const float* db3 = (const float*)d_in[13];
    float* out = (float*)d_out;
    float* loss = out + 2560000;

    float* ws = (float*)d_ws;
    float* cn = ws;                                        // 512 f
    unsigned short* wB1  = (unsigned short*)(ws + 512);    // 65536 sh = 32768 f
    unsigned short* wB2  = (unsigned short*)(ws + 33280);  // 32768 sh = 16384 f
    unsigned short* wB2n = (unsigned short*)(ws + 49664);  // 55296 sh = 27648 f
    unsigned short* wB3  = (unsigned short*)(ws + 77312);  // 12288 sh = 6144 f
    unsigned short* cbm  = (unsigned short*)(ws + 83456);  // 131072 sh = 65536 f
    const size_t tw_floats = 148992;

    const int B = 1024;
    // regA 40000 f/img: h1 (20000), q (10816), d2-bf16 (80000 sh)
    // regB 20000 f/img: z (10816), d1-bf16 (40000 sh)
    const size_t A_per = 40000, B_per = 20000;
    size_t avail = (ws_size / 4 > tw_floats) ? ws_size / 4 - tw_floats : 0;
    int BC = (int)(avail / (A_per + B_per));
    if (BC > B) BC = B;
    if (BC < 1) BC = 1;
    float* regA = ws + tw_floats;
    float* regB = regA + (size_t)BC * A_per;

    k_zero<<<1, 64, 0, stream>>>(loss);
    k_prep_cn <<<2, 256, 0, stream>>>(cb, cn);
    k_prep_cbm<<<512, 256, 0, stream>>>(cb, cbm);
    k_prep_B2n<<<216, 256, 0, stream>>>(ew2, wB2n);
    k_prep_B3 <<<48, 256, 0, stream>>>(ew3, wB3);
    k_prep_B1 <<<256, 256, 0, stream>>>(dw1, wB1);
    k_prep_B2 <<<128, 256, 0, stream>>>(dw2, wB2);

    for (int n0 = 0; n0 < B; n0 += BC) {
        int bc = (B - n0 < BC) ? (B - n0) : BC;
        const float* xch = x + (size_t)n0 * 2500;

        int t1 = bc * 625;   // conv1: x -> h1 (regA)
        k_conv1<<<(t1 + 255) / 256, 256, 0, stream>>>(xch, ew1, eb1, regA, t1);

        int npix = bc * 169;
        // fused conv2+conv3 MFMA: h1 (regA) -> z (regB)
        k_enc_m<<<(npix + 15) / 16, 256, 0, stream>>>(regA, wB2n, wB3, eb2, eb3, regB, npix);

        // MFMA VQ: z (regB) -> q (regA) + loss
        k_vq_m<<<(npix + 15) / 16, 256, 0, stream>>>(regB, cb, cbm, cn, regA, loss, npix);

        // tconv1 MFMA: q (regA f32) -> d1 (regB bf16)
        unsigned short* d1 = (unsigned short*)regB;
        k_tconv1_m<<<(npix + 15) / 16, 256, 0, stream>>>(regA, wB1, db1, d1, npix);

        // tconv2 MFMA: d1 (regB bf16) -> d2 (regA bf16)
        int nq2 = bc * 625;
        unsigned short* d2 = (unsigned short*)regA;
        k_tconv2_m<<<(nq2 + 15) / 16, 256, 0, stream>>>(d1, wB2, db2, d2, nq2);

        int t6 = bc * 2500;  // convf: d2 bf16 (regA) -> out
        k_convf<<<(t6 + 255) / 256, 256, 0, stream>>>(d2, dw3, db3, out + (size_t)n0 * 2500, t6);
    }
}

// Round 12
// 538.687 us; speedup vs baseline: 6.6618x; 1.1601x over previous
//
#include <hip/hip_runtime.h>
#include <math.h>

// ---------------------------------------------------------------------------
// VQ-VAE forward. R12: vq_m restructured — M=32/block (2 m-tiles per wave,
// A-frags in registers => 2 MFMA per B-load), 3-product split (K=192),
// nt-loop unroll 2. Rest identical to R11.
//  conv1: x -> h1 (n,25,25,32) f32            [regA]
//  enc_m: h1 -> z (n,13,13,64) f32            [regB]
//  vq_m:  z -> q f32 [regA] + loss            (MFMA distance + argmin fused)
//  tconv1 MFMA: q -> d1 (n,25,25,64) bf16     [regB]
//  tconv2 MFMA: d1 -> d2 (n,50,50,32) bf16    [regA]
//  convf k3s1p1+sigm (bf16 in, fp32 math) -> out (n,50,50)
// ---------------------------------------------------------------------------

typedef __attribute__((ext_vector_type(8))) short s8v;   // 8 bf16 frag
typedef __attribute__((ext_vector_type(4))) float f4v;   // MFMA acc
typedef __attribute__((ext_vector_type(4))) int i4v;

__device__ inline unsigned short f2bf(float f) {  // RNE fp32->bf16
    unsigned u = __builtin_bit_cast(unsigned, f);
    return (unsigned short)((u + 0x7fffu + ((u >> 16) & 1u)) >> 16);
}
__device__ inline float bf2f(unsigned short h) {
    return __builtin_bit_cast(float, ((unsigned)h) << 16);
}

__global__ __launch_bounds__(64) void k_zero(float* __restrict__ p) {
    if (threadIdx.x == 0 && blockIdx.x == 0) *p = 0.f;
}

// ---- weight preps ----------------------------------------------------------
__global__ __launch_bounds__(256) void k_prep_cn(const float* __restrict__ cb,
                                                 float* __restrict__ cn) {
    int k = blockIdx.x * 256 + threadIdx.x;  // 512
    const float* r = cb + k * 64;
    float s = 0.f;
#pragma unroll
    for (int c = 0; c < 64; ++c) s += r[c] * r[c];
    cn[k] = s;
}
// cbm: VQ codebook 3-product split-bf16 B-frags. (nt32, kc6, lane64, j8):
// k = kc*32+(lane>>4)*8+j in [0,192); n = nt*16+(lane&15) = code.
// seg=k>>6: A=[zh,zh,zl] pairs with B=[ch,cl,ch].
__global__ __launch_bounds__(256) void k_prep_cbm(const float* __restrict__ cb,
                                                  unsigned short* __restrict__ o) {
    int i = blockIdx.x * 256 + threadIdx.x;  // 98304
    int j = i & 7, lane = (i >> 3) & 63;
    int kc = (i >> 9) % 6, nt = (i >> 9) / 6;
    int n = nt * 16 + (lane & 15);
    int k = kc * 32 + ((lane >> 4) << 3) + j;
    int seg = k >> 6, kk = k & 63;
    float c = cb[n * 64 + kk];
    unsigned short ch = f2bf(c);
    o[i] = (seg == 1) ? f2bf(c - bf2f(ch)) : ch;
}
// B2n: conv2 split-bf16 B (nt4, kc27, lane64, j8); K1=864 = [hi288|lo288|hi288]
__global__ __launch_bounds__(256) void k_prep_B2n(const float* __restrict__ w,  // ew2 (64,32,3,3)
                                                  unsigned short* __restrict__ o) {
    int i = blockIdx.x * 256 + threadIdx.x;  // 55296
    if (i >= 55296) return;
    int j = i & 7, lane = (i >> 3) & 63;
    int kc = (i >> 9) % 27, nt = (i >> 9) / 27;
    int k = kc * 32 + ((lane >> 4) << 3) + j;
    int co = nt * 16 + (lane & 15);
    int part = (k < 288) ? 0 : (k < 576) ? 1 : 0;  // 0=hi,1=lo
    int kk = (k < 288) ? k : (k < 576) ? k - 288 : k - 576;
    int tap = kk >> 5, ci = kk & 31;
    float v = w[(co * 32 + ci) * 9 + tap];
    unsigned short hi = f2bf(v);
    o[i] = part ? f2bf(v - bf2f(hi)) : hi;
}
// B3: conv3 split-bf16 B (nt4, kc6, lane64, j8); K2=192 = [hi64|lo64|hi64]
__global__ __launch_bounds__(256) void k_prep_B3(const float* __restrict__ w,  // ew3 (64,64)
                                                 unsigned short* __restrict__ o) {
    int i = blockIdx.x * 256 + threadIdx.x;  // 12288
    if (i >= 12288) return;
    int j = i & 7, lane = (i >> 3) & 63;
    int kc = (i >> 9) % 6, nt = (i >> 9) / 6;
    int k = kc * 32 + ((lane >> 4) << 3) + j;
    int n = nt * 16 + (lane & 15);
    int part = (k < 64) ? 0 : (k < 128) ? 1 : 0;
    int kk = (k < 64) ? k : (k < 128) ? k - 64 : k - 128;
    float v = w[n * 64 + kk];
    unsigned short hi = f2bf(v);
    o[i] = part ? f2bf(v - bf2f(hi)) : hi;
}
// Zero-padded tconv weight matrices
__global__ __launch_bounds__(256) void k_prep_B1(const float* __restrict__ w,  // dw1 (64,64,3,3)
                                                 unsigned short* __restrict__ o) {
    int i = blockIdx.x * 256 + threadIdx.x;  // 65536
    int j = i & 7, l = (i >> 3) & 63, kc = (i >> 9) & 7, nt = i >> 12;
    int n = nt * 16 + (l & 15), k = kc * 32 + (l >> 4) * 8 + j;
    int cls = n >> 6, co = n & 63, p = k >> 6, ci = k & 63;
    int jh = -1, jw = -1;
    if (cls == 0)      { if (p == 0) { jh = 1; jw = 1; } }
    else if (cls == 1) { if (p == 1) { jh = 1; jw = 0; } else if (p == 0) { jh = 1; jw = 2; } }
    else if (cls == 2) { if (p == 2) { jh = 0; jw = 1; } else if (p == 0) { jh = 2; jw = 1; } }
    else { if (p == 3) { jh = 0; jw = 0; } else if (p == 2) { jh = 0; jw = 2; }
           else if (p == 1) { jh = 2; jw = 0; } else { jh = 2; jw = 2; } }
    float v = (jh >= 0) ? w[((co * 64 + ci) * 3 + jh) * 3 + jw] : 0.f;
    o[i] = f2bf(v);
}
__global__ __launch_bounds__(256) void k_prep_B2(const float* __restrict__ w,  // dw2 (32,64,3,3)
                                                 unsigned short* __restrict__ o) {
    int i = blockIdx.x * 256 + threadIdx.x;  // 32768
    int j = i & 7, l = (i >> 3) & 63, kc = (i >> 9) & 7, nt = i >> 12;
    int n = nt * 16 + (l & 15), k = kc * 32 + (l >> 4) * 8 + j;
    int cls = n >> 5, co = n & 31, p = k >> 6, ci = k & 63;
    int jh = -1, jw = -1;
    if (cls == 0)      { if (p == 0) { jh = 1; jw = 1; } }
    else if (cls == 1) { if (p == 1) { jh = 1; jw = 0; } else if (p == 0) { jh = 1; jw = 2; } }
    else if (cls == 2) { if (p == 2) { jh = 0; jw = 1; } else if (p == 0) { jh = 2; jw = 1; } }
    else { if (p == 3) { jh = 0; jw = 0; } else if (p == 2) { jh = 0; jw = 2; }
           else if (p == 1) { jh = 2; jw = 0; } else { jh = 2; jw = 2; } }
    float v = (jh >= 0) ? w[((co * 64 + ci) * 3 + jh) * 3 + jw] : 0.f;
    o[i] = f2bf(v);
}

// ---- conv1: x (bc,50,50) -> h1 (bc,25,25,32) f32, relu ---------------------
__global__ __launch_bounds__(256) void k_conv1(const float* __restrict__ x,
                                               const float* __restrict__ w,
                                               const float* __restrict__ b,
                                               float* __restrict__ h1, int total) {
    __shared__ float4 wl4[72];
    float* wl = (float*)wl4;
    int tid = threadIdx.x;
    for (int t = tid; t < 288; t += 256) {
        int tap = t >> 5, co = t & 31;
        wl[t] = w[co * 9 + tap];
    }
    __syncthreads();
    int pix = blockIdx.x * 256 + tid;
    if (pix >= total) return;
    int n = pix / 625, p = pix % 625, oh = p / 25, ow = p % 25;
    const float* xp = x + (size_t)n * 2500;
    float4 a[8];
#pragma unroll
    for (int j = 0; j < 8; ++j) a[j] = ((const float4*)b)[j];
#pragma unroll
    for (int kh = 0; kh < 3; ++kh) {
        int ih = 2 * oh - 1 + kh;
        if ((unsigned)ih >= 50u) continue;
#pragma unroll
        for (int kw = 0; kw < 3; ++kw) {
            int iw = 2 * ow - 1 + kw;
            if ((unsigned)iw >= 50u) continue;
            float v = xp[ih * 50 + iw];
            int tap = kh * 3 + kw;
#pragma unroll
            for (int j = 0; j < 8; ++j) {
                float4 ww = wl4[tap * 8 + j];
                a[j].x += v * ww.x; a[j].y += v * ww.y;
                a[j].z += v * ww.z; a[j].w += v * ww.w;
            }
        }
    }
    float4* op = (float4*)(h1 + (size_t)pix * 32);
#pragma unroll
    for (int j = 0; j < 8; ++j) {
        float4 r;
        r.x = fmaxf(a[j].x, 0.f); r.y = fmaxf(a[j].y, 0.f);
        r.z = fmaxf(a[j].z, 0.f); r.w = fmaxf(a[j].w, 0.f);
        op[j] = r;
    }
}

// ---- enc_m: fused conv2(k3s2p1)+relu+conv3(1x1), split-bf16 MFMA -----------
__global__ __launch_bounds__(256) void k_enc_m(const float* __restrict__ h1,
                                               const unsigned short* __restrict__ B2n,
                                               const unsigned short* __restrict__ B3,
                                               const float* __restrict__ b2,
                                               const float* __restrict__ b3,
                                               float* __restrict__ z, int npix) {
    __shared__ short a1[16 * 872];
    __shared__ short a2[16 * 200];
    __shared__ float cz[16 * 68];
    int tid = threadIdx.x, blk = blockIdx.x;
    {
        int m = tid >> 4, chunk = tid & 15;
        if (chunk < 9) {
            int pix = blk * 16 + m;
            float4 v[8];
            const float4 zero = {0.f, 0.f, 0.f, 0.f};
            bool ok = false;
            if (pix < npix) {
                int n = pix / 169, p = pix % 169, oh = p / 13, ow = p % 13;
                int kh = chunk / 3, kw = chunk % 3;
                int ih = 2 * oh - 1 + kh, iw = 2 * ow - 1 + kw;
                ok = ((unsigned)ih < 25u) && ((unsigned)iw < 25u);
                if (ok) {
                    const float4* ip = (const float4*)(h1 + (((size_t)n * 25 + ih) * 25 + iw) * 32);
#pragma unroll
                    for (int c4 = 0; c4 < 8; ++c4) v[c4] = ip[c4];
                }
            }
            if (!ok) {
#pragma unroll
                for (int c4 = 0; c4 < 8; ++c4) v[c4] = zero;
            }
            unsigned short hi[32], lo[32];
#pragma unroll
            for (int c4 = 0; c4 < 8; ++c4) {
                float vv[4] = {v[c4].x, v[c4].y, v[c4].z, v[c4].w};
#pragma unroll
                for (int e = 0; e < 4; ++e) {
                    int ci = c4 * 4 + e;
                    unsigned short h = f2bf(vv[e]);
                    hi[ci] = h;
                    lo[ci] = f2bf(vv[e] - bf2f(h));
                }
            }
            short* row = a1 + m * 872 + chunk * 32;
            i4v* d0 = (i4v*)row;
            i4v* d1 = (i4v*)(row + 288);
            i4v* d2 = (i4v*)(row + 576);
#pragma unroll
            for (int g = 0; g < 4; ++g) {
                i4v ph, pl;
#pragma unroll
                for (int e = 0; e < 4; ++e) {
                    int b0 = g * 8 + e * 2;
                    ph[e] = (int)((unsigned)hi[b0] | ((unsigned)hi[b0 + 1] << 16));
                    pl[e] = (int)((unsigned)lo[b0] | ((unsigned)lo[b0 + 1] << 16));
                }
                d0[g] = ph; d1[g] = ph; d2[g] = pl;
            }
        }
    }
    __syncthreads();
    int wave = tid >> 6, lane = tid & 63;
    int arow1 = (lane & 15) * 872 + (lane >> 4) * 8;
    f4v acc = (f4v){0.f, 0.f, 0.f, 0.f};
#pragma unroll
    for (int kc = 0; kc < 27; ++kc) {
        s8v a = *(const s8v*)(a1 + arow1 + kc * 32);
        s8v b = *(const s8v*)((const short*)B2n + ((size_t)((wave * 27 + kc) * 64 + lane)) * 8);
        acc = __builtin_amdgcn_mfma_f32_16x16x32_bf16(a, b, acc, 0, 0, 0);
    }
    {
        float bv = b2[wave * 16 + (lane & 15)];
        int n = wave * 16 + (lane & 15);
#pragma unroll
        for (int r = 0; r < 4; ++r) {
            int m = (lane >> 4) * 4 + r;
            float h = fmaxf(acc[r] + bv, 0.f);
            unsigned short hh = f2bf(h);
            unsigned short ll = f2bf(h - bf2f(hh));
            a2[m * 200 + n] = (short)hh;
            a2[m * 200 + 64 + n] = (short)hh;
            a2[m * 200 + 128 + n] = (short)ll;
        }
    }
    __syncthreads();
    int arow2 = (lane & 15) * 200 + (lane >> 4) * 8;
    f4v acc2 = (f4v){0.f, 0.f, 0.f, 0.f};
#pragma unroll
    for (int kc = 0; kc < 6; ++kc) {
        s8v a = *(const s8v*)(a2 + arow2 + kc * 32);
        s8v b = *(const s8v*)((const short*)B3 + ((size_t)((wave * 6 + kc) * 64 + lane)) * 8);
        acc2 = __builtin_amdgcn_mfma_f32_16x16x32_bf16(a, b, acc2, 0, 0, 0);
    }
    {
        float bv = b3[wave * 16 + (lane & 15)];
        int n = wave * 16 + (lane & 15);
#pragma unroll
        for (int r = 0; r < 4; ++r) {
            int m = (lane >> 4) * 4 + r;
            cz[m * 68 + n] = acc2[r] + bv;
        }
    }
    __syncthreads();
    {
        int m = tid >> 4, c4 = tid & 15;
        int pix = blk * 16 + m;
        if (pix < npix) {
            float4 v = *(float4*)(cz + m * 68 + c4 * 4);
            *(float4*)(z + (size_t)pix * 64 + c4 * 4) = v;
        }
    }
}

// ---- vq_m: MFMA distance GEMM + fused argmin + q gather + loss -------------
// M=32/block (2 m-tiles/wave, A-frags in regs), N=512 (4 waves x 8 nt),
// K=192 (zh,zh,zl x ch,cl,ch). First-min semantics: ascending-k scan,
// strict <, explicit k tie-break at every merge level.
__global__ __launch_bounds__(256) void k_vq_m(const float* __restrict__ z,
                                              const float* __restrict__ cb,
                                              const unsigned short* __restrict__ cbm,
                                              const float* __restrict__ cn,
                                              float* __restrict__ q,
                                              float* __restrict__ loss, int npix) {
    __shared__ short a_lds[32 * 200];  // 12.8 KB, row = [zh64|zh64|zl64] + pad8
    __shared__ float reds[4 * 32];
    __shared__ int   redk[4 * 32];
    __shared__ int   bkf[32];
    __shared__ float lred[4];
    int tid = threadIdx.x, blk = blockIdx.x;
    {   // stage: thread (m = tid>>3, p = tid&7) handles ci [p*8, p*8+8)
        int m = tid >> 3, p = tid & 7;
        int pix = blk * 32 + m;
        unsigned short zh[8], zl[8];
        if (pix < npix) {
            const float* src = z + (size_t)pix * 64 + p * 8;
#pragma unroll
            for (int v = 0; v < 8; ++v) {
                float f = src[v];
                unsigned short h = f2bf(f);
                zh[v] = h; zl[v] = f2bf(f - bf2f(h));
            }
        } else {
#pragma unroll
            for (int v = 0; v < 8; ++v) { zh[v] = 0; zl[v] = 0; }
        }
        unsigned ph[4], pl[4];
#pragma unroll
        for (int v = 0; v < 4; ++v) {
            ph[v] = (unsigned)zh[2 * v] | ((unsigned)zh[2 * v + 1] << 16);
            pl[v] = (unsigned)zl[2 * v] | ((unsigned)zl[2 * v + 1] << 16);
        }
        short* row = a_lds + m * 200;
        i4v vh = (i4v){(int)ph[0], (int)ph[1], (int)ph[2], (int)ph[3]};
        i4v vl = (i4v){(int)pl[0], (int)pl[1], (int)pl[2], (int)pl[3]};
        *(i4v*)(row + p * 8) = vh;        // k in [0,64): zh
        *(i4v*)(row + 64 + p * 8) = vh;   // k in [64,128): zh dup
        *(i4v*)(row + 128 + p * 8) = vl;  // k in [128,192): zl
    }
    __syncthreads();
    int wave = tid >> 6, lane = tid & 63;
    s8v af[2][6];  // A-frags for 2 m-tiles
#pragma unroll
    for (int mt = 0; mt < 2; ++mt) {
        int arow = (mt * 16 + (lane & 15)) * 200 + (lane >> 4) * 8;
#pragma unroll
        for (int kc = 0; kc < 6; ++kc)
            af[mt][kc] = *(const s8v*)(a_lds + arow + kc * 32);
    }
    float bd[2][4];
    int bk[2][4];
#pragma unroll
    for (int mt = 0; mt < 2; ++mt)
#pragma unroll
        for (int r = 0; r < 4; ++r) { bd[mt][r] = 3.4e38f; bk[mt][r] = 0; }
#pragma unroll 2
    for (int nt = 0; nt < 8; ++nt) {
        int ntg = wave * 8 + nt;
        s8v bf[6];
#pragma unroll
        for (int kc = 0; kc < 6; ++kc)
            bf[kc] = *(const s8v*)((const short*)cbm + ((size_t)((ntg * 6 + kc) * 64 + lane)) * 8);
        f4v acc0 = (f4v){0.f, 0.f, 0.f, 0.f};
        f4v acc1 = (f4v){0.f, 0.f, 0.f, 0.f};
#pragma unroll
        for (int kc = 0; kc < 6; ++kc) {
            acc0 = __builtin_amdgcn_mfma_f32_16x16x32_bf16(af[0][kc], bf[kc], acc0, 0, 0, 0);
            acc1 = __builtin_amdgcn_mfma_f32_16x16x32_bf16(af[1][kc], bf[kc], acc1, 0, 0, 0);
        }
        int kcol = ntg * 16 + (lane & 15);
        float cnk = cn[kcol];
#pragma unroll
        for (int r = 0; r < 4; ++r) {
            float d0 = cnk - 2.f * acc0[r];
            if (d0 < bd[0][r]) { bd[0][r] = d0; bk[0][r] = kcol; }
            float d1 = cnk - 2.f * acc1[r];
            if (d1 < bd[1][r]) { bd[1][r] = d1; bk[1][r] = kcol; }
        }
    }
    // butterfly argmin across the 16 columns
#pragma unroll
    for (int off = 1; off < 16; off <<= 1) {
#pragma unroll
        for (int mt = 0; mt < 2; ++mt)
#pragma unroll
            for (int r = 0; r < 4; ++r) {
                float od = __shfl_xor(bd[mt][r], off);
                int ok = __shfl_xor(bk[mt][r], off);
                if (od < bd[mt][r] || (od == bd[mt][r] && ok < bk[mt][r])) {
                    bd[mt][r] = od; bk[mt][r] = ok;
                }
            }
    }
    if ((lane & 15) == 0) {
#pragma unroll
        for (int mt = 0; mt < 2; ++mt)
#pragma unroll
            for (int r = 0; r < 4; ++r) {
                int m = mt * 16 + (lane >> 4) * 4 + r;
                reds[wave * 32 + m] = bd[mt][r];
                redk[wave * 32 + m] = bk[mt][r];
            }
    }
    __syncthreads();
    if (tid < 32) {  // merge 4 waves (ascending k ranges)
        float d0 = reds[tid]; int k0 = redk[tid];
#pragma unroll
        for (int w = 1; w < 4; ++w) {
            float dw = reds[w * 32 + tid]; int kw = redk[w * 32 + tid];
            if (dw < d0 || (dw == d0 && kw < k0)) { d0 = dw; k0 = kw; }
        }
        bkf[tid] = k0;
    }
    __syncthreads();
    float lsum = 0.f;
#pragma unroll
    for (int it = 0; it < 2; ++it) {
        int m = tid >> 3, c4 = (tid & 7) + it * 8;
        int pix = blk * 32 + m;
        if (pix < npix) {
            int k0 = bkf[m];
            float4 cq = ((const float4*)cb)[(size_t)k0 * 16 + c4];
            float4 zz = ((const float4*)(z + (size_t)pix * 64))[c4];
            float dx = cq.x - zz.x, dy = cq.y - zz.y, dz = cq.z - zz.z, dw = cq.w - zz.w;
            lsum += dx * dx + dy * dy + dz * dz + dw * dw;
            ((float4*)(q + (size_t)pix * 64))[c4] = cq;
        }
    }
#pragma unroll
    for (int off = 32; off > 0; off >>= 1) lsum += __shfl_down(lsum, off);
    if ((tid & 63) == 0) lred[tid >> 6] = lsum;
    __syncthreads();
    if (tid == 0) {
        float t = lred[0] + lred[1] + lred[2] + lred[3];
        atomicAdd(loss, t * (1.25f / 11075584.f));
    }
}

// ---- tconv1 MFMA: q f32 (13,13,64) -> d1 bf16 (25,25,64), relu -------------
__global__ __launch_bounds__(256) void k_tconv1_m(const float* __restrict__ q,
                                                  const unsigned short* __restrict__ wB,
                                                  const float* __restrict__ bias,
                                                  unsigned short* __restrict__ d1,
                                                  int nquad) {
    __shared__ short a_lds[16 * 264];
    __shared__ short c_lds[16 * 264];
    int tid = threadIdx.x, blk = blockIdx.x;
    {
        int m = tid >> 4, chunk = tid & 15;
        int qg = blk * 16 + m;
        unsigned short tmp[16];
        bool have = false;
        if (qg < nquad) {
            int img = qg / 169, r = qg % 169, qm = r / 13, qw = r % 13;
            int p = chunk >> 2, ci0 = (chunk & 3) * 16;
            int sm = qm + (p >> 1), sw = qw + (p & 1);
            if (sm < 13 && sw < 13) {
                const float* src = q + (((size_t)img * 13 + sm) * 13 + sw) * 64 + ci0;
#pragma unroll
                for (int v = 0; v < 16; ++v) tmp[v] = f2bf(src[v]);
                have = true;
            }
        }
        if (!have) {
#pragma unroll
            for (int v = 0; v < 16; ++v) tmp[v] = 0;
        }
        unsigned pk[8];
#pragma unroll
        for (int v = 0; v < 8; ++v) pk[v] = (unsigned)tmp[2 * v] | ((unsigned)tmp[2 * v + 1] << 16);
        i4v* dst = (i4v*)(a_lds + m * 264 + chunk * 16);
        dst[0] = (i4v){(int)pk[0], (int)pk[1], (int)pk[2], (int)pk[3]};
        dst[1] = (i4v){(int)pk[4], (int)pk[5], (int)pk[6], (int)pk[7]};
    }
    __syncthreads();
    int wave = tid >> 6, lane = tid & 63;
    f4v acc[4];
#pragma unroll
    for (int i = 0; i < 4; ++i) acc[i] = (f4v){0.f, 0.f, 0.f, 0.f};
    float bv[4];
#pragma unroll
    for (int i = 0; i < 4; ++i) bv[i] = bias[((wave * 4 + i) * 16 + (lane & 15)) & 63];
    int arow = (lane & 15) * 264 + (lane >> 4) * 8;
#pragma unroll
    for (int kc = 0; kc < 8; ++kc) {
        s8v a = *(const s8v*)(a_lds + arow + kc * 32);
#pragma unroll
        for (int i = 0; i < 4; ++i) {
            int nt = wave * 4 + i;
            s8v b = *(const s8v*)((const short*)wB + ((size_t)((nt * 8 + kc) * 64 + lane)) * 8);
            acc[i] = __builtin_amdgcn_mfma_f32_16x16x32_bf16(a, b, acc[i], 0, 0, 0);
        }
    }
#pragma unroll
    for (int i = 0; i < 4; ++i) {
        int n = (wave * 4 + i) * 16 + (lane & 15);
#pragma unroll
        for (int r2 = 0; r2 < 4; ++r2) {
            int m = (lane >> 4) * 4 + r2;
            float v = fmaxf(acc[i][r2] + bv[i], 0.f);
            c_lds[m * 264 + n] = (short)f2bf(v);
        }
    }
    __syncthreads();
#pragma unroll
    for (int ch2 = 0; ch2 < 2; ++ch2) {
        int ch = tid + ch2 * 256;
        int m = ch >> 5, cpart = ch & 31;
        int qg = blk * 16 + m;
        if (qg >= nquad) continue;
        int img = qg / 169, r = qg % 169, qm = r / 13, qw = r % 13;
        int cls = cpart >> 3, co8 = (cpart & 7) * 8;
        int oh = 2 * qm + (cls >> 1), ow = 2 * qw + (cls & 1);
        if (oh >= 25 || ow >= 25) continue;
        i4v val = *(i4v*)(c_lds + m * 264 + cls * 64 + co8);
        *(i4v*)(d1 + (((size_t)img * 25 + oh) * 25 + ow) * 64 + co8) = val;
    }
}

// ---- tconv2 MFMA: d1 bf16 (25,25,64) -> d2 bf16 (50,50,32), relu -----------
__global__ __launch_bounds__(256) void k_tconv2_m(const unsigned short* __restrict__ d1,
                                                  const unsigned short* __restrict__ wB,
                                                  const float* __restrict__ bias,
                                                  unsigned short* __restrict__ d2,
                                                  int nquad) {
    __shared__ short a_lds[16 * 264];
    __shared__ short c_lds[16 * 136];
    int tid = threadIdx.x, blk = blockIdx.x;
    {
        int m = tid >> 4, chunk = tid & 15;
        int qg = blk * 16 + m;
        i4v v0 = (i4v){0, 0, 0, 0}, v1 = v0;
        if (qg < nquad) {
            int img = qg / 625, r = qg % 625, qm = r / 25, qw = r % 25;
            int p = chunk >> 2, ci0 = (chunk & 3) * 16;
            int sm = qm + (p >> 1), sw = qw + (p & 1);
            if (sm < 25 && sw < 25) {
                const i4v* src = (const i4v*)(d1 + (((size_t)img * 25 + sm) * 25 + sw) * 64 + ci0);
                v0 = src[0]; v1 = src[1];
            }
        }
        i4v* dst = (i4v*)(a_lds + m * 264 + chunk * 16);
        dst[0] = v0; dst[1] = v1;
    }
    __syncthreads();
    int wave = tid >> 6, lane = tid & 63;
    f4v acc[2];
    acc[0] = (f4v){0.f, 0.f, 0.f, 0.f};
    acc[1] = acc[0];
    float bv[2];
#pragma unroll
    for (int i = 0; i < 2; ++i) bv[i] = bias[((wave * 2 + i) * 16 + (lane & 15)) & 31];
    int arow = (lane & 15) * 264 + (lane >> 4) * 8;
#pragma unroll
    for (int kc = 0; kc < 8; ++kc) {
        s8v a = *(const s8v*)(a_lds + arow + kc * 32);
#pragma unroll
        for (int i = 0; i < 2; ++i) {
            int nt = wave * 2 + i;
            s8v b = *(const s8v*)((const short*)wB + ((size_t)((nt * 8 + kc) * 64 + lane)) * 8);
            acc[i] = __builtin_amdgcn_mfma_f32_16x16x32_bf16(a, b, acc[i], 0, 0, 0);
        }
    }
#pragma unroll
    for (int i = 0; i < 2; ++i) {
        int n = (wave * 2 + i) * 16 + (lane & 15);
#pragma unroll
        for (int r2 = 0; r2 < 4; ++r2) {
            int m = (lane >> 4) * 4 + r2;
            float v = fmaxf(acc[i][r2] + bv[i], 0.f);
            c_lds[m * 136 + n] = (short)f2bf(v);
        }
    }
    __syncthreads();
    {
        int m = tid >> 4, cpart = tid & 15;
        int qg = blk * 16 + m;
        if (qg < nquad) {
            int img = qg / 625, r = qg % 625, qm = r / 25, qw = r % 25;
            int cls = cpart >> 2, co8 = (cpart & 3) * 8;
            int oh = 2 * qm + (cls >> 1), ow = 2 * qw + (cls & 1);
            i4v val = *(i4v*)(c_lds + m * 136 + cls * 32 + co8);
            *(i4v*)(d2 + (((size_t)img * 50 + oh) * 50 + ow) * 32 + co8) = val;
        }
    }
}

// ---- convf: d2 bf16 (bc,50,50,32) -> out f32 (bc,50,50), sigmoid -----------
__global__ __launch_bounds__(256) void k_convf(const unsigned short* __restrict__ in,
                                               const float* __restrict__ w,  // dw3 (1,32,3,3)
                                               const float* __restrict__ b,
                                               float* __restrict__ out, int total) {
    __shared__ float wl[288];  // [tap9][ci32]
    int tid = threadIdx.x;
    for (int t = tid; t < 288; t += 256) {
        int tap = t >> 5, ci = t & 31;
        wl[t] = w[ci * 9 + tap];
    }
    __syncthreads();
    int pix = blockIdx.x * 256 + tid;
    if (pix >= total) return;
    int n = pix / 2500, p = pix % 2500, oh = p / 50, ow = p % 50;
    float acc = b[0];
#pragma unroll
    for (int kh = 0; kh < 3; ++kh) {
        int ih = oh - 1 + kh;
        if ((unsigned)ih >= 50u) continue;
#pragma unroll
        for (int kw = 0; kw < 3; ++kw) {
            int iw = ow - 1 + kw;
            if ((unsigned)iw >= 50u) continue;
            const float* wt = wl + (kh * 3 + kw) * 32;
            const i4v* ip4 = (const i4v*)(in + (((size_t)n * 50 + ih) * 50 + iw) * 32);
#pragma unroll
            for (int c8 = 0; c8 < 4; ++c8) {
                i4v u = ip4[c8];
#pragma unroll
                for (int e = 0; e < 4; ++e) {
                    unsigned uu = (unsigned)u[e];
                    float x0 = __builtin_bit_cast(float, uu << 16);
                    float x1 = __builtin_bit_cast(float, uu & 0xffff0000u);
                    acc = fmaf(x0, wt[c8 * 8 + e * 2], acc);
                    acc = fmaf(x1, wt[c8 * 8 + e * 2 + 1], acc);
                }
            }
        }
    }
    out[pix] = 1.f / (1.f + expf(-acc));
}

extern "C" void kernel_launch(void* const* d_in, const int* in_sizes, int n_in,
                              void* d_out, int out_size, void* d_ws, size_t ws_size,
                              hipStream_t stream) {
    const float* x   = (const float*)d_in[0];
    const float* ew1 = (const float*)d_in[1];
    const float* eb1 = (const float*)d_in[2];
    const float* ew2 = (const float*)d_in[3];
    const float* eb2 = (const float*)d_in[4];
    const float* ew3 = (const float*)d_in[5];
    const float* eb3 = (const float*)d_in[6];
    const float* cb  = (const float*)d_in[7];
    const float* dw1 = (const float*)d_in[8];
    const float* db1 = (const float*)d_in[9];
    const float* dw2 = (const float*)d_in[10];
    const float* db2 = (const float*)d_in[11];
    const float* dw3 = (const float*)d_in[12];
    const float* db3 = (const float*)d_in[13];
    float* out = (float*)d_out;
    float* loss = out + 2560000;

    float* ws = (float*)d_ws;
    float* cn = ws;                                        // 512 f
    unsigned short* wB1  = (unsigned short*)(ws + 512);    // 65536 sh = 32768 f
    unsigned short* wB2  = (unsigned short*)(ws + 33280);  // 32768 sh = 16384 f
    unsigned short* wB2n = (unsigned short*)(ws + 49664);  // 55296 sh = 27648 f
    unsigned short* wB3  = (unsigned short*)(ws + 77312);  // 12288 sh = 6144 f
    unsigned short* cbm  = (unsigned short*)(ws + 83456);  // 98304 sh = 49152 f
    const size_t tw_floats = 132608;

    const int B = 1024;
    // regA 40000 f/img: h1 (20000), q (10816), d2-bf16 (80000 sh)
    // regB 20000 f/img: z (10816), d1-bf16 (40000 sh)
    const size_t A_per = 40000, B_per = 20000;
    size_t avail = (ws_size / 4 > tw_floats) ? ws_size / 4 - tw_floats : 0;
    int BC = (int)(avail / (A_per + B_per));
    if (BC > B) BC = B;
    if (BC < 1) BC = 1;
    float* regA = ws + tw_floats;
    float* regB = regA + (size_t)BC * A_per;

    k_zero<<<1, 64, 0, stream>>>(loss);
    k_prep_cn <<<2, 256, 0, stream>>>(cb, cn);
    k_prep_cbm<<<384, 256, 0, stream>>>(cb, cbm);
    k_prep_B2n<<<216, 256, 0, stream>>>(ew2, wB2n);
    k_prep_B3 <<<48, 256, 0, stream>>>(ew3, wB3);
    k_prep_B1 <<<256, 256, 0, stream>>>(dw1, wB1);
    k_prep_B2 <<<128, 256, 0, stream>>>(dw2, wB2);

    for (int n0 = 0; n0 < B; n0 += BC) {
        int bc = (B - n0 < BC) ? (B - n0) : BC;
        const float* xch = x + (size_t)n0 * 2500;

        int t1 = bc * 625;   // conv1: x -> h1 (regA)
        k_conv1<<<(t1 + 255) / 256, 256, 0, stream>>>(xch, ew1, eb1, regA, t1);

        int npix = bc * 169;
        // fused conv2+conv3 MFMA: h1 (regA) -> z (regB)
        k_enc_m<<<(npix + 15) / 16, 256, 0, stream>>>(regA, wB2n, wB3, eb2, eb3, regB, npix);

        // MFMA VQ: z (regB) -> q (regA) + loss
        k_vq_m<<<(npix + 31) / 32, 256, 0, stream>>>(regB, cb, cbm, cn, regA, loss, npix);

        // tconv1 MFMA: q (regA f32) -> d1 (regB bf16)
        unsigned short* d1 = (unsigned short*)regB;
        k_tconv1_m<<<(npix + 15) / 16, 256, 0, stream>>>(regA, wB1, db1, d1, npix);

        // tconv2 MFMA: d1 (regB bf16) -> d2 (regA bf16)
        int nq2 = bc * 625;
        unsigned short* d2 = (unsigned short*)regA;
        k_tconv2_m<<<(nq2 + 15) / 16, 256, 0, stream>>>(d1, wB2, db2, d2, nq2);

        int t6 = bc * 2500;  // convf: d2 bf16 (regA) -> out
        k_convf<<<(t6 + 255) / 256, 256, 0, stream>>>(d2, dw3, db3, out + (size_t)n0 * 2500, t6);
    }
}

// Round 13
// 513.637 us; speedup vs baseline: 6.9867x; 1.0488x over previous
//
#include <hip/hip_runtime.h>
#include <math.h>

// ---------------------------------------------------------------------------
// VQ-VAE forward. R13: tconv1/tconv2 restructured like R12's vq_m —
// M=32/block (2 m-tiles per wave, A-frags in regs => 2 MFMA per B-load,
// halves B L2-traffic) and conflict-free 16B/thread LDS staging.
//  conv1: x -> h1 (n,25,25,32) f32            [regA]
//  enc_m: h1 -> z (n,13,13,64) f32            [regB]
//  vq_m:  z -> q f32 [regA] + loss
//  tconv1 MFMA: q -> d1 (n,25,25,64) bf16     [regB]
//  tconv2 MFMA: d1 -> d2 (n,50,50,32) bf16    [regA]
//  convf k3s1p1+sigm (bf16 in, fp32 math) -> out (n,50,50)
// ---------------------------------------------------------------------------

typedef __attribute__((ext_vector_type(8))) short s8v;   // 8 bf16 frag
typedef __attribute__((ext_vector_type(4))) float f4v;   // MFMA acc
typedef __attribute__((ext_vector_type(4))) int i4v;

__device__ inline unsigned short f2bf(float f) {  // RNE fp32->bf16
    unsigned u = __builtin_bit_cast(unsigned, f);
    return (unsigned short)((u + 0x7fffu + ((u >> 16) & 1u)) >> 16);
}
__device__ inline float bf2f(unsigned short h) {
    return __builtin_bit_cast(float, ((unsigned)h) << 16);
}

__global__ __launch_bounds__(64) void k_zero(float* __restrict__ p) {
    if (threadIdx.x == 0 && blockIdx.x == 0) *p = 0.f;
}

// ---- weight preps ----------------------------------------------------------
__global__ __launch_bounds__(256) void k_prep_cn(const float* __restrict__ cb,
                                                 float* __restrict__ cn) {
    int k = blockIdx.x * 256 + threadIdx.x;  // 512
    const float* r = cb + k * 64;
    float s = 0.f;
#pragma unroll
    for (int c = 0; c < 64; ++c) s += r[c] * r[c];
    cn[k] = s;
}
// cbm: VQ codebook 3-product split-bf16 B-frags. (nt32, kc6, lane64, j8)
__global__ __launch_bounds__(256) void k_prep_cbm(const float* __restrict__ cb,
                                                  unsigned short* __restrict__ o) {
    int i = blockIdx.x * 256 + threadIdx.x;  // 98304
    int j = i & 7, lane = (i >> 3) & 63;
    int kc = (i >> 9) % 6, nt = (i >> 9) / 6;
    int n = nt * 16 + (lane & 15);
    int k = kc * 32 + ((lane >> 4) << 3) + j;
    int seg = k >> 6, kk = k & 63;
    float c = cb[n * 64 + kk];
    unsigned short ch = f2bf(c);
    o[i] = (seg == 1) ? f2bf(c - bf2f(ch)) : ch;
}
// B2n: conv2 split-bf16 B (nt4, kc27, lane64, j8); K1=864 = [hi288|lo288|hi288]
__global__ __launch_bounds__(256) void k_prep_B2n(const float* __restrict__ w,  // ew2 (64,32,3,3)
                                                  unsigned short* __restrict__ o) {
    int i = blockIdx.x * 256 + threadIdx.x;  // 55296
    if (i >= 55296) return;
    int j = i & 7, lane = (i >> 3) & 63;
    int kc = (i >> 9) % 27, nt = (i >> 9) / 27;
    int k = kc * 32 + ((lane >> 4) << 3) + j;
    int co = nt * 16 + (lane & 15);
    int part = (k < 288) ? 0 : (k < 576) ? 1 : 0;
    int kk = (k < 288) ? k : (k < 576) ? k - 288 : k - 576;
    int tap = kk >> 5, ci = kk & 31;
    float v = w[(co * 32 + ci) * 9 + tap];
    unsigned short hi = f2bf(v);
    o[i] = part ? f2bf(v - bf2f(hi)) : hi;
}
// B3: conv3 split-bf16 B (nt4, kc6, lane64, j8); K2=192 = [hi64|lo64|hi64]
__global__ __launch_bounds__(256) void k_prep_B3(const float* __restrict__ w,  // ew3 (64,64)
                                                 unsigned short* __restrict__ o) {
    int i = blockIdx.x * 256 + threadIdx.x;  // 12288
    if (i >= 12288) return;
    int j = i & 7, lane = (i >> 3) & 63;
    int kc = (i >> 9) % 6, nt = (i >> 9) / 6;
    int k = kc * 32 + ((lane >> 4) << 3) + j;
    int n = nt * 16 + (lane & 15);
    int part = (k < 64) ? 0 : (k < 128) ? 1 : 0;
    int kk = (k < 64) ? k : (k < 128) ? k - 64 : k - 128;
    float v = w[n * 64 + kk];
    unsigned short hi = f2bf(v);
    o[i] = part ? f2bf(v - bf2f(hi)) : hi;
}
// Zero-padded tconv weight matrices
__global__ __launch_bounds__(256) void k_prep_B1(const float* __restrict__ w,  // dw1 (64,64,3,3)
                                                 unsigned short* __restrict__ o) {
    int i = blockIdx.x * 256 + threadIdx.x;  // 65536
    int j = i & 7, l = (i >> 3) & 63, kc = (i >> 9) & 7, nt = i >> 12;
    int n = nt * 16 + (l & 15), k = kc * 32 + (l >> 4) * 8 + j;
    int cls = n >> 6, co = n & 63, p = k >> 6, ci = k & 63;
    int jh = -1, jw = -1;
    if (cls == 0)      { if (p == 0) { jh = 1; jw = 1; } }
    else if (cls == 1) { if (p == 1) { jh = 1; jw = 0; } else if (p == 0) { jh = 1; jw = 2; } }
    else if (cls == 2) { if (p == 2) { jh = 0; jw = 1; } else if (p == 0) { jh = 2; jw = 1; } }
    else { if (p == 3) { jh = 0; jw = 0; } else if (p == 2) { jh = 0; jw = 2; }
           else if (p == 1) { jh = 2; jw = 0; } else { jh = 2; jw = 2; } }
    float v = (jh >= 0) ? w[((co * 64 + ci) * 3 + jh) * 3 + jw] : 0.f;
    o[i] = f2bf(v);
}
__global__ __launch_bounds__(256) void k_prep_B2(const float* __restrict__ w,  // dw2 (32,64,3,3)
                                                 unsigned short* __restrict__ o) {
    int i = blockIdx.x * 256 + threadIdx.x;  // 32768
    int j = i & 7, l = (i >> 3) & 63, kc = (i >> 9) & 7, nt = i >> 12;
    int n = nt * 16 + (l & 15), k = kc * 32 + (l >> 4) * 8 + j;
    int cls = n >> 5, co = n & 31, p = k >> 6, ci = k & 63;
    int jh = -1, jw = -1;
    if (cls == 0)      { if (p == 0) { jh = 1; jw = 1; } }
    else if (cls == 1) { if (p == 1) { jh = 1; jw = 0; } else if (p == 0) { jh = 1; jw = 2; } }
    else if (cls == 2) { if (p == 2) { jh = 0; jw = 1; } else if (p == 0) { jh = 2; jw = 1; } }
    else { if (p == 3) { jh = 0; jw = 0; } else if (p == 2) { jh = 0; jw = 2; }
           else if (p == 1) { jh = 2; jw = 0; } else { jh = 2; jw = 2; } }
    float v = (jh >= 0) ? w[((co * 64 + ci) * 3 + jh) * 3 + jw] : 0.f;
    o[i] = f2bf(v);
}

// ---- conv1: x (bc,50,50) -> h1 (bc,25,25,32) f32, relu ---------------------
__global__ __launch_bounds__(256) void k_conv1(const float* __restrict__ x,
                                               const float* __restrict__ w,
                                               const float* __restrict__ b,
                                               float* __restrict__ h1, int total) {
    __shared__ float4 wl4[72];
    float* wl = (float*)wl4;
    int tid = threadIdx.x;
    for (int t = tid; t < 288; t += 256) {
        int tap = t >> 5, co = t & 31;
        wl[t] = w[co * 9 + tap];
    }
    __syncthreads();
    int pix = blockIdx.x * 256 + tid;
    if (pix >= total) return;
    int n = pix / 625, p = pix % 625, oh = p / 25, ow = p % 25;
    const float* xp = x + (size_t)n * 2500;
    float4 a[8];
#pragma unroll
    for (int j = 0; j < 8; ++j) a[j] = ((const float4*)b)[j];
#pragma unroll
    for (int kh = 0; kh < 3; ++kh) {
        int ih = 2 * oh - 1 + kh;
        if ((unsigned)ih >= 50u) continue;
#pragma unroll
        for (int kw = 0; kw < 3; ++kw) {
            int iw = 2 * ow - 1 + kw;
            if ((unsigned)iw >= 50u) continue;
            float v = xp[ih * 50 + iw];
            int tap = kh * 3 + kw;
#pragma unroll
            for (int j = 0; j < 8; ++j) {
                float4 ww = wl4[tap * 8 + j];
                a[j].x += v * ww.x; a[j].y += v * ww.y;
                a[j].z += v * ww.z; a[j].w += v * ww.w;
            }
        }
    }
    float4* op = (float4*)(h1 + (size_t)pix * 32);
#pragma unroll
    for (int j = 0; j < 8; ++j) {
        float4 r;
        r.x = fmaxf(a[j].x, 0.f); r.y = fmaxf(a[j].y, 0.f);
        r.z = fmaxf(a[j].z, 0.f); r.w = fmaxf(a[j].w, 0.f);
        op[j] = r;
    }
}

// ---- enc_m: fused conv2(k3s2p1)+relu+conv3(1x1), split-bf16 MFMA -----------
__global__ __launch_bounds__(256) void k_enc_m(const float* __restrict__ h1,
                                               const unsigned short* __restrict__ B2n,
                                               const unsigned short* __restrict__ B3,
                                               const float* __restrict__ b2,
                                               const float* __restrict__ b3,
                                               float* __restrict__ z, int npix) {
    __shared__ short a1[16 * 872];
    __shared__ short a2[16 * 200];
    __shared__ float cz[16 * 68];
    int tid = threadIdx.x, blk = blockIdx.x;
    {
        int m = tid >> 4, chunk = tid & 15;
        if (chunk < 9) {
            int pix = blk * 16 + m;
            float4 v[8];
            const float4 zero = {0.f, 0.f, 0.f, 0.f};
            bool ok = false;
            if (pix < npix) {
                int n = pix / 169, p = pix % 169, oh = p / 13, ow = p % 13;
                int kh = chunk / 3, kw = chunk % 3;
                int ih = 2 * oh - 1 + kh, iw = 2 * ow - 1 + kw;
                ok = ((unsigned)ih < 25u) && ((unsigned)iw < 25u);
                if (ok) {
                    const float4* ip = (const float4*)(h1 + (((size_t)n * 25 + ih) * 25 + iw) * 32);
#pragma unroll
                    for (int c4 = 0; c4 < 8; ++c4) v[c4] = ip[c4];
                }
            }
            if (!ok) {
#pragma unroll
                for (int c4 = 0; c4 < 8; ++c4) v[c4] = zero;
            }
            unsigned short hi[32], lo[32];
#pragma unroll
            for (int c4 = 0; c4 < 8; ++c4) {
                float vv[4] = {v[c4].x, v[c4].y, v[c4].z, v[c4].w};
#pragma unroll
                for (int e = 0; e < 4; ++e) {
                    int ci = c4 * 4 + e;
                    unsigned short h = f2bf(vv[e]);
                    hi[ci] = h;
                    lo[ci] = f2bf(vv[e] - bf2f(h));
                }
            }
            short* row = a1 + m * 872 + chunk * 32;
            i4v* d0 = (i4v*)row;
            i4v* d1 = (i4v*)(row + 288);
            i4v* d2 = (i4v*)(row + 576);
#pragma unroll
            for (int g = 0; g < 4; ++g) {
                i4v ph, pl;
#pragma unroll
                for (int e = 0; e < 4; ++e) {
                    int b0 = g * 8 + e * 2;
                    ph[e] = (int)((unsigned)hi[b0] | ((unsigned)hi[b0 + 1] << 16));
                    pl[e] = (int)((unsigned)lo[b0] | ((unsigned)lo[b0 + 1] << 16));
                }
                d0[g] = ph; d1[g] = ph; d2[g] = pl;
            }
        }
    }
    __syncthreads();
    int wave = tid >> 6, lane = tid & 63;
    int arow1 = (lane & 15) * 872 + (lane >> 4) * 8;
    f4v acc = (f4v){0.f, 0.f, 0.f, 0.f};
#pragma unroll
    for (int kc = 0; kc < 27; ++kc) {
        s8v a = *(const s8v*)(a1 + arow1 + kc * 32);
        s8v b = *(const s8v*)((const short*)B2n + ((size_t)((wave * 27 + kc) * 64 + lane)) * 8);
        acc = __builtin_amdgcn_mfma_f32_16x16x32_bf16(a, b, acc, 0, 0, 0);
    }
    {
        float bv = b2[wave * 16 + (lane & 15)];
        int n = wave * 16 + (lane & 15);
#pragma unroll
        for (int r = 0; r < 4; ++r) {
            int m = (lane >> 4) * 4 + r;
            float h = fmaxf(acc[r] + bv, 0.f);
            unsigned short hh = f2bf(h);
            unsigned short ll = f2bf(h - bf2f(hh));
            a2[m * 200 + n] = (short)hh;
            a2[m * 200 + 64 + n] = (short)hh;
            a2[m * 200 + 128 + n] = (short)ll;
        }
    }
    __syncthreads();
    int arow2 = (lane & 15) * 200 + (lane >> 4) * 8;
    f4v acc2 = (f4v){0.f, 0.f, 0.f, 0.f};
#pragma unroll
    for (int kc = 0; kc < 6; ++kc) {
        s8v a = *(const s8v*)(a2 + arow2 + kc * 32);
        s8v b = *(const s8v*)((const short*)B3 + ((size_t)((wave * 6 + kc) * 64 + lane)) * 8);
        acc2 = __builtin_amdgcn_mfma_f32_16x16x32_bf16(a, b, acc2, 0, 0, 0);
    }
    {
        float bv = b3[wave * 16 + (lane & 15)];
        int n = wave * 16 + (lane & 15);
#pragma unroll
        for (int r = 0; r < 4; ++r) {
            int m = (lane >> 4) * 4 + r;
            cz[m * 68 + n] = acc2[r] + bv;
        }
    }
    __syncthreads();
    {
        int m = tid >> 4, c4 = tid & 15;
        int pix = blk * 16 + m;
        if (pix < npix) {
            float4 v = *(float4*)(cz + m * 68 + c4 * 4);
            *(float4*)(z + (size_t)pix * 64 + c4 * 4) = v;
        }
    }
}

// ---- vq_m: MFMA distance GEMM + fused argmin + q gather + loss (R12) -------
__global__ __launch_bounds__(256) void k_vq_m(const float* __restrict__ z,
                                              const float* __restrict__ cb,
                                              const unsigned short* __restrict__ cbm,
                                              const float* __restrict__ cn,
                                              float* __restrict__ q,
                                              float* __restrict__ loss, int npix) {
    __shared__ short a_lds[32 * 200];
    __shared__ float reds[4 * 32];
    __shared__ int   redk[4 * 32];
    __shared__ int   bkf[32];
    __shared__ float lred[4];
    int tid = threadIdx.x, blk = blockIdx.x;
    {
        int m = tid >> 3, p = tid & 7;
        int pix = blk * 32 + m;
        unsigned short zh[8], zl[8];
        if (pix < npix) {
            const float* src = z + (size_t)pix * 64 + p * 8;
#pragma unroll
            for (int v = 0; v < 8; ++v) {
                float f = src[v];
                unsigned short h = f2bf(f);
                zh[v] = h; zl[v] = f2bf(f - bf2f(h));
            }
        } else {
#pragma unroll
            for (int v = 0; v < 8; ++v) { zh[v] = 0; zl[v] = 0; }
        }
        unsigned ph[4], pl[4];
#pragma unroll
        for (int v = 0; v < 4; ++v) {
            ph[v] = (unsigned)zh[2 * v] | ((unsigned)zh[2 * v + 1] << 16);
            pl[v] = (unsigned)zl[2 * v] | ((unsigned)zl[2 * v + 1] << 16);
        }
        short* row = a_lds + m * 200;
        i4v vh = (i4v){(int)ph[0], (int)ph[1], (int)ph[2], (int)ph[3]};
        i4v vl = (i4v){(int)pl[0], (int)pl[1], (int)pl[2], (int)pl[3]};
        *(i4v*)(row + p * 8) = vh;
        *(i4v*)(row + 64 + p * 8) = vh;
        *(i4v*)(row + 128 + p * 8) = vl;
    }
    __syncthreads();
    int wave = tid >> 6, lane = tid & 63;
    s8v af[2][6];
#pragma unroll
    for (int mt = 0; mt < 2; ++mt) {
        int arow = (mt * 16 + (lane & 15)) * 200 + (lane >> 4) * 8;
#pragma unroll
        for (int kc = 0; kc < 6; ++kc)
            af[mt][kc] = *(const s8v*)(a_lds + arow + kc * 32);
    }
    float bd[2][4];
    int bk[2][4];
#pragma unroll
    for (int mt = 0; mt < 2; ++mt)
#pragma unroll
        for (int r = 0; r < 4; ++r) { bd[mt][r] = 3.4e38f; bk[mt][r] = 0; }
#pragma unroll 2
    for (int nt = 0; nt < 8; ++nt) {
        int ntg = wave * 8 + nt;
        s8v bf[6];
#pragma unroll
        for (int kc = 0; kc < 6; ++kc)
            bf[kc] = *(const s8v*)((const short*)cbm + ((size_t)((ntg * 6 + kc) * 64 + lane)) * 8);
        f4v acc0 = (f4v){0.f, 0.f, 0.f, 0.f};
        f4v acc1 = (f4v){0.f, 0.f, 0.f, 0.f};
#pragma unroll
        for (int kc = 0; kc < 6; ++kc) {
            acc0 = __builtin_amdgcn_mfma_f32_16x16x32_bf16(af[0][kc], bf[kc], acc0, 0, 0, 0);
            acc1 = __builtin_amdgcn_mfma_f32_16x16x32_bf16(af[1][kc], bf[kc], acc1, 0, 0, 0);
        }
        int kcol = ntg * 16 + (lane & 15);
        float cnk = cn[kcol];
#pragma unroll
        for (int r = 0; r < 4; ++r) {
            float d0 = cnk - 2.f * acc0[r];
            if (d0 < bd[0][r]) { bd[0][r] = d0; bk[0][r] = kcol; }
            float d1 = cnk - 2.f * acc1[r];
            if (d1 < bd[1][r]) { bd[1][r] = d1; bk[1][r] = kcol; }
        }
    }
#pragma unroll
    for (int off = 1; off < 16; off <<= 1) {
#pragma unroll
        for (int mt = 0; mt < 2; ++mt)
#pragma unroll
            for (int r = 0; r < 4; ++r) {
                float od = __shfl_xor(bd[mt][r], off);
                int ok = __shfl_xor(bk[mt][r], off);
                if (od < bd[mt][r] || (od == bd[mt][r] && ok < bk[mt][r])) {
                    bd[mt][r] = od; bk[mt][r] = ok;
                }
            }
    }
    if ((lane & 15) == 0) {
#pragma unroll
        for (int mt = 0; mt < 2; ++mt)
#pragma unroll
            for (int r = 0; r < 4; ++r) {
                int m = mt * 16 + (lane >> 4) * 4 + r;
                reds[wave * 32 + m] = bd[mt][r];
                redk[wave * 32 + m] = bk[mt][r];
            }
    }
    __syncthreads();
    if (tid < 32) {
        float d0 = reds[tid]; int k0 = redk[tid];
#pragma unroll
        for (int w = 1; w < 4; ++w) {
            float dw = reds[w * 32 + tid]; int kw = redk[w * 32 + tid];
            if (dw < d0 || (dw == d0 && kw < k0)) { d0 = dw; k0 = kw; }
        }
        bkf[tid] = k0;
    }
    __syncthreads();
    float lsum = 0.f;
#pragma unroll
    for (int it = 0; it < 2; ++it) {
        int m = tid >> 3, c4 = (tid & 7) + it * 8;
        int pix = blk * 32 + m;
        if (pix < npix) {
            int k0 = bkf[m];
            float4 cq = ((const float4*)cb)[(size_t)k0 * 16 + c4];
            float4 zz = ((const float4*)(z + (size_t)pix * 64))[c4];
            float dx = cq.x - zz.x, dy = cq.y - zz.y, dz = cq.z - zz.z, dw = cq.w - zz.w;
            lsum += dx * dx + dy * dy + dz * dz + dw * dw;
            ((float4*)(q + (size_t)pix * 64))[c4] = cq;
        }
    }
#pragma unroll
    for (int off = 32; off > 0; off >>= 1) lsum += __shfl_down(lsum, off);
    if ((tid & 63) == 0) lred[tid >> 6] = lsum;
    __syncthreads();
    if (tid == 0) {
        float t = lred[0] + lred[1] + lred[2] + lred[3];
        atomicAdd(loss, t * (1.25f / 11075584.f));
    }
}

// ---- tconv1 MFMA: q f32 -> d1 bf16 (25,25,64), relu. M=32/block ------------
// 2 m-tiles/wave (A in regs), 4 n-tiles/wave (N=256): 32 B-loads, 64 MFMAs.
__global__ __launch_bounds__(256) void k_tconv1_m(const float* __restrict__ q,
                                                  const unsigned short* __restrict__ wB,
                                                  const float* __restrict__ bias,
                                                  unsigned short* __restrict__ d1,
                                                  int nquad) {
    __shared__ short a_lds[32 * 264];  // 16.9 KB
    __shared__ short c_lds[32 * 264];  // 16.9 KB
    int tid = threadIdx.x, blk = blockIdx.x;
    // stage A: 4 passes, 16B/thread (quarter-wave contiguous -> conflict-free)
#pragma unroll
    for (int pass = 0; pass < 4; ++pass) {
        int idx = tid + pass * 256;          // 1024 chunks
        int m = idx >> 5, sub = idx & 31;    // sub*8 = k offset
        int qg = blk * 32 + m;
        int p = sub >> 3, ci0 = (sub & 7) * 8;
        unsigned short t8[8];
        bool have = false;
        if (qg < nquad) {
            int img = qg / 169, r = qg % 169, qm = r / 13, qw = r % 13;
            int sm = qm + (p >> 1), sw = qw + (p & 1);
            if (sm < 13 && sw < 13) {
                const float* src = q + (((size_t)img * 13 + sm) * 13 + sw) * 64 + ci0;
#pragma unroll
                for (int v = 0; v < 8; ++v) t8[v] = f2bf(src[v]);
                have = true;
            }
        }
        if (!have) {
#pragma unroll
            for (int v = 0; v < 8; ++v) t8[v] = 0;
        }
        i4v pk;
#pragma unroll
        for (int e = 0; e < 4; ++e)
            pk[e] = (int)((unsigned)t8[2 * e] | ((unsigned)t8[2 * e + 1] << 16));
        *(i4v*)(a_lds + m * 264 + sub * 8) = pk;
    }
    __syncthreads();
    int wave = tid >> 6, lane = tid & 63;
    f4v acc[2][4];
#pragma unroll
    for (int mt = 0; mt < 2; ++mt)
#pragma unroll
        for (int i = 0; i < 4; ++i) acc[mt][i] = (f4v){0.f, 0.f, 0.f, 0.f};
    float bv[4];
#pragma unroll
    for (int i = 0; i < 4; ++i) bv[i] = bias[((wave * 4 + i) * 16 + (lane & 15)) & 63];
#pragma unroll
    for (int kc = 0; kc < 8; ++kc) {
        s8v a0 = *(const s8v*)(a_lds + ((lane & 15)) * 264 + (lane >> 4) * 8 + kc * 32);
        s8v a1 = *(const s8v*)(a_lds + (16 + (lane & 15)) * 264 + (lane >> 4) * 8 + kc * 32);
#pragma unroll
        for (int i = 0; i < 4; ++i) {
            int nt = wave * 4 + i;
            s8v b = *(const s8v*)((const short*)wB + ((size_t)((nt * 8 + kc) * 64 + lane)) * 8);
            acc[0][i] = __builtin_amdgcn_mfma_f32_16x16x32_bf16(a0, b, acc[0][i], 0, 0, 0);
            acc[1][i] = __builtin_amdgcn_mfma_f32_16x16x32_bf16(a1, b, acc[1][i], 0, 0, 0);
        }
    }
#pragma unroll
    for (int mt = 0; mt < 2; ++mt)
#pragma unroll
        for (int i = 0; i < 4; ++i) {
            int n = (wave * 4 + i) * 16 + (lane & 15);
#pragma unroll
            for (int r2 = 0; r2 < 4; ++r2) {
                int m = mt * 16 + (lane >> 4) * 4 + r2;
                float v = fmaxf(acc[mt][i][r2] + bv[i], 0.f);
                c_lds[m * 264 + n] = (short)f2bf(v);
            }
        }
    __syncthreads();
#pragma unroll
    for (int pass = 0; pass < 4; ++pass) {
        int ch = tid + pass * 256;           // 1024 chunks of 8 co
        int m = ch >> 5, cpart = ch & 31;
        int qg = blk * 32 + m;
        if (qg >= nquad) continue;
        int img = qg / 169, r = qg % 169, qm = r / 13, qw = r % 13;
        int cls = cpart >> 3, co8 = (cpart & 7) * 8;
        int oh = 2 * qm + (cls >> 1), ow = 2 * qw + (cls & 1);
        if (oh >= 25 || ow >= 25) continue;
        i4v val = *(i4v*)(c_lds + m * 264 + cls * 64 + co8);
        *(i4v*)(d1 + (((size_t)img * 25 + oh) * 25 + ow) * 64 + co8) = val;
    }
}

// ---- tconv2 MFMA: d1 bf16 -> d2 bf16 (50,50,32), relu. M=32/block ----------
// 2 m-tiles/wave (A in regs), 2 n-tiles/wave (N=128): 16 B-loads, 32 MFMAs.
__global__ __launch_bounds__(256) void k_tconv2_m(const unsigned short* __restrict__ d1,
                                                  const unsigned short* __restrict__ wB,
                                                  const float* __restrict__ bias,
                                                  unsigned short* __restrict__ d2,
                                                  int nquad) {
    __shared__ short a_lds[32 * 264];  // 16.9 KB
    __shared__ short c_lds[32 * 136];  // 8.7 KB
    int tid = threadIdx.x, blk = blockIdx.x;
#pragma unroll
    for (int pass = 0; pass < 4; ++pass) {
        int idx = tid + pass * 256;
        int m = idx >> 5, sub = idx & 31;
        int qg = blk * 32 + m;
        int p = sub >> 3, ci0 = (sub & 7) * 8;
        i4v v = (i4v){0, 0, 0, 0};
        if (qg < nquad) {
            int img = qg / 625, r = qg % 625, qm = r / 25, qw = r % 25;
            int sm = qm + (p >> 1), sw = qw + (p & 1);
            if (sm < 25 && sw < 25)
                v = *(const i4v*)(d1 + (((size_t)img * 25 + sm) * 25 + sw) * 64 + ci0);
        }
        *(i4v*)(a_lds + m * 264 + sub * 8) = v;
    }
    __syncthreads();
    int wave = tid >> 6, lane = tid & 63;
    f4v acc[2][2];
#pragma unroll
    for (int mt = 0; mt < 2; ++mt)
#pragma unroll
        for (int i = 0; i < 2; ++i) acc[mt][i] = (f4v){0.f, 0.f, 0.f, 0.f};
    float bv[2];
#pragma unroll
    for (int i = 0; i < 2; ++i) bv[i] = bias[((wave * 2 + i) * 16 + (lane & 15)) & 31];
#pragma unroll
    for (int kc = 0; kc < 8; ++kc) {
        s8v a0 = *(const s8v*)(a_lds + ((lane & 15)) * 264 + (lane >> 4) * 8 + kc * 32);
        s8v a1 = *(const s8v*)(a_lds + (16 + (lane & 15)) * 264 + (lane >> 4) * 8 + kc * 32);
#pragma unroll
        for (int i = 0; i < 2; ++i) {
            int nt = wave * 2 + i;
            s8v b = *(const s8v*)((const short*)wB + ((size_t)((nt * 8 + kc) * 64 + lane)) * 8);
            acc[0][i] = __builtin_amdgcn_mfma_f32_16x16x32_bf16(a0, b, acc[0][i], 0, 0, 0);
            acc[1][i] = __builtin_amdgcn_mfma_f32_16x16x32_bf16(a1, b, acc[1][i], 0, 0, 0);
        }
    }
#pragma unroll
    for (int mt = 0; mt < 2; ++mt)
#pragma unroll
        for (int i = 0; i < 2; ++i) {
            int n = (wave * 2 + i) * 16 + (lane & 15);
#pragma unroll
            for (int r2 = 0; r2 < 4; ++r2) {
                int m = mt * 16 + (lane >> 4) * 4 + r2;
                float v = fmaxf(acc[mt][i][r2] + bv[i], 0.f);
                c_lds[m * 136 + n] = (short)f2bf(v);
            }
        }
    __syncthreads();
#pragma unroll
    for (int pass = 0; pass < 2; ++pass) {
        int ch = tid + pass * 256;           // 512 chunks of 8 co
        int m = ch >> 4, cpart = ch & 15;
        int qg = blk * 32 + m;
        if (qg >= nquad) continue;
        int img = qg / 625, r = qg % 625, qm = r / 25, qw = r % 25;
        int cls = cpart >> 2, co8 = (cpart & 3) * 8;
        int oh = 2 * qm + (cls >> 1), ow = 2 * qw + (cls & 1);
        i4v val = *(i4v*)(c_lds + m * 136 + cls * 32 + co8);
        *(i4v*)(d2 + (((size_t)img * 50 + oh) * 50 + ow) * 32 + co8) = val;
    }
}

// ---- convf: d2 bf16 (bc,50,50,32) -> out f32 (bc,50,50), sigmoid -----------
__global__ __launch_bounds__(256) void k_convf(const unsigned short* __restrict__ in,
                                               const float* __restrict__ w,  // dw3 (1,32,3,3)
                                               const float* __restrict__ b,
                                               float* __restrict__ out, int total) {
    __shared__ float wl[288];  // [tap9][ci32]
    int tid = threadIdx.x;
    for (int t = tid; t < 288; t += 256) {
        int tap = t >> 5, ci = t & 31;
        wl[t] = w[ci * 9 + tap];
    }
    __syncthreads();
    int pix = blockIdx.x * 256 + tid;
    if (pix >= total) return;
    int n = pix / 2500, p = pix % 2500, oh = p / 50, ow = p % 50;
    float acc = b[0];
#pragma unroll
    for (int kh = 0; kh < 3; ++kh) {
        int ih = oh - 1 + kh;
        if ((unsigned)ih >= 50u) continue;
#pragma unroll
        for (int kw = 0; kw < 3; ++kw) {
            int iw = ow - 1 + kw;
            if ((unsigned)iw >= 50u) continue;
            const float* wt = wl + (kh * 3 + kw) * 32;
            const i4v* ip4 = (const i4v*)(in + (((size_t)n * 50 + ih) * 50 + iw) * 32);
#pragma unroll
            for (int c8 = 0; c8 < 4; ++c8) {
                i4v u = ip4[c8];
#pragma unroll
                for (int e = 0; e < 4; ++e) {
                    unsigned uu = (unsigned)u[e];
                    float x0 = __builtin_bit_cast(float, uu << 16);
                    float x1 = __builtin_bit_cast(float, uu & 0xffff0000u);
                    acc = fmaf(x0, wt[c8 * 8 + e * 2], acc);
                    acc = fmaf(x1, wt[c8 * 8 + e * 2 + 1], acc);
                }
            }
        }
    }
    out[pix] = 1.f / (1.f + expf(-acc));
}

extern "C" void kernel_launch(void* const* d_in, const int* in_sizes, int n_in,
                              void* d_out, int out_size, void* d_ws, size_t ws_size,
                              hipStream_t stream) {
    const float* x   = (const float*)d_in[0];
    const float* ew1 = (const float*)d_in[1];
    const float* eb1 = (const float*)d_in[2];
    const float* ew2 = (const float*)d_in[3];
    const float* eb2 = (const float*)d_in[4];
    const float* ew3 = (const float*)d_in[5];
    const float* eb3 = (const float*)d_in[6];
    const float* cb  = (const float*)d_in[7];
    const float* dw1 = (const float*)d_in[8];
    const float* db1 = (const float*)d_in[9];
    const float* dw2 = (const float*)d_in[10];
    const float* db2 = (const float*)d_in[11];
    const float* dw3 = (const float*)d_in[12];
    const float* db3 = (const float*)d_in[13];
    float* out = (float*)d_out;
    float* loss = out + 2560000;

    float* ws = (float*)d_ws;
    float* cn = ws;                                        // 512 f
    unsigned short* wB1  = (unsigned short*)(ws + 512);    // 65536 sh
    unsigned short* wB2  = (unsigned short*)(ws + 33280);  // 32768 sh
    unsigned short* wB2n = (unsigned short*)(ws + 49664);  // 55296 sh
    unsigned short* wB3  = (unsigned short*)(ws + 77312);  // 12288 sh
    unsigned short* cbm  = (unsigned short*)(ws + 83456);  // 98304 sh
    const size_t tw_floats = 132608;

    const int B = 1024;
    const size_t A_per = 40000, B_per = 20000;
    size_t avail = (ws_size / 4 > tw_floats) ? ws_size / 4 - tw_floats : 0;
    int BC = (int)(avail / (A_per + B_per));
    if (BC > B) BC = B;
    if (BC < 1) BC = 1;
    float* regA = ws + tw_floats;
    float* regB = regA + (size_t)BC * A_per;

    k_zero<<<1, 64, 0, stream>>>(loss);
    k_prep_cn <<<2, 256, 0, stream>>>(cb, cn);
    k_prep_cbm<<<384, 256, 0, stream>>>(cb, cbm);
    k_prep_B2n<<<216, 256, 0, stream>>>(ew2, wB2n);
    k_prep_B3 <<<48, 256, 0, stream>>>(ew3, wB3);
    k_prep_B1 <<<256, 256, 0, stream>>>(dw1, wB1);
    k_prep_B2 <<<128, 256, 0, stream>>>(dw2, wB2);

    for (int n0 = 0; n0 < B; n0 += BC) {
        int bc = (B - n0 < BC) ? (B - n0) : BC;
        const float* xch = x + (size_t)n0 * 2500;

        int t1 = bc * 625;   // conv1: x -> h1 (regA)
        k_conv1<<<(t1 + 255) / 256, 256, 0, stream>>>(xch, ew1, eb1, regA, t1);

        int npix = bc * 169;
        // fused conv2+conv3 MFMA: h1 (regA) -> z (regB)
        k_enc_m<<<(npix + 15) / 16, 256, 0, stream>>>(regA, wB2n, wB3, eb2, eb3, regB, npix);

        // MFMA VQ: z (regB) -> q (regA) + loss
        k_vq_m<<<(npix + 31) / 32, 256, 0, stream>>>(regB, cb, cbm, cn, regA, loss, npix);

        // tconv1 MFMA: q (regA f32) -> d1 (regB bf16)
        unsigned short* d1 = (unsigned short*)regB;
        k_tconv1_m<<<(npix + 31) / 32, 256, 0, stream>>>(regA, wB1, db1, d1, npix);

        // tconv2 MFMA: d1 (regB bf16) -> d2 (regA bf16)
        int nq2 = bc * 625;
        unsigned short* d2 = (unsigned short*)regA;
        k_tconv2_m<<<(nq2 + 31) / 32, 256, 0, stream>>>(d1, wB2, db2, d2, nq2);

        int t6 = bc * 2500;  // convf: d2 bf16 (regA) -> out
        k_convf<<<(t6 + 255) / 256, 256, 0, stream>>>(d2, dw3, db3, out + (size_t)n0 * 2500, t6);
    }
}

// Round 14
// 503.667 us; speedup vs baseline: 7.1250x; 1.0198x over previous
//
#include <hip/hip_runtime.h>
#include <math.h>

// ---------------------------------------------------------------------------
// VQ-VAE forward. R14: vq_m M=64/block (4 m-tiles per wave => 4 MFMA per
// B-load, halves B L2-traffic); all weight preps fused into one kernel.
//  conv1: x -> h1 (n,25,25,32) f32            [regA]
//  enc_m: h1 -> z (n,13,13,64) f32            [regB]
//  vq_m:  z -> q f32 [regA] + loss
//  tconv1 MFMA: q -> d1 (n,25,25,64) bf16     [regB]
//  tconv2 MFMA: d1 -> d2 (n,50,50,32) bf16    [regA]
//  convf k3s1p1+sigm (bf16 in, fp32 math) -> out (n,50,50)
// ---------------------------------------------------------------------------

typedef __attribute__((ext_vector_type(8))) short s8v;   // 8 bf16 frag
typedef __attribute__((ext_vector_type(4))) float f4v;   // MFMA acc
typedef __attribute__((ext_vector_type(4))) int i4v;

__device__ inline unsigned short f2bf(float f) {  // RNE fp32->bf16
    unsigned u = __builtin_bit_cast(unsigned, f);
    return (unsigned short)((u + 0x7fffu + ((u >> 16) & 1u)) >> 16);
}
__device__ inline float bf2f(unsigned short h) {
    return __builtin_bit_cast(float, ((unsigned)h) << 16);
}

// ---- fused prep: cbm | B2n | B1 | B2 | B3 | cn | loss-zero ------------------
// segment offsets: cbm 0..98304, B2n ..153600, B1 ..219136, B2 ..251904,
// B3 ..264192, cn ..264704, loss-zero at 264704. grid = 1035 x 256.
__global__ __launch_bounds__(256) void k_prep_all(
        const float* __restrict__ cb,  const float* __restrict__ ew2,
        const float* __restrict__ ew3, const float* __restrict__ dw1,
        const float* __restrict__ dw2,
        unsigned short* __restrict__ cbm, unsigned short* __restrict__ wB2n,
        unsigned short* __restrict__ wB1, unsigned short* __restrict__ wB2,
        unsigned short* __restrict__ wB3, float* __restrict__ cn,
        float* __restrict__ loss) {
    int i = blockIdx.x * 256 + threadIdx.x;
    if (i < 98304) {
        // cbm: VQ codebook 3-product split (nt32, kc6, lane64, j8)
        int j = i & 7, lane = (i >> 3) & 63;
        int kc = (i >> 9) % 6, nt = (i >> 9) / 6;
        int n = nt * 16 + (lane & 15);
        int k = kc * 32 + ((lane >> 4) << 3) + j;
        int seg = k >> 6, kk = k & 63;
        float c = cb[n * 64 + kk];
        unsigned short ch = f2bf(c);
        cbm[i] = (seg == 1) ? f2bf(c - bf2f(ch)) : ch;
    } else if (i < 153600) {
        // B2n: conv2 split (nt4, kc27, lane64, j8); K1=864 = [hi288|lo288|hi288]
        int q = i - 98304;
        int j = q & 7, lane = (q >> 3) & 63;
        int kc = (q >> 9) % 27, nt = (q >> 9) / 27;
        int k = kc * 32 + ((lane >> 4) << 3) + j;
        int co = nt * 16 + (lane & 15);
        int part = (k < 288) ? 0 : (k < 576) ? 1 : 0;
        int kk = (k < 288) ? k : (k < 576) ? k - 288 : k - 576;
        int tap = kk >> 5, ci = kk & 31;
        float v = ew2[(co * 32 + ci) * 9 + tap];
        unsigned short hi = f2bf(v);
        wB2n[q] = part ? f2bf(v - bf2f(hi)) : hi;
    } else if (i < 219136) {
        // B1: tconv1 zero-padded (nt16, kc8, lane64, j8)
        int q = i - 153600;
        int j = q & 7, l = (q >> 3) & 63, kc = (q >> 9) & 7, nt = q >> 12;
        int n = nt * 16 + (l & 15), k = kc * 32 + (l >> 4) * 8 + j;
        int cls = n >> 6, co = n & 63, p = k >> 6, ci = k & 63;
        int jh = -1, jw = -1;
        if (cls == 0)      { if (p == 0) { jh = 1; jw = 1; } }
        else if (cls == 1) { if (p == 1) { jh = 1; jw = 0; } else if (p == 0) { jh = 1; jw = 2; } }
        else if (cls == 2) { if (p == 2) { jh = 0; jw = 1; } else if (p == 0) { jh = 2; jw = 1; } }
        else { if (p == 3) { jh = 0; jw = 0; } else if (p == 2) { jh = 0; jw = 2; }
               else if (p == 1) { jh = 2; jw = 0; } else { jh = 2; jw = 2; } }
        float v = (jh >= 0) ? dw1[((co * 64 + ci) * 3 + jh) * 3 + jw] : 0.f;
        wB1[q] = f2bf(v);
    } else if (i < 251904) {
        // B2: tconv2 zero-padded (nt8, kc8, lane64, j8)
        int q = i - 219136;
        int j = q & 7, l = (q >> 3) & 63, kc = (q >> 9) & 7, nt = q >> 12;
        int n = nt * 16 + (l & 15), k = kc * 32 + (l >> 4) * 8 + j;
        int cls = n >> 5, co = n & 31, p = k >> 6, ci = k & 63;
        int jh = -1, jw = -1;
        if (cls == 0)      { if (p == 0) { jh = 1; jw = 1; } }
        else if (cls == 1) { if (p == 1) { jh = 1; jw = 0; } else if (p == 0) { jh = 1; jw = 2; } }
        else if (cls == 2) { if (p == 2) { jh = 0; jw = 1; } else if (p == 0) { jh = 2; jw = 1; } }
        else { if (p == 3) { jh = 0; jw = 0; } else if (p == 2) { jh = 0; jw = 2; }
               else if (p == 1) { jh = 2; jw = 0; } else { jh = 2; jw = 2; } }
        float v = (jh >= 0) ? dw2[((co * 64 + ci) * 3 + jh) * 3 + jw] : 0.f;
        wB2[q] = f2bf(v);
    } else if (i < 264192) {
        // B3: conv3 split (nt4, kc6, lane64, j8); K2=192 = [hi64|lo64|hi64]
        int q = i - 251904;
        int j = q & 7, lane = (q >> 3) & 63;
        int kc = (q >> 9) % 6, nt = (q >> 9) / 6;
        int k = kc * 32 + ((lane >> 4) << 3) + j;
        int n = nt * 16 + (lane & 15);
        int part = (k < 64) ? 0 : (k < 128) ? 1 : 0;
        int kk = (k < 64) ? k : (k < 128) ? k - 64 : k - 128;
        float v = ew3[n * 64 + kk];
        unsigned short hi = f2bf(v);
        wB3[q] = part ? f2bf(v - bf2f(hi)) : hi;
    } else if (i < 264704) {
        int k = i - 264192;
        const float* r = cb + k * 64;
        float s = 0.f;
#pragma unroll
        for (int c = 0; c < 64; ++c) s += r[c] * r[c];
        cn[k] = s;
    } else if (i == 264704) {
        *loss = 0.f;
    }
}

// ---- conv1: x (bc,50,50) -> h1 (bc,25,25,32) f32, relu ---------------------
__global__ __launch_bounds__(256) void k_conv1(const float* __restrict__ x,
                                               const float* __restrict__ w,
                                               const float* __restrict__ b,
                                               float* __restrict__ h1, int total) {
    __shared__ float4 wl4[72];
    float* wl = (float*)wl4;
    int tid = threadIdx.x;
    for (int t = tid; t < 288; t += 256) {
        int tap = t >> 5, co = t & 31;
        wl[t] = w[co * 9 + tap];
    }
    __syncthreads();
    int pix = blockIdx.x * 256 + tid;
    if (pix >= total) return;
    int n = pix / 625, p = pix % 625, oh = p / 25, ow = p % 25;
    const float* xp = x + (size_t)n * 2500;
    float4 a[8];
#pragma unroll
    for (int j = 0; j < 8; ++j) a[j] = ((const float4*)b)[j];
#pragma unroll
    for (int kh = 0; kh < 3; ++kh) {
        int ih = 2 * oh - 1 + kh;
        if ((unsigned)ih >= 50u) continue;
#pragma unroll
        for (int kw = 0; kw < 3; ++kw) {
            int iw = 2 * ow - 1 + kw;
            if ((unsigned)iw >= 50u) continue;
            float v = xp[ih * 50 + iw];
            int tap = kh * 3 + kw;
#pragma unroll
            for (int j = 0; j < 8; ++j) {
                float4 ww = wl4[tap * 8 + j];
                a[j].x += v * ww.x; a[j].y += v * ww.y;
                a[j].z += v * ww.z; a[j].w += v * ww.w;
            }
        }
    }
    float4* op = (float4*)(h1 + (size_t)pix * 32);
#pragma unroll
    for (int j = 0; j < 8; ++j) {
        float4 r;
        r.x = fmaxf(a[j].x, 0.f); r.y = fmaxf(a[j].y, 0.f);
        r.z = fmaxf(a[j].z, 0.f); r.w = fmaxf(a[j].w, 0.f);
        op[j] = r;
    }
}

// ---- enc_m: fused conv2(k3s2p1)+relu+conv3(1x1), split-bf16 MFMA -----------
__global__ __launch_bounds__(256) void k_enc_m(const float* __restrict__ h1,
                                               const unsigned short* __restrict__ B2n,
                                               const unsigned short* __restrict__ B3,
                                               const float* __restrict__ b2,
                                               const float* __restrict__ b3,
                                               float* __restrict__ z, int npix) {
    __shared__ short a1[16 * 872];
    __shared__ short a2[16 * 200];
    __shared__ float cz[16 * 68];
    int tid = threadIdx.x, blk = blockIdx.x;
    {
        int m = tid >> 4, chunk = tid & 15;
        if (chunk < 9) {
            int pix = blk * 16 + m;
            float4 v[8];
            const float4 zero = {0.f, 0.f, 0.f, 0.f};
            bool ok = false;
            if (pix < npix) {
                int n = pix / 169, p = pix % 169, oh = p / 13, ow = p % 13;
                int kh = chunk / 3, kw = chunk % 3;
                int ih = 2 * oh - 1 + kh, iw = 2 * ow - 1 + kw;
                ok = ((unsigned)ih < 25u) && ((unsigned)iw < 25u);
                if (ok) {
                    const float4* ip = (const float4*)(h1 + (((size_t)n * 25 + ih) * 25 + iw) * 32);
#pragma unroll
                    for (int c4 = 0; c4 < 8; ++c4) v[c4] = ip[c4];
                }
            }
            if (!ok) {
#pragma unroll
                for (int c4 = 0; c4 < 8; ++c4) v[c4] = zero;
            }
            unsigned short hi[32], lo[32];
#pragma unroll
            for (int c4 = 0; c4 < 8; ++c4) {
                float vv[4] = {v[c4].x, v[c4].y, v[c4].z, v[c4].w};
#pragma unroll
                for (int e = 0; e < 4; ++e) {
                    int ci = c4 * 4 + e;
                    unsigned short h = f2bf(vv[e]);
                    hi[ci] = h;
                    lo[ci] = f2bf(vv[e] - bf2f(h));
                }
            }
            short* row = a1 + m * 872 + chunk * 32;
            i4v* d0 = (i4v*)row;
            i4v* d1 = (i4v*)(row + 288);
            i4v* d2 = (i4v*)(row + 576);
#pragma unroll
            for (int g = 0; g < 4; ++g) {
                i4v ph, pl;
#pragma unroll
                for (int e = 0; e < 4; ++e) {
                    int b0 = g * 8 + e * 2;
                    ph[e] = (int)((unsigned)hi[b0] | ((unsigned)hi[b0 + 1] << 16));
                    pl[e] = (int)((unsigned)lo[b0] | ((unsigned)lo[b0 + 1] << 16));
                }
                d0[g] = ph; d1[g] = ph; d2[g] = pl;
            }
        }
    }
    __syncthreads();
    int wave = tid >> 6, lane = tid & 63;
    int arow1 = (lane & 15) * 872 + (lane >> 4) * 8;
    f4v acc = (f4v){0.f, 0.f, 0.f, 0.f};
#pragma unroll
    for (int kc = 0; kc < 27; ++kc) {
        s8v a = *(const s8v*)(a1 + arow1 + kc * 32);
        s8v b = *(const s8v*)((const short*)B2n + ((size_t)((wave * 27 + kc) * 64 + lane)) * 8);
        acc = __builtin_amdgcn_mfma_f32_16x16x32_bf16(a, b, acc, 0, 0, 0);
    }
    {
        float bv = b2[wave * 16 + (lane & 15)];
        int n = wave * 16 + (lane & 15);
#pragma unroll
        for (int r = 0; r < 4; ++r) {
            int m = (lane >> 4) * 4 + r;
            float h = fmaxf(acc[r] + bv, 0.f);
            unsigned short hh = f2bf(h);
            unsigned short ll = f2bf(h - bf2f(hh));
            a2[m * 200 + n] = (short)hh;
            a2[m * 200 + 64 + n] = (short)hh;
            a2[m * 200 + 128 + n] = (short)ll;
        }
    }
    __syncthreads();
    int arow2 = (lane & 15) * 200 + (lane >> 4) * 8;
    f4v acc2 = (f4v){0.f, 0.f, 0.f, 0.f};
#pragma unroll
    for (int kc = 0; kc < 6; ++kc) {
        s8v a = *(const s8v*)(a2 + arow2 + kc * 32);
        s8v b = *(const s8v*)((const short*)B3 + ((size_t)((wave * 6 + kc) * 64 + lane)) * 8);
        acc2 = __builtin_amdgcn_mfma_f32_16x16x32_bf16(a, b, acc2, 0, 0, 0);
    }
    {
        float bv = b3[wave * 16 + (lane & 15)];
        int n = wave * 16 + (lane & 15);
#pragma unroll
        for (int r = 0; r < 4; ++r) {
            int m = (lane >> 4) * 4 + r;
            cz[m * 68 + n] = acc2[r] + bv;
        }
    }
    __syncthreads();
    {
        int m = tid >> 4, c4 = tid & 15;
        int pix = blk * 16 + m;
        if (pix < npix) {
            float4 v = *(float4*)(cz + m * 68 + c4 * 4);
            *(float4*)(z + (size_t)pix * 64 + c4 * 4) = v;
        }
    }
}

// ---- vq_m: MFMA distance GEMM + fused argmin + q gather + loss -------------
// M=64/block (4 m-tiles/wave, A-frags in regs => 4 MFMA per B-load),
// N=512 (4 waves x 8 nt), K=192. First-min semantics: ascending-k scan,
// strict <, explicit k tie-break at every merge level.
__global__ __launch_bounds__(256) void k_vq_m(const float* __restrict__ z,
                                              const float* __restrict__ cb,
                                              const unsigned short* __restrict__ cbm,
                                              const float* __restrict__ cn,
                                              float* __restrict__ q,
                                              float* __restrict__ loss, int npix) {
    __shared__ short a_lds[64 * 200];  // 25.6 KB
    __shared__ float reds[4 * 64];
    __shared__ int   redk[4 * 64];
    __shared__ int   bkf[64];
    __shared__ float lred[4];
    int tid = threadIdx.x, blk = blockIdx.x;
#pragma unroll
    for (int it = 0; it < 2; ++it) {   // stage 64 pixels, 8 threads each
        int idx = tid + it * 256;
        int m = idx >> 3, p = idx & 7;
        int pix = blk * 64 + m;
        unsigned short zh[8], zl[8];
        if (pix < npix) {
            const float* src = z + (size_t)pix * 64 + p * 8;
#pragma unroll
            for (int v = 0; v < 8; ++v) {
                float f = src[v];
                unsigned short h = f2bf(f);
                zh[v] = h; zl[v] = f2bf(f - bf2f(h));
            }
        } else {
#pragma unroll
            for (int v = 0; v < 8; ++v) { zh[v] = 0; zl[v] = 0; }
        }
        unsigned ph[4], pl[4];
#pragma unroll
        for (int v = 0; v < 4; ++v) {
            ph[v] = (unsigned)zh[2 * v] | ((unsigned)zh[2 * v + 1] << 16);
            pl[v] = (unsigned)zl[2 * v] | ((unsigned)zl[2 * v + 1] << 16);
        }
        short* row = a_lds + m * 200;
        i4v vh = (i4v){(int)ph[0], (int)ph[1], (int)ph[2], (int)ph[3]};
        i4v vl = (i4v){(int)pl[0], (int)pl[1], (int)pl[2], (int)pl[3]};
        *(i4v*)(row + p * 8) = vh;
        *(i4v*)(row + 64 + p * 8) = vh;
        *(i4v*)(row + 128 + p * 8) = vl;
    }
    __syncthreads();
    int wave = tid >> 6, lane = tid & 63;
    s8v af[4][6];  // A-frags for 4 m-tiles
#pragma unroll
    for (int mt = 0; mt < 4; ++mt) {
        int arow = (mt * 16 + (lane & 15)) * 200 + (lane >> 4) * 8;
#pragma unroll
        for (int kc = 0; kc < 6; ++kc)
            af[mt][kc] = *(const s8v*)(a_lds + arow + kc * 32);
    }
    float bd[4][4];
    int bk[4][4];
#pragma unroll
    for (int mt = 0; mt < 4; ++mt)
#pragma unroll
        for (int r = 0; r < 4; ++r) { bd[mt][r] = 3.4e38f; bk[mt][r] = 0; }
#pragma unroll 1
    for (int nt = 0; nt < 8; ++nt) {
        int ntg = wave * 8 + nt;
        s8v bf[6];
#pragma unroll
        for (int kc = 0; kc < 6; ++kc)
            bf[kc] = *(const s8v*)((const short*)cbm + ((size_t)((ntg * 6 + kc) * 64 + lane)) * 8);
        f4v acc[4];
#pragma unroll
        for (int mt = 0; mt < 4; ++mt) acc[mt] = (f4v){0.f, 0.f, 0.f, 0.f};
#pragma unroll
        for (int kc = 0; kc < 6; ++kc) {
#pragma unroll
            for (int mt = 0; mt < 4; ++mt)
                acc[mt] = __builtin_amdgcn_mfma_f32_16x16x32_bf16(af[mt][kc], bf[kc], acc[mt], 0, 0, 0);
        }
        int kcol = ntg * 16 + (lane & 15);
        float cnk = cn[kcol];
#pragma unroll
        for (int mt = 0; mt < 4; ++mt)
#pragma unroll
            for (int r = 0; r < 4; ++r) {
                float d = cnk - 2.f * acc[mt][r];
                if (d < bd[mt][r]) { bd[mt][r] = d; bk[mt][r] = kcol; }
            }
    }
    // butterfly argmin across the 16 columns
#pragma unroll
    for (int off = 1; off < 16; off <<= 1) {
#pragma unroll
        for (int mt = 0; mt < 4; ++mt)
#pragma unroll
            for (int r = 0; r < 4; ++r) {
                float od = __shfl_xor(bd[mt][r], off);
                int ok = __shfl_xor(bk[mt][r], off);
                if (od < bd[mt][r] || (od == bd[mt][r] && ok < bk[mt][r])) {
                    bd[mt][r] = od; bk[mt][r] = ok;
                }
            }
    }
    if ((lane & 15) == 0) {
#pragma unroll
        for (int mt = 0; mt < 4; ++mt)
#pragma unroll
            for (int r = 0; r < 4; ++r) {
                int m = mt * 16 + (lane >> 4) * 4 + r;
                reds[wave * 64 + m] = bd[mt][r];
                redk[wave * 64 + m] = bk[mt][r];
            }
    }
    __syncthreads();
    if (tid < 64) {  // merge 4 waves (ascending k ranges)
        float d0 = reds[tid]; int k0 = redk[tid];
#pragma unroll
        for (int w = 1; w < 4; ++w) {
            float dw = reds[w * 64 + tid]; int kw = redk[w * 64 + tid];
            if (dw < d0 || (dw == d0 && kw < k0)) { d0 = dw; k0 = kw; }
        }
        bkf[tid] = k0;
    }
    __syncthreads();
    float lsum = 0.f;
#pragma unroll
    for (int it = 0; it < 4; ++it) {   // 64 pixels x 16 f4 chunks
        int idx = tid + it * 256;
        int m = idx >> 4, c4 = idx & 15;
        int pix = blk * 64 + m;
        if (pix < npix) {
            int k0 = bkf[m];
            float4 cq = ((const float4*)cb)[(size_t)k0 * 16 + c4];
            float4 zz = ((const float4*)(z + (size_t)pix * 64))[c4];
            float dx = cq.x - zz.x, dy = cq.y - zz.y, dz = cq.z - zz.z, dw = cq.w - zz.w;
            lsum += dx * dx + dy * dy + dz * dz + dw * dw;
            ((float4*)(q + (size_t)pix * 64))[c4] = cq;
        }
    }
#pragma unroll
    for (int off = 32; off > 0; off >>= 1) lsum += __shfl_down(lsum, off);
    if ((tid & 63) == 0) lred[tid >> 6] = lsum;
    __syncthreads();
    if (tid == 0) {
        float t = lred[0] + lred[1] + lred[2] + lred[3];
        atomicAdd(loss, t * (1.25f / 11075584.f));
    }
}

// ---- tconv1 MFMA: q f32 -> d1 bf16 (25,25,64), relu. M=32/block ------------
__global__ __launch_bounds__(256) void k_tconv1_m(const float* __restrict__ q,
                                                  const unsigned short* __restrict__ wB,
                                                  const float* __restrict__ bias,
                                                  unsigned short* __restrict__ d1,
                                                  int nquad) {
    __shared__ short a_lds[32 * 264];
    __shared__ short c_lds[32 * 264];
    int tid = threadIdx.x, blk = blockIdx.x;
#pragma unroll
    for (int pass = 0; pass < 4; ++pass) {
        int idx = tid + pass * 256;
        int m = idx >> 5, sub = idx & 31;
        int qg = blk * 32 + m;
        int p = sub >> 3, ci0 = (sub & 7) * 8;
        unsigned short t8[8];
        bool have = false;
        if (qg < nquad) {
            int img = qg / 169, r = qg % 169, qm = r / 13, qw = r % 13;
            int sm = qm + (p >> 1), sw = qw + (p & 1);
            if (sm < 13 && sw < 13) {
                const float* src = q + (((size_t)img * 13 + sm) * 13 + sw) * 64 + ci0;
#pragma unroll
                for (int v = 0; v < 8; ++v) t8[v] = f2bf(src[v]);
                have = true;
            }
        }
        if (!have) {
#pragma unroll
            for (int v = 0; v < 8; ++v) t8[v] = 0;
        }
        i4v pk;
#pragma unroll
        for (int e = 0; e < 4; ++e)
            pk[e] = (int)((unsigned)t8[2 * e] | ((unsigned)t8[2 * e + 1] << 16));
        *(i4v*)(a_lds + m * 264 + sub * 8) = pk;
    }
    __syncthreads();
    int wave = tid >> 6, lane = tid & 63;
    f4v acc[2][4];
#pragma unroll
    for (int mt = 0; mt < 2; ++mt)
#pragma unroll
        for (int i = 0; i < 4; ++i) acc[mt][i] = (f4v){0.f, 0.f, 0.f, 0.f};
    float bv[4];
#pragma unroll
    for (int i = 0; i < 4; ++i) bv[i] = bias[((wave * 4 + i) * 16 + (lane & 15)) & 63];
#pragma unroll
    for (int kc = 0; kc < 8; ++kc) {
        s8v a0 = *(const s8v*)(a_lds + ((lane & 15)) * 264 + (lane >> 4) * 8 + kc * 32);
        s8v a1 = *(const s8v*)(a_lds + (16 + (lane & 15)) * 264 + (lane >> 4) * 8 + kc * 32);
#pragma unroll
        for (int i = 0; i < 4; ++i) {
            int nt = wave * 4 + i;
            s8v b = *(const s8v*)((const short*)wB + ((size_t)((nt * 8 + kc) * 64 + lane)) * 8);
            acc[0][i] = __builtin_amdgcn_mfma_f32_16x16x32_bf16(a0, b, acc[0][i], 0, 0, 0);
            acc[1][i] = __builtin_amdgcn_mfma_f32_16x16x32_bf16(a1, b, acc[1][i], 0, 0, 0);
        }
    }
#pragma unroll
    for (int mt = 0; mt < 2; ++mt)
#pragma unroll
        for (int i = 0; i < 4; ++i) {
            int n = (wave * 4 + i) * 16 + (lane & 15);
#pragma unroll
            for (int r2 = 0; r2 < 4; ++r2) {
                int m = mt * 16 + (lane >> 4) * 4 + r2;
                float v = fmaxf(acc[mt][i][r2] + bv[i], 0.f);
                c_lds[m * 264 + n] = (short)f2bf(v);
            }
        }
    __syncthreads();
#pragma unroll
    for (int pass = 0; pass < 4; ++pass) {
        int ch = tid + pass * 256;
        int m = ch >> 5, cpart = ch & 31;
        int qg = blk * 32 + m;
        if (qg >= nquad) continue;
        int img = qg / 169, r = qg % 169, qm = r / 13, qw = r % 13;
        int cls = cpart >> 3, co8 = (cpart & 7) * 8;
        int oh = 2 * qm + (cls >> 1), ow = 2 * qw + (cls & 1);
        if (oh >= 25 || ow >= 25) continue;
        i4v val = *(i4v*)(c_lds + m * 264 + cls * 64 + co8);
        *(i4v*)(d1 + (((size_t)img * 25 + oh) * 25 + ow) * 64 + co8) = val;
    }
}

// ---- tconv2 MFMA: d1 bf16 -> d2 bf16 (50,50,32), relu. M=32/block ----------
__global__ __launch_bounds__(256) void k_tconv2_m(const unsigned short* __restrict__ d1,
                                                  const unsigned short* __restrict__ wB,
                                                  const float* __restrict__ bias,
                                                  unsigned short* __restrict__ d2,
                                                  int nquad) {
    __shared__ short a_lds[32 * 264];
    __shared__ short c_lds[32 * 136];
    int tid = threadIdx.x, blk = blockIdx.x;
#pragma unroll
    for (int pass = 0; pass < 4; ++pass) {
        int idx = tid + pass * 256;
        int m = idx >> 5, sub = idx & 31;
        int qg = blk * 32 + m;
        int p = sub >> 3, ci0 = (sub & 7) * 8;
        i4v v = (i4v){0, 0, 0, 0};
        if (qg < nquad) {
            int img = qg / 625, r = qg % 625, qm = r / 25, qw = r % 25;
            int sm = qm + (p >> 1), sw = qw + (p & 1);
            if (sm < 25 && sw < 25)
                v = *(const i4v*)(d1 + (((size_t)img * 25 + sm) * 25 + sw) * 64 + ci0);
        }
        *(i4v*)(a_lds + m * 264 + sub * 8) = v;
    }
    __syncthreads();
    int wave = tid >> 6, lane = tid & 63;
    f4v acc[2][2];
#pragma unroll
    for (int mt = 0; mt < 2; ++mt)
#pragma unroll
        for (int i = 0; i < 2; ++i) acc[mt][i] = (f4v){0.f, 0.f, 0.f, 0.f};
    float bv[2];
#pragma unroll
    for (int i = 0; i < 2; ++i) bv[i] = bias[((wave * 2 + i) * 16 + (lane & 15)) & 31];
#pragma unroll
    for (int kc = 0; kc < 8; ++kc) {
        s8v a0 = *(const s8v*)(a_lds + ((lane & 15)) * 264 + (lane >> 4) * 8 + kc * 32);
        s8v a1 = *(const s8v*)(a_lds + (16 + (lane & 15)) * 264 + (lane >> 4) * 8 + kc * 32);
#pragma unroll
        for (int i = 0; i < 2; ++i) {
            int nt = wave * 2 + i;
            s8v b = *(const s8v*)((const short*)wB + ((size_t)((nt * 8 + kc) * 64 + lane)) * 8);
            acc[0][i] = __builtin_amdgcn_mfma_f32_16x16x32_bf16(a0, b, acc[0][i], 0, 0, 0);
            acc[1][i] = __builtin_amdgcn_mfma_f32_16x16x32_bf16(a1, b, acc[1][i], 0, 0, 0);
        }
    }
#pragma unroll
    for (int mt = 0; mt < 2; ++mt)
#pragma unroll
        for (int i = 0; i < 2; ++i) {
            int n = (wave * 2 + i) * 16 + (lane & 15);
#pragma unroll
            for (int r2 = 0; r2 < 4; ++r2) {
                int m = mt * 16 + (lane >> 4) * 4 + r2;
                float v = fmaxf(acc[mt][i][r2] + bv[i], 0.f);
                c_lds[m * 136 + n] = (short)f2bf(v);
            }
        }
    __syncthreads();
#pragma unroll
    for (int pass = 0; pass < 2; ++pass) {
        int ch = tid + pass * 256;
        int m = ch >> 4, cpart = ch & 15;
        int qg = blk * 32 + m;
        if (qg >= nquad) continue;
        int img = qg / 625, r = qg % 625, qm = r / 25, qw = r % 25;
        int cls = cpart >> 2, co8 = (cpart & 3) * 8;
        int oh = 2 * qm + (cls >> 1), ow = 2 * qw + (cls & 1);
        i4v val = *(i4v*)(c_lds + m * 136 + cls * 32 + co8);
        *(i4v*)(d2 + (((size_t)img * 50 + oh) * 50 + ow) * 32 + co8) = val;
    }
}

// ---- convf: d2 bf16 (bc,50,50,32) -> out f32 (bc,50,50), sigmoid -----------
__global__ __launch_bounds__(256) void k_convf(const unsigned short* __restrict__ in,
                                               const float* __restrict__ w,  // dw3 (1,32,3,3)
                                               const float* __restrict__ b,
                                               float* __restrict__ out, int total) {
    __shared__ float wl[288];  // [tap9][ci32]
    int tid = threadIdx.x;
    for (int t = tid; t < 288; t += 256) {
        int tap = t >> 5, ci = t & 31;
        wl[t] = w[ci * 9 + tap];
    }
    __syncthreads();
    int pix = blockIdx.x * 256 + tid;
    if (pix >= total) return;
    int n = pix / 2500, p = pix % 2500, oh = p / 50, ow = p % 50;
    float acc = b[0];
#pragma unroll
    for (int kh = 0; kh < 3; ++kh) {
        int ih = oh - 1 + kh;
        if ((unsigned)ih >= 50u) continue;
#pragma unroll
        for (int kw = 0; kw < 3; ++kw) {
            int iw = ow - 1 + kw;
            if ((unsigned)iw >= 50u) continue;
            const float* wt = wl + (kh * 3 + kw) * 32;
            const i4v* ip4 = (const i4v*)(in + (((size_t)n * 50 + ih) * 50 + iw) * 32);
#pragma unroll
            for (int c8 = 0; c8 < 4; ++c8) {
                i4v u = ip4[c8];
#pragma unroll
                for (int e = 0; e < 4; ++e) {
                    unsigned uu = (unsigned)u[e];
                    float x0 = __builtin_bit_cast(float, uu << 16);
                    float x1 = __builtin_bit_cast(float, uu & 0xffff0000u);
                    acc = fmaf(x0, wt[c8 * 8 + e * 2], acc);
                    acc = fmaf(x1, wt[c8 * 8 + e * 2 + 1], acc);
                }
            }
        }
    }
    out[pix] = 1.f / (1.f + expf(-acc));
}

extern "C" void kernel_launch(void* const* d_in, const int* in_sizes, int n_in,
                              void* d_out, int out_size, void* d_ws, size_t ws_size,
                              hipStream_t stream) {
    const float* x   = (const float*)d_in[0];
    const float* ew1 = (const float*)d_in[1];
    const float* eb1 = (const float*)d_in[2];
    const float* ew2 = (const float*)d_in[3];
    const float* eb2 = (const float*)d_in[4];
    const float* ew3 = (const float*)d_in[5];
    const float* eb3 = (const float*)d_in[6];
    const float* cb  = (const float*)d_in[7];
    const float* dw1 = (const float*)d_in[8];
    const float* db1 = (const float*)d_in[9];
    const float* dw2 = (const float*)d_in[10];
    const float* db2 = (const float*)d_in[11];
    const float* dw3 = (const float*)d_in[12];
    const float* db3 = (const float*)d_in[13];
    float* out = (float*)d_out;
    float* loss = out + 2560000;

    float* ws = (float*)d_ws;
    float* cn = ws;                                        // 512 f
    unsigned short* wB1  = (unsigned short*)(ws + 512);    // 65536 sh
    unsigned short* wB2  = (unsigned short*)(ws + 33280);  // 32768 sh
    unsigned short* wB2n = (unsigned short*)(ws + 49664);  // 55296 sh
    unsigned short* wB3  = (unsigned short*)(ws + 77312);  // 12288 sh
    unsigned short* cbm  = (unsigned short*)(ws + 83456);  // 98304 sh
    const size_t tw_floats = 132608;

    const int B = 1024;
    const size_t A_per = 40000, B_per = 20000;
    size_t avail = (ws_size / 4 > tw_floats) ? ws_size / 4 - tw_floats : 0;
    int BC = (int)(avail / (A_per + B_per));
    if (BC > B) BC = B;
    if (BC < 1) BC = 1;
    float* regA = ws + tw_floats;
    float* regB = regA + (size_t)BC * A_per;

    // one fused prep kernel (cbm|B2n|B1|B2|B3|cn|loss-zero)
    k_prep_all<<<1035, 256, 0, stream>>>(cb, ew2, ew3, dw1, dw2,
                                         cbm, wB2n, wB1, wB2, wB3, cn, loss);

    for (int n0 = 0; n0 < B; n0 += BC) {
        int bc = (B - n0 < BC) ? (B - n0) : BC;
        const float* xch = x + (size_t)n0 * 2500;

        int t1 = bc * 625;   // conv1: x -> h1 (regA)
        k_conv1<<<(t1 + 255) / 256, 256, 0, stream>>>(xch, ew1, eb1, regA, t1);

        int npix = bc * 169;
        // fused conv2+conv3 MFMA: h1 (regA) -> z (regB)
        k_enc_m<<<(npix + 15) / 16, 256, 0, stream>>>(regA, wB2n, wB3, eb2, eb3, regB, npix);

        // MFMA VQ (M=64): z (regB) -> q (regA) + loss
        k_vq_m<<<(npix + 63) / 64, 256, 0, stream>>>(regB, cb, cbm, cn, regA, loss, npix);

        // tconv1 MFMA: q (regA f32) -> d1 (regB bf16)
        unsigned short* d1 = (unsigned short*)regB;
        k_tconv1_m<<<(npix + 31) / 32, 256, 0, stream>>>(regA, wB1, db1, d1, npix);

        // tconv2 MFMA: d1 (regB bf16) -> d2 (regA bf16)
        int nq2 = bc * 625;
        unsigned short* d2 = (unsigned short*)regA;
        k_tconv2_m<<<(nq2 + 31) / 32, 256, 0, stream>>>(d1, wB2, db2, d2, nq2);

        int t6 = bc * 2500;  // convf: d2 bf16 (regA) -> out
        k_convf<<<(t6 + 255) / 256, 256, 0, stream>>>(d2, dw3, db3, out + (size_t)n0 * 2500, t6);
    }
}